// Round 15
// baseline (1226.598 us; speedup 1.0000x reference)
//
#include <hip/hip_runtime.h>

#define DEV static __device__ __forceinline__

DEV float sqdist(float dx, float dy, float dz) {
    // ((dx*dx + dy*dy) + dz*dz) with no FMA contraction — must match numpy f32
    return __fadd_rn(__fadd_rn(__fmul_rn(dx, dx), __fmul_rn(dy, dy)), __fmul_rn(dz, dz));
}

DEV void fma4(float4& acc, float h, const float4& w) {
    acc.x = fmaf(h, w.x, acc.x); acc.y = fmaf(h, w.y, acc.y);
    acc.z = fmaf(h, w.z, acc.z); acc.w = fmaf(h, w.w, acc.w);
}

// ---- argmax combine steps (value desc, index asc on ties) ----
template<int CTRL>
DEV int dpp_mov(int v) {
    return __builtin_amdgcn_update_dpp(v, v, CTRL, 0xF, 0xF, false);
}
template<int CTRL>
DEV void red_step_dpp(float& bv, int& bi) {
    float ov = __builtin_bit_cast(float, dpp_mov<CTRL>(__builtin_bit_cast(int, bv)));
    int   oi = dpp_mov<CTRL>(bi);
    if (ov > bv || (ov == bv && oi < bi)) { bv = ov; bi = oi; }
}
// full 64-lane argmax; result valid in lane 63
DEV void wave_argmax(float& bv, int& bi) {
    red_step_dpp<0xB1>(bv, bi);    // quad_perm xor 1
    red_step_dpp<0x4E>(bv, bi);    // quad_perm xor 2
    red_step_dpp<0x141>(bv, bi);   // row_half_mirror (xor 4)
    red_step_dpp<0x140>(bv, bi);   // row_mirror (xor 8)
    red_step_dpp<0x142>(bv, bi);   // row_bcast15
    red_step_dpp<0x143>(bv, bi);   // row_bcast31 -> lane 63 has full result
}

// ---- single-wave FPS over SoA LDS points (no barriers) ----
template<int N, int NPOINT>
DEV void fps_wave64_soa(const float* px, const float* py, const float* pz,
                        float* sout, int lane) {
    constexpr int K = (N + 63) / 64;
    float rx[K], ry[K], rz[K], d[K];
#pragma unroll
    for (int k = 0; k < K; ++k) {
        const int p = lane + k * 64;
        rx[k] = px[p]; ry[k] = py[p]; rz[k] = pz[p]; d[k] = 1e10f;
    }
    float cx = px[0], cy = py[0], cz = pz[0];
    for (int s = 0; s < NPOINT; ++s) {
        if (lane == 0) { sout[s * 3 + 0] = cx; sout[s * 3 + 1] = cy; sout[s * 3 + 2] = cz; }
        float bestv = -1.0f; int besti = 0x7fffffff;
#pragma unroll
        for (int k = 0; k < K; ++k) {
            float d2 = sqdist(rx[k] - cx, ry[k] - cy, rz[k] - cz);
            d[k] = fminf(d[k], d2);
            if (d[k] > bestv) { bestv = d[k]; besti = lane + k * 64; }
        }
        wave_argmax(bestv, besti);
        const int far = __builtin_amdgcn_readlane(besti, 63);
        cx = px[far]; cy = py[far]; cz = pz[far];
    }
}

// ---------------- Fused FPS, TWO batches per block -----------------
// The per-step tail (~1900cyc: argmax chain + barrier + slot exchange +
// far-lookup) is pure latency. Two independent batches interleave their
// chains and share ONE barrier -> tail amortized over 2 steps.
// Stages 2/3: wave 0 handles batch A, wave 1 handles batch B (parallel).
__global__ __launch_bounds__(256)
void fps_fused2_kernel(const float* __restrict__ pc,
                       float* __restrict__ nxyz1, float* __restrict__ nxyz2,
                       float* __restrict__ nxyz3)
{
    constexpr int N1 = 4096, NP1 = 256, NP2 = 64, NP3 = 16, T = 256, NW = T / 64;
    constexpr int K = N1 / T;
    __shared__ float pxA[N1], pyA[N1], pzA[N1];
    __shared__ float pxB[N1], pyB[N1], pzB[N1];
    __shared__ float sout1[2][NP1 * 3];
    __shared__ float sout2[2][NP2 * 3];
    __shared__ float sout3[2][NP3 * 3];
    __shared__ float rv[2][2][NW];     // [batch][parity][wave]
    __shared__ int   ri[2][2][NW];

    const int bA = blockIdx.x * 2, bB = bA + 1;
    const int tid = threadIdx.x;
    const int w = tid >> 6, lane = tid & 63;
    const float* baseA = pc + (size_t)bA * N1 * 6;
    const float* baseB = pc + (size_t)bB * N1 * 6;

    float rxA[K], ryA[K], rzA[K], dA[K];
    float rxB[K], ryB[K], rzB[K], dB[K];
#pragma unroll
    for (int k = 0; k < K; ++k) {
        const int p = tid + k * T;
        rxA[k] = baseA[p * 6 + 0]; ryA[k] = baseA[p * 6 + 1]; rzA[k] = baseA[p * 6 + 2];
        rxB[k] = baseB[p * 6 + 0]; ryB[k] = baseB[p * 6 + 1]; rzB[k] = baseB[p * 6 + 2];
        pxA[p] = rxA[k]; pyA[p] = ryA[k]; pzA[p] = rzA[k];
        pxB[p] = rxB[k]; pyB[p] = ryB[k]; pzB[p] = rzB[k];
        dA[k] = 1e10f; dB[k] = 1e10f;
    }
    __syncthreads();

    // ---- stage 1 for both batches, lockstep, one barrier per step ----
    {
        float cxA = pxA[0], cyA = pyA[0], czA = pzA[0];
        float cxB = pxB[0], cyB = pyB[0], czB = pzB[0];
        for (int s = 0; s < NP1; ++s) {
            if (tid == 0) {
                sout1[0][s * 3 + 0] = cxA; sout1[0][s * 3 + 1] = cyA; sout1[0][s * 3 + 2] = czA;
                sout1[1][s * 3 + 0] = cxB; sout1[1][s * 3 + 1] = cyB; sout1[1][s * 3 + 2] = czB;
            }
            float bvA = -1.0f; int biA = 0x7fffffff;
            float bvB = -1.0f; int biB = 0x7fffffff;
#pragma unroll
            for (int k = 0; k < K; ++k) {
                const int p = tid + k * T;
                float d2a = sqdist(rxA[k] - cxA, ryA[k] - cyA, rzA[k] - czA);
                float d2b = sqdist(rxB[k] - cxB, ryB[k] - cyB, rzB[k] - czB);
                dA[k] = fminf(dA[k], d2a);
                dB[k] = fminf(dB[k], d2b);
                if (dA[k] > bvA) { bvA = dA[k]; biA = p; }  // k asc => lowest p on tie
                if (dB[k] > bvB) { bvB = dB[k]; biB = p; }
            }
            wave_argmax(bvA, biA);
            wave_argmax(bvB, biB);

            const int par = s & 1;
            if (lane == 63) {
                rv[0][par][w] = bvA; ri[0][par][w] = biA;
                rv[1][par][w] = bvB; ri[1][par][w] = biB;
            }
            __syncthreads();
            float bvvA = rv[0][par][0]; int biiA = ri[0][par][0];
            float bvvB = rv[1][par][0]; int biiB = ri[1][par][0];
#pragma unroll
            for (int q = 1; q < NW; ++q) {
                const float qvA = rv[0][par][q]; const int qiA = ri[0][par][q];
                if (qvA > bvvA || (qvA == bvvA && qiA < biiA)) { bvvA = qvA; biiA = qiA; }
                const float qvB = rv[1][par][q]; const int qiB = ri[1][par][q];
                if (qvB > bvvB || (qvB == bvvB && qiB < biiB)) { bvvB = qvB; biiB = qiB; }
            }
            cxA = pxA[biiA]; cyA = pyA[biiA]; czA = pzA[biiA];
            cxB = pxB[biiB]; cyB = pyB[biiB]; czB = pzB[biiB];
        }
    }
    __syncthreads();   // sout1[1] (written by wave 0) must be visible to wave 1

    // ---- stages 2 + 3: wave 0 -> batch A, wave 1 -> batch B (parallel) ----
    if (w == 0) {
        for (int i = lane; i < NP1; i += 64) {
            pxA[i] = sout1[0][i * 3 + 0]; pyA[i] = sout1[0][i * 3 + 1]; pzA[i] = sout1[0][i * 3 + 2];
        }
        fps_wave64_soa<NP1, NP2>(pxA, pyA, pzA, sout2[0], lane);
        for (int i = lane; i < NP2; i += 64) {
            pxA[i] = sout2[0][i * 3 + 0]; pyA[i] = sout2[0][i * 3 + 1]; pzA[i] = sout2[0][i * 3 + 2];
        }
        fps_wave64_soa<NP2, NP3>(pxA, pyA, pzA, sout3[0], lane);
    } else if (w == 1) {
        for (int i = lane; i < NP1; i += 64) {
            pxB[i] = sout1[1][i * 3 + 0]; pyB[i] = sout1[1][i * 3 + 1]; pzB[i] = sout1[1][i * 3 + 2];
        }
        fps_wave64_soa<NP1, NP2>(pxB, pyB, pzB, sout2[1], lane);
        for (int i = lane; i < NP2; i += 64) {
            pxB[i] = sout2[1][i * 3 + 0]; pyB[i] = sout2[1][i * 3 + 1]; pzB[i] = sout2[1][i * 3 + 2];
        }
        fps_wave64_soa<NP2, NP3>(pxB, pyB, pzB, sout3[1], lane);
    }
    __syncthreads();

    for (int u = 0; u < 2; ++u) {
        const int bb = bA + u;
        float* o1 = nxyz1 + (size_t)bb * NP1 * 3;
        for (int i = tid; i < NP1 * 3; i += T) o1[i] = sout1[u][i];
        float* o2 = nxyz2 + (size_t)bb * NP2 * 3;
        if (tid < NP2 * 3) o2[tid] = sout2[u][tid];
        float* o3 = nxyz3 + (size_t)bb * NP3 * 3;
        if (tid < NP3 * 3) o3[tid] = sout3[u][tid];
    }
}

// ---------------- Ball query -----------------
template<int N, int NSAMP, int STRIDE>
__global__ __launch_bounds__(256)
void bq_kernel(const float* __restrict__ xyz, const float* __restrict__ newxyz,
               int* __restrict__ gidx, float r2, int S, int total)
{
    const int wid = blockIdx.x * 4 + (threadIdx.x >> 6);
    if (wid >= total) return;
    const int lane = threadIdx.x & 63;
    const int b = wid / S;
    const float cx = newxyz[(size_t)wid * 3 + 0];
    const float cy = newxyz[(size_t)wid * 3 + 1];
    const float cz = newxyz[(size_t)wid * 3 + 2];
    const float* base = xyz + (size_t)b * N * STRIDE;
    int* out = gidx + (size_t)wid * NSAMP;

    int count = 0, first = N - 1;
    constexpr int NCH = (N + 63) / 64;
    for (int ch = 0; ch < NCH; ++ch) {
        int p = ch * 64 + lane;
        bool pred = false;
        if (N % 64 == 0 || p < N) {
            float dx = base[p * STRIDE + 0] - cx;
            float dy = base[p * STRIDE + 1] - cy;
            float dz = base[p * STRIDE + 2] - cz;
            pred = sqdist(dx, dy, dz) < r2;
        }
        unsigned long long m = __ballot(pred);
        if (m) {
            if (count == 0) first = ch * 64 + __builtin_ctzll(m);
            int pos = count + __popcll(m & ((1ull << lane) - 1ull));
            if (pred && pos < NSAMP) out[pos] = p;
            count += __popcll(m);
            if (count >= NSAMP) break;
        }
    }
    if (count > NSAMP) count = NSAMP;
    for (int pos = count + lane; pos < NSAMP; pos += 64) out[pos] = first;
}

// ---------------- Grouped 2-layer MLP + maxpool -----------------
// MODE 0: stage1 (xyz stride 6, feats = pc permuted). MODE 1: feats array.
// Phase B: unified CHB=4 register tile, PTSB = NS/GRP points per thread.
template<int NS, int CIN, int C1, int C2, int NSRC, int MODE>
__global__ __launch_bounds__(256)
void sa_mlp2_kernel(const float* __restrict__ sxyz, const float* __restrict__ sfeat,
                    const float* __restrict__ newxyz, const int* __restrict__ gidx,
                    const float* __restrict__ W1, const float* __restrict__ B1v,
                    const float* __restrict__ W2, const float* __restrict__ B2v,
                    float* __restrict__ outf, int S)
{
    constexpr int T    = 256;
    constexpr int KCC  = (CIN < 32) ? CIN : 32;            // k-chunk length
    constexpr int KCP0 = ((KCC + 3) / 4) * 4 + 4;
    constexpr int KCP  = ((KCP0 / 4) % 2 == 0) ? KCP0 + 4 : KCP0;  // odd quad stride
    constexpr int NPT  = NS / 4;
    constexpr int NCT1 = C1 / 4;
    constexpr int TPT  = (NPT * NCT1) / T;                 // phase-A tiles per thread
    constexpr int C1P  = C1 + 4;
    constexpr int CT2  = C2 / 4;                           // phase-B: 4 channels/thread
    constexpr int GRP  = T / CT2;                          // parallel point-groups
    constexpr int PTSB = NS / GRP;                         // points per thread
    constexpr int XS   = (MODE == 0) ? 6 : 3;
    constexpr int CF   = CIN - 3;
    static_assert(NS % 4 == 0 && C1 % 4 == 0 && C2 % 4 == 0, "");
    static_assert((NPT * NCT1) % T == 0 && TPT >= 1, "");
    static_assert(T % CT2 == 0 && NS % GRP == 0 && PTSB >= 1, "");

    __shared__ float xgc[NS][KCP];
    __shared__ __align__(16) float h1s[NS][C1P];
    __shared__ int   gix[NS];
    __shared__ float mpart[(GRP > 1) ? GRP * C2 : 4];

    const int g   = blockIdx.x;
    const int b   = g / S;
    const int tid = threadIdx.x;

    float ctr0 = 0.f, ctr1 = 0.f, ctr2 = 0.f;
    ctr0 = newxyz[(size_t)g * 3 + 0];
    ctr1 = newxyz[(size_t)g * 3 + 1];
    ctr2 = newxyz[(size_t)g * 3 + 2];
    for (int i = tid; i < NS; i += T) gix[i] = gidx[(size_t)g * NS + i];
    __syncthreads();

    // ---- Phase A: layer 1, K-chunked, accumulators in registers ----
    float4 acc[TPT][4];
#pragma unroll
    for (int j = 0; j < TPT; ++j) {
        const int tl = tid + j * T;
        const int ct = tl % NCT1;
        const float4 bb = *(const float4*)&B1v[ct * 4];
#pragma unroll
        for (int i = 0; i < 4; ++i) acc[j][i] = bb;
    }

    const int nchunk = (CIN + KCC - 1) / KCC;
    for (int cch = 0; cch < nchunk; ++cch) {
        const int k0 = cch * KCC;
        const int kcLen = (CIN - k0 < KCC) ? (CIN - k0) : KCC;
        if (cch > 0) __syncthreads();
        // gather chunk
        for (int idx = tid; idx < NS * kcLen; idx += T) {
            const int p = idx / kcLen, kk = idx - p * kcLen, k = k0 + kk;
            float v;
            const int gi = gix[p];
            if (k < 3) {
                const float c = (k == 0) ? ctr0 : ((k == 1) ? ctr1 : ctr2);
                v = sxyz[((size_t)b * NSRC + gi) * XS + k] - c;
            } else if constexpr (MODE == 0) {
                const int j2 = k - 3;
                v = sfeat[((size_t)b * NSRC + gi) * 6 + (j2 < 3 ? 3 + j2 : j2 - 3)];
            } else {
                v = sfeat[((size_t)b * NSRC + gi) * CF + (k - 3)];
            }
            xgc[p][kk] = v;
        }
        __syncthreads();
        // compute chunk
#pragma unroll
        for (int j = 0; j < TPT; ++j) {
            const int tl = tid + j * T;
            const int pt = tl / NCT1, ct = tl % NCT1;
            const int p0 = pt * 4, c0 = ct * 4;
            int kk = 0;
            for (; kk + 4 <= kcLen; kk += 4) {
                const float4 xa = *(const float4*)&xgc[p0 + 0][kk];
                const float4 xb = *(const float4*)&xgc[p0 + 1][kk];
                const float4 xc = *(const float4*)&xgc[p0 + 2][kk];
                const float4 xd = *(const float4*)&xgc[p0 + 3][kk];
                const float4 w0 = *(const float4*)&W1[(size_t)(k0 + kk + 0) * C1 + c0];
                const float4 w1 = *(const float4*)&W1[(size_t)(k0 + kk + 1) * C1 + c0];
                const float4 w2 = *(const float4*)&W1[(size_t)(k0 + kk + 2) * C1 + c0];
                const float4 w3 = *(const float4*)&W1[(size_t)(k0 + kk + 3) * C1 + c0];
                fma4(acc[j][0], xa.x, w0); fma4(acc[j][0], xa.y, w1); fma4(acc[j][0], xa.z, w2); fma4(acc[j][0], xa.w, w3);
                fma4(acc[j][1], xb.x, w0); fma4(acc[j][1], xb.y, w1); fma4(acc[j][1], xb.z, w2); fma4(acc[j][1], xb.w, w3);
                fma4(acc[j][2], xc.x, w0); fma4(acc[j][2], xc.y, w1); fma4(acc[j][2], xc.z, w2); fma4(acc[j][2], xc.w, w3);
                fma4(acc[j][3], xd.x, w0); fma4(acc[j][3], xd.y, w1); fma4(acc[j][3], xd.z, w2); fma4(acc[j][3], xd.w, w3);
            }
            for (; kk < kcLen; ++kk) {
                const float4 w = *(const float4*)&W1[(size_t)(k0 + kk) * C1 + c0];
                fma4(acc[j][0], xgc[p0 + 0][kk], w);
                fma4(acc[j][1], xgc[p0 + 1][kk], w);
                fma4(acc[j][2], xgc[p0 + 2][kk], w);
                fma4(acc[j][3], xgc[p0 + 3][kk], w);
            }
        }
    }
    // write h1 (relu)
    __syncthreads();
#pragma unroll
    for (int j = 0; j < TPT; ++j) {
        const int tl = tid + j * T;
        const int pt = tl / NCT1, ct = tl % NCT1;
        const int p0 = pt * 4, c0 = ct * 4;
#pragma unroll
        for (int i = 0; i < 4; ++i) {
            float4 r;
            r.x = fmaxf(acc[j][i].x, 0.f); r.y = fmaxf(acc[j][i].y, 0.f);
            r.z = fmaxf(acc[j][i].z, 0.f); r.w = fmaxf(acc[j][i].w, 0.f);
            *(float4*)&h1s[p0 + i][c0] = r;
        }
    }
    __syncthreads();

    // ---- Phase B: layer 2 + maxpool, PTSB pts x 4 ch per thread ----
    {
        const int ct = tid % CT2, pb = tid / CT2;
        const int c0 = ct * 4;
        const int p0 = pb * PTSB;
        const float4 bb = *(const float4*)&B2v[c0];
        float4 ac[PTSB];
#pragma unroll
        for (int i = 0; i < PTSB; ++i) ac[i] = bb;
#pragma unroll 2
        for (int k = 0; k < C1; k += 4) {
            const float4 w0 = *(const float4*)&W2[(size_t)(k + 0) * C2 + c0];
            const float4 w1 = *(const float4*)&W2[(size_t)(k + 1) * C2 + c0];
            const float4 w2 = *(const float4*)&W2[(size_t)(k + 2) * C2 + c0];
            const float4 w3 = *(const float4*)&W2[(size_t)(k + 3) * C2 + c0];
#pragma unroll
            for (int i = 0; i < PTSB; ++i) {
                const float4 h = *(const float4*)&h1s[p0 + i][k];
                fma4(ac[i], h.x, w0); fma4(ac[i], h.y, w1);
                fma4(ac[i], h.z, w2); fma4(ac[i], h.w, w3);
            }
        }
        float4 m = make_float4(0.f, 0.f, 0.f, 0.f);   // relu>=0
#pragma unroll
        for (int i = 0; i < PTSB; ++i) {
            m.x = fmaxf(m.x, ac[i].x); m.y = fmaxf(m.y, ac[i].y);
            m.z = fmaxf(m.z, ac[i].z); m.w = fmaxf(m.w, ac[i].w);
        }
        if constexpr (GRP == 1) {
            *(float4*)&outf[(size_t)g * C2 + c0] = m;
        } else {
            *(float4*)&mpart[pb * C2 + c0] = m;
            __syncthreads();
            for (int c = tid; c < C2; c += T) {
                float mm = mpart[c];
#pragma unroll
                for (int q = 1; q < GRP; ++q) mm = fmaxf(mm, mpart[q * C2 + c]);
                outf[(size_t)g * C2 + c] = mm;
            }
        }
    }
}

// ---------------- Head part 1: 4 points per block, 515->512->1024 MLP ----
__global__ __launch_bounds__(256)
void head1_kernel(const float* __restrict__ nxyz3, const float* __restrict__ feats3,
                  const float* __restrict__ w4a, const float* __restrict__ b4a,
                  const float* __restrict__ w4b, const float* __restrict__ b4b,
                  float* __restrict__ h4)
{
    const int g0  = blockIdx.x * 4;   // 4 consecutive (b,point) groups
    const int tid = threadIdx.x;
    __shared__ float xrow[4][516];
    __shared__ float h1s[4][512];
    for (int i = tid; i < 4 * 515; i += 256) {
        const int p = i / 515, k = i - p * 515;
        xrow[p][k] = (k < 3) ? nxyz3[(size_t)(g0 + p) * 3 + k]
                             : feats3[(size_t)(g0 + p) * 512 + (k - 3)];
    }
    __syncthreads();
#pragma unroll
    for (int cc = 0; cc < 2; ++cc) {
        const int c = tid + cc * 256;
        const float bb = b4a[c];
        float a0 = bb, a1 = bb, a2 = bb, a3 = bb;
#pragma unroll 4
        for (int k = 0; k < 515; ++k) {
            const float w = w4a[(size_t)k * 512 + c];
            a0 = fmaf(xrow[0][k], w, a0);
            a1 = fmaf(xrow[1][k], w, a1);
            a2 = fmaf(xrow[2][k], w, a2);
            a3 = fmaf(xrow[3][k], w, a3);
        }
        h1s[0][c] = fmaxf(a0, 0.f); h1s[1][c] = fmaxf(a1, 0.f);
        h1s[2][c] = fmaxf(a2, 0.f); h1s[3][c] = fmaxf(a3, 0.f);
    }
    __syncthreads();
    {
        const int c0 = tid * 4;
        const float4 bb = *(const float4*)&b4b[c0];
        float4 a0 = bb, a1 = bb, a2 = bb, a3 = bb;
#pragma unroll 4
        for (int k = 0; k < 512; ++k) {
            const float4 w = *(const float4*)&w4b[(size_t)k * 1024 + c0];
            fma4(a0, h1s[0][k], w);
            fma4(a1, h1s[1][k], w);
            fma4(a2, h1s[2][k], w);
            fma4(a3, h1s[3][k], w);
        }
        float4 r;
        r.x = fmaxf(a0.x, 0.f); r.y = fmaxf(a0.y, 0.f); r.z = fmaxf(a0.z, 0.f); r.w = fmaxf(a0.w, 0.f);
        *(float4*)&h4[(size_t)(g0 + 0) * 1024 + c0] = r;
        r.x = fmaxf(a1.x, 0.f); r.y = fmaxf(a1.y, 0.f); r.z = fmaxf(a1.z, 0.f); r.w = fmaxf(a1.w, 0.f);
        *(float4*)&h4[(size_t)(g0 + 1) * 1024 + c0] = r;
        r.x = fmaxf(a2.x, 0.f); r.y = fmaxf(a2.y, 0.f); r.z = fmaxf(a2.z, 0.f); r.w = fmaxf(a2.w, 0.f);
        *(float4*)&h4[(size_t)(g0 + 2) * 1024 + c0] = r;
        r.x = fmaxf(a3.x, 0.f); r.y = fmaxf(a3.y, 0.f); r.z = fmaxf(a3.z, 0.f); r.w = fmaxf(a3.w, 0.f);
        *(float4*)&h4[(size_t)(g0 + 3) * 1024 + c0] = r;
    }
}

// ---------------- Head part 2: maxpool(16) -> fc1(relu) -> fc2 -> bn-ish ----
__global__ __launch_bounds__(256)
void head2_kernel(const float* __restrict__ h4,
                  const float* __restrict__ fc1w, const float* __restrict__ fc1b,
                  const float* __restrict__ fc2w, const float* __restrict__ fc2b,
                  const float* __restrict__ gamma, const float* __restrict__ beta,
                  float* __restrict__ out)
{
    const int b   = blockIdx.x;
    const int tid = threadIdx.x;
    __shared__ float gm[1024], g1[1024];
    {
        const int c0 = tid * 4;
        float4 m = *(const float4*)&h4[((size_t)b * 16 + 0) * 1024 + c0];
#pragma unroll
        for (int p = 1; p < 16; ++p) {
            const float4 v = *(const float4*)&h4[((size_t)b * 16 + p) * 1024 + c0];
            m.x = fmaxf(m.x, v.x); m.y = fmaxf(m.y, v.y);
            m.z = fmaxf(m.z, v.z); m.w = fmaxf(m.w, v.w);
        }
        *(float4*)&gm[c0] = m;
    }
    __syncthreads();
    {
        const int c0 = tid * 4;
        float4 a = *(const float4*)&fc1b[c0];
#pragma unroll 4
        for (int k = 0; k < 1024; ++k) {
            const float4 w = *(const float4*)&fc1w[(size_t)k * 1024 + c0];
            fma4(a, gm[k], w);
        }
        g1[c0 + 0] = fmaxf(a.x, 0.f); g1[c0 + 1] = fmaxf(a.y, 0.f);
        g1[c0 + 2] = fmaxf(a.z, 0.f); g1[c0 + 3] = fmaxf(a.w, 0.f);
    }
    __syncthreads();
    if (tid < 128) {
        const float s = sqrtf(1.00001f);
        const int c = tid;
        float a = fc2b[c];
#pragma unroll 4
        for (int k = 0; k < 1024; ++k) a = fmaf(g1[k], fc2w[(size_t)k * 128 + c], a);
        out[(size_t)b * 128 + c] = (a / s) * gamma[c] + beta[c];
    }
}

// ---------------------------------------------------------------------------
extern "C" void kernel_launch(void* const* d_in, const int* in_sizes, int n_in,
                              void* d_out, int out_size, void* d_ws, size_t ws_size,
                              hipStream_t stream)
{
    const float* pc   = (const float*)d_in[0];
    const float* w1a  = (const float*)d_in[1];  const float* b1a = (const float*)d_in[2];
    const float* w1b  = (const float*)d_in[3];  const float* b1b = (const float*)d_in[4];
    const float* w2a  = (const float*)d_in[5];  const float* b2a = (const float*)d_in[6];
    const float* w2b  = (const float*)d_in[7];  const float* b2b = (const float*)d_in[8];
    const float* w3a  = (const float*)d_in[9];  const float* b3a = (const float*)d_in[10];
    const float* w3b  = (const float*)d_in[11]; const float* b3b = (const float*)d_in[12];
    const float* w4a  = (const float*)d_in[13]; const float* b4a = (const float*)d_in[14];
    const float* w4b  = (const float*)d_in[15]; const float* b4b = (const float*)d_in[16];
    const float* fc1w = (const float*)d_in[17]; const float* fc1b = (const float*)d_in[18];
    const float* fc2w = (const float*)d_in[19]; const float* fc2b = (const float*)d_in[20];
    const float* gam  = (const float*)d_in[21]; const float* bet  = (const float*)d_in[22];
    float* out = (float*)d_out;

    char* ws = (char*)d_ws;
    size_t off = 0;
    auto alloc = [&](size_t bytes) -> void* {
        void* p = ws + off;
        off = (off + bytes + 255) & ~(size_t)255;
        return p;
    };
    float* nxyz1  = (float*)alloc((size_t)32 * 256 * 3 * 4);
    int*   gidx1  = (int*)  alloc((size_t)32 * 256 * 64 * 4);
    float* feats1 = (float*)alloc((size_t)32 * 256 * 128 * 4);
    float* nxyz2  = (float*)alloc((size_t)32 * 64 * 3 * 4);
    int*   gidx2  = (int*)  alloc((size_t)32 * 64 * 64 * 4);
    float* feats2 = (float*)alloc((size_t)32 * 64 * 256 * 4);
    float* nxyz3  = (float*)alloc((size_t)32 * 16 * 3 * 4);
    int*   gidx3  = (int*)  alloc((size_t)32 * 16 * 32 * 4);
    float* feats3 = (float*)alloc((size_t)32 * 16 * 512 * 4);
    float* h4     = (float*)alloc((size_t)32 * 16 * 1024 * 4);

    const float r2a = (float)(0.1 * 0.1);
    const float r2b = (float)(0.2 * 0.2);
    const float r2c = (float)(0.4 * 0.4);

    // ---- FPS: two batches per block (16 blocks), all 3 stages fused ----
    fps_fused2_kernel<<<16, 256, 0, stream>>>(pc, nxyz1, nxyz2, nxyz3);

    // ---- Ball queries ----
    bq_kernel<4096, 64, 6><<<(32 * 256 + 3) / 4, 256, 0, stream>>>(pc, nxyz1, gidx1, r2a, 256, 32 * 256);
    bq_kernel<256, 64, 3><<<(32 * 64 + 3) / 4, 256, 0, stream>>>(nxyz1, nxyz2, gidx2, r2b, 64, 32 * 64);
    bq_kernel<64, 32, 3><<<(32 * 16 + 3) / 4, 256, 0, stream>>>(nxyz2, nxyz3, gidx3, r2c, 16, 32 * 16);

    // ---- SA MLPs ----
    sa_mlp2_kernel<64, 9, 64, 128, 4096, 0><<<32 * 256, 256, 0, stream>>>(
        pc, pc, nxyz1, gidx1, w1a, b1a, w1b, b1b, feats1, 256);
    sa_mlp2_kernel<64, 131, 128, 256, 256, 1><<<32 * 64, 256, 0, stream>>>(
        nxyz1, feats1, nxyz2, gidx2, w2a, b2a, w2b, b2b, feats2, 64);
    sa_mlp2_kernel<32, 259, 256, 512, 64, 1><<<32 * 16, 256, 0, stream>>>(
        nxyz2, feats2, nxyz3, gidx3, w3a, b3a, w3b, b3b, feats3, 16);

    // ---- Head: 4 points per block (128 blocks), then maxpool+fc in head2
    head1_kernel<<<32 * 16 / 4, 256, 0, stream>>>(nxyz3, feats3, w4a, b4a, w4b, b4b, h4);
    head2_kernel<<<32, 256, 0, stream>>>(h4, fc1w, fc1b, fc2w, fc2b, gam, bet, out);
}

// Round 16
// 1018.339 us; speedup vs baseline: 1.2045x; 1.2045x over previous
//
#include <hip/hip_runtime.h>

#define DEV static __device__ __forceinline__

DEV float sqdist(float dx, float dy, float dz) {
    // ((dx*dx + dy*dy) + dz*dz) with no FMA contraction — must match numpy f32
    return __fadd_rn(__fadd_rn(__fmul_rn(dx, dx), __fmul_rn(dy, dy)), __fmul_rn(dz, dz));
}

DEV void fma4(float4& acc, float h, const float4& w) {
    acc.x = fmaf(h, w.x, acc.x); acc.y = fmaf(h, w.y, acc.y);
    acc.z = fmaf(h, w.z, acc.z); acc.w = fmaf(h, w.w, acc.w);
}

// ---- argmax combine steps (value desc, index asc on ties) ----
template<int CTRL>
DEV int dpp_mov(int v) {
    return __builtin_amdgcn_update_dpp(v, v, CTRL, 0xF, 0xF, false);
}
template<int CTRL>
DEV void red_step_dpp(float& bv, int& bi) {
    float ov = __builtin_bit_cast(float, dpp_mov<CTRL>(__builtin_bit_cast(int, bv)));
    int   oi = dpp_mov<CTRL>(bi);
    if (ov > bv || (ov == bv && oi < bi)) { bv = ov; bi = oi; }
}
// full 64-lane argmax; result valid in lane 63
DEV void wave_argmax(float& bv, int& bi) {
    red_step_dpp<0xB1>(bv, bi);    // quad_perm xor 1
    red_step_dpp<0x4E>(bv, bi);    // quad_perm xor 2
    red_step_dpp<0x141>(bv, bi);   // row_half_mirror (xor 4)
    red_step_dpp<0x140>(bv, bi);   // row_mirror (xor 8)
    red_step_dpp<0x142>(bv, bi);   // row_bcast15
    red_step_dpp<0x143>(bv, bi);   // row_bcast31 -> lane 63 has full result
}

// ---- single-wave FPS over LDS points (no barriers) ----
template<int N, int NPOINT>
DEV void fps_wave64(const float4* pts, float* sout, int lane) {
    constexpr int K = (N + 63) / 64;
    float rx[K], ry[K], rz[K], d[K];
#pragma unroll
    for (int k = 0; k < K; ++k) {
        const float4 c = pts[lane + k * 64];
        rx[k] = c.x; ry[k] = c.y; rz[k] = c.z; d[k] = 1e10f;
    }
    const float4 c0 = pts[0];
    float cx = c0.x, cy = c0.y, cz = c0.z;
    for (int s = 0; s < NPOINT; ++s) {
        if (lane == 0) { sout[s * 3 + 0] = cx; sout[s * 3 + 1] = cy; sout[s * 3 + 2] = cz; }
        float bestv = -1.0f; int besti = 0x7fffffff;
#pragma unroll
        for (int k = 0; k < K; ++k) {
            float d2 = sqdist(rx[k] - cx, ry[k] - cy, rz[k] - cz);
            d[k] = fminf(d[k], d2);
            if (d[k] > bestv) { bestv = d[k]; besti = lane + k * 64; }
        }
        wave_argmax(bestv, besti);
        const int far = __builtin_amdgcn_readlane(besti, 63);
        const float4 c = pts[far];
        cx = c.x; cy = c.y; cz = c.z;
    }
}

// ---------------- Fused FPS (all 3 stages) — measured-floor config ----
// 4 waves / 1 barrier per step (measured minimum over {1w,4w,8w,spin,2-batch}).
__global__ __launch_bounds__(256)
void fps_fused_kernel(const float* __restrict__ pc,
                      float* __restrict__ nxyz1, float* __restrict__ nxyz2,
                      float* __restrict__ nxyz3)
{
    constexpr int N1 = 4096, NP1 = 256, NP2 = 64, NP3 = 16, T = 256, NW = T / 64;
    constexpr int K = N1 / T;
    __shared__ float4 pxyz[N1];
    __shared__ float  sout1[NP1 * 3];
    __shared__ float  sout2[NP2 * 3];
    __shared__ float  sout3[NP3 * 3];
    __shared__ float  rv[2][NW];
    __shared__ int    ri[2][NW];

    const int b = blockIdx.x, tid = threadIdx.x;
    const int w = tid >> 6, lane = tid & 63;
    const float* base = pc + (size_t)b * N1 * 6;

    float rx[K], ry[K], rz[K], d[K];
#pragma unroll
    for (int k = 0; k < K; ++k) {
        const int p = tid + k * T;
        const float x = base[p * 6 + 0];
        const float y = base[p * 6 + 1];
        const float z = base[p * 6 + 2];
        pxyz[p] = make_float4(x, y, z, 0.f);
        rx[k] = x; ry[k] = y; rz[k] = z;
        d[k] = 1e10f;
    }
    __syncthreads();

    // ---- stage 1 ----
    {
        const float4 c0 = pxyz[0];
        float cx = c0.x, cy = c0.y, cz = c0.z;
        for (int s = 0; s < NP1; ++s) {
            if (tid == 0) { sout1[s * 3 + 0] = cx; sout1[s * 3 + 1] = cy; sout1[s * 3 + 2] = cz; }
            float bestv = -1.0f; int besti = 0x7fffffff;
#pragma unroll
            for (int k = 0; k < K; ++k) {
                float d2 = sqdist(rx[k] - cx, ry[k] - cy, rz[k] - cz);
                d[k] = fminf(d[k], d2);
                if (d[k] > bestv) { bestv = d[k]; besti = tid + k * T; }  // k asc => lowest p
            }
            wave_argmax(bestv, besti);

            const int par = s & 1;
            if (lane == 63) { rv[par][w] = bestv; ri[par][w] = besti; }
            __syncthreads();
            float bvv = rv[par][0]; int bii = ri[par][0];
#pragma unroll
            for (int q = 1; q < NW; ++q) {
                const float qv = rv[par][q]; const int qi = ri[par][q];
                if (qv > bvv || (qv == bvv && qi < bii)) { bvv = qv; bii = qi; }
            }
            const float4 c = pxyz[bii];
            cx = c.x; cy = c.y; cz = c.z;
        }
    }

    // ---- stages 2 + 3 on wave 0 ----
    if (w == 0) {
        for (int i = lane; i < NP1; i += 64)
            pxyz[i] = make_float4(sout1[i * 3 + 0], sout1[i * 3 + 1], sout1[i * 3 + 2], 0.f);
        fps_wave64<NP1, NP2>(pxyz, sout2, lane);
        for (int i = lane; i < NP2; i += 64)
            pxyz[i] = make_float4(sout2[i * 3 + 0], sout2[i * 3 + 1], sout2[i * 3 + 2], 0.f);
        fps_wave64<NP2, NP3>(pxyz, sout3, lane);
    }
    __syncthreads();

    float* o1 = nxyz1 + (size_t)b * NP1 * 3;
    for (int i = tid; i < NP1 * 3; i += T) o1[i] = sout1[i];
    float* o2 = nxyz2 + (size_t)b * NP2 * 3;
    if (tid < NP2 * 3) o2[tid] = sout2[tid];
    float* o3 = nxyz3 + (size_t)b * NP3 * 3;
    if (tid < NP3 * 3) o3[tid] = sout3[tid];
}

// ---------------- Ball query -----------------
template<int N, int NSAMP, int STRIDE>
__global__ __launch_bounds__(256)
void bq_kernel(const float* __restrict__ xyz, const float* __restrict__ newxyz,
               int* __restrict__ gidx, float r2, int S, int total)
{
    const int wid = blockIdx.x * 4 + (threadIdx.x >> 6);
    if (wid >= total) return;
    const int lane = threadIdx.x & 63;
    const int b = wid / S;
    const float cx = newxyz[(size_t)wid * 3 + 0];
    const float cy = newxyz[(size_t)wid * 3 + 1];
    const float cz = newxyz[(size_t)wid * 3 + 2];
    const float* base = xyz + (size_t)b * N * STRIDE;
    int* out = gidx + (size_t)wid * NSAMP;

    int count = 0, first = N - 1;
    constexpr int NCH = (N + 63) / 64;
    for (int ch = 0; ch < NCH; ++ch) {
        int p = ch * 64 + lane;
        bool pred = false;
        if (N % 64 == 0 || p < N) {
            float dx = base[p * STRIDE + 0] - cx;
            float dy = base[p * STRIDE + 1] - cy;
            float dz = base[p * STRIDE + 2] - cz;
            pred = sqdist(dx, dy, dz) < r2;
        }
        unsigned long long m = __ballot(pred);
        if (m) {
            if (count == 0) first = ch * 64 + __builtin_ctzll(m);
            int pos = count + __popcll(m & ((1ull << lane) - 1ull));
            if (pred && pos < NSAMP) out[pos] = p;
            count += __popcll(m);
            if (count >= NSAMP) break;
        }
    }
    if (count > NSAMP) count = NSAMP;
    for (int pos = count + lane; pos < NSAMP; pos += 64) out[pos] = first;
}

// ---------------- Grouped 2-layer MLP + maxpool -----------------
// MODE 0: stage1 (xyz stride 6, feats = pc permuted). MODE 1: feats array.
// Phase B: unified CHB=4 register tile, PTSB = NS/GRP points per thread with
// GRP = T/(C2/4) parallel groups — minimizes per-block W2 re-streaming
// (the confirmed R11 mechanism).
template<int NS, int CIN, int C1, int C2, int NSRC, int MODE>
__global__ __launch_bounds__(256)
void sa_mlp2_kernel(const float* __restrict__ sxyz, const float* __restrict__ sfeat,
                    const float* __restrict__ newxyz, const int* __restrict__ gidx,
                    const float* __restrict__ W1, const float* __restrict__ B1v,
                    const float* __restrict__ W2, const float* __restrict__ B2v,
                    float* __restrict__ outf, int S)
{
    constexpr int T    = 256;
    constexpr int KCC  = (CIN < 32) ? CIN : 32;            // k-chunk length
    constexpr int KCP0 = ((KCC + 3) / 4) * 4 + 4;
    constexpr int KCP  = ((KCP0 / 4) % 2 == 0) ? KCP0 + 4 : KCP0;  // odd quad stride
    constexpr int NPT  = NS / 4;
    constexpr int NCT1 = C1 / 4;
    constexpr int TPT  = (NPT * NCT1) / T;                 // phase-A tiles per thread
    constexpr int C1P  = C1 + 4;
    constexpr int CT2  = C2 / 4;                           // phase-B: 4 channels/thread
    constexpr int GRP  = T / CT2;                          // parallel point-groups
    constexpr int PTSB = NS / GRP;                         // points per thread
    constexpr int XS   = (MODE == 0) ? 6 : 3;
    constexpr int CF   = CIN - 3;
    static_assert(NS % 4 == 0 && C1 % 4 == 0 && C2 % 4 == 0, "");
    static_assert((NPT * NCT1) % T == 0 && TPT >= 1, "");
    static_assert(T % CT2 == 0 && NS % GRP == 0 && PTSB >= 1, "");

    __shared__ float xgc[NS][KCP];
    __shared__ __align__(16) float h1s[NS][C1P];
    __shared__ int   gix[NS];
    __shared__ float mpart[(GRP > 1) ? GRP * C2 : 4];

    const int g   = blockIdx.x;
    const int b   = g / S;
    const int tid = threadIdx.x;

    float ctr0 = 0.f, ctr1 = 0.f, ctr2 = 0.f;
    ctr0 = newxyz[(size_t)g * 3 + 0];
    ctr1 = newxyz[(size_t)g * 3 + 1];
    ctr2 = newxyz[(size_t)g * 3 + 2];
    for (int i = tid; i < NS; i += T) gix[i] = gidx[(size_t)g * NS + i];
    __syncthreads();

    // ---- Phase A: layer 1, K-chunked, accumulators in registers ----
    float4 acc[TPT][4];
#pragma unroll
    for (int j = 0; j < TPT; ++j) {
        const int tl = tid + j * T;
        const int ct = tl % NCT1;
        const float4 bb = *(const float4*)&B1v[ct * 4];
#pragma unroll
        for (int i = 0; i < 4; ++i) acc[j][i] = bb;
    }

    const int nchunk = (CIN + KCC - 1) / KCC;
    for (int cch = 0; cch < nchunk; ++cch) {
        const int k0 = cch * KCC;
        const int kcLen = (CIN - k0 < KCC) ? (CIN - k0) : KCC;
        if (cch > 0) __syncthreads();
        // gather chunk
        for (int idx = tid; idx < NS * kcLen; idx += T) {
            const int p = idx / kcLen, kk = idx - p * kcLen, k = k0 + kk;
            float v;
            const int gi = gix[p];
            if (k < 3) {
                const float c = (k == 0) ? ctr0 : ((k == 1) ? ctr1 : ctr2);
                v = sxyz[((size_t)b * NSRC + gi) * XS + k] - c;
            } else if constexpr (MODE == 0) {
                const int j2 = k - 3;
                v = sfeat[((size_t)b * NSRC + gi) * 6 + (j2 < 3 ? 3 + j2 : j2 - 3)];
            } else {
                v = sfeat[((size_t)b * NSRC + gi) * CF + (k - 3)];
            }
            xgc[p][kk] = v;
        }
        __syncthreads();
        // compute chunk
#pragma unroll
        for (int j = 0; j < TPT; ++j) {
            const int tl = tid + j * T;
            const int pt = tl / NCT1, ct = tl % NCT1;
            const int p0 = pt * 4, c0 = ct * 4;
            int kk = 0;
            for (; kk + 4 <= kcLen; kk += 4) {
                const float4 xa = *(const float4*)&xgc[p0 + 0][kk];
                const float4 xb = *(const float4*)&xgc[p0 + 1][kk];
                const float4 xc = *(const float4*)&xgc[p0 + 2][kk];
                const float4 xd = *(const float4*)&xgc[p0 + 3][kk];
                const float4 w0 = *(const float4*)&W1[(size_t)(k0 + kk + 0) * C1 + c0];
                const float4 w1 = *(const float4*)&W1[(size_t)(k0 + kk + 1) * C1 + c0];
                const float4 w2 = *(const float4*)&W1[(size_t)(k0 + kk + 2) * C1 + c0];
                const float4 w3 = *(const float4*)&W1[(size_t)(k0 + kk + 3) * C1 + c0];
                fma4(acc[j][0], xa.x, w0); fma4(acc[j][0], xa.y, w1); fma4(acc[j][0], xa.z, w2); fma4(acc[j][0], xa.w, w3);
                fma4(acc[j][1], xb.x, w0); fma4(acc[j][1], xb.y, w1); fma4(acc[j][1], xb.z, w2); fma4(acc[j][1], xb.w, w3);
                fma4(acc[j][2], xc.x, w0); fma4(acc[j][2], xc.y, w1); fma4(acc[j][2], xc.z, w2); fma4(acc[j][2], xc.w, w3);
                fma4(acc[j][3], xd.x, w0); fma4(acc[j][3], xd.y, w1); fma4(acc[j][3], xd.z, w2); fma4(acc[j][3], xd.w, w3);
            }
            for (; kk < kcLen; ++kk) {
                const float4 w = *(const float4*)&W1[(size_t)(k0 + kk) * C1 + c0];
                fma4(acc[j][0], xgc[p0 + 0][kk], w);
                fma4(acc[j][1], xgc[p0 + 1][kk], w);
                fma4(acc[j][2], xgc[p0 + 2][kk], w);
                fma4(acc[j][3], xgc[p0 + 3][kk], w);
            }
        }
    }
    // write h1 (relu)
    __syncthreads();
#pragma unroll
    for (int j = 0; j < TPT; ++j) {
        const int tl = tid + j * T;
        const int pt = tl / NCT1, ct = tl % NCT1;
        const int p0 = pt * 4, c0 = ct * 4;
#pragma unroll
        for (int i = 0; i < 4; ++i) {
            float4 r;
            r.x = fmaxf(acc[j][i].x, 0.f); r.y = fmaxf(acc[j][i].y, 0.f);
            r.z = fmaxf(acc[j][i].z, 0.f); r.w = fmaxf(acc[j][i].w, 0.f);
            *(float4*)&h1s[p0 + i][c0] = r;
        }
    }
    __syncthreads();

    // ---- Phase B: layer 2 + maxpool, PTSB pts x 4 ch per thread ----
    {
        const int ct = tid % CT2, pb = tid / CT2;
        const int c0 = ct * 4;
        const int p0 = pb * PTSB;
        const float4 bb = *(const float4*)&B2v[c0];
        float4 ac[PTSB];
#pragma unroll
        for (int i = 0; i < PTSB; ++i) ac[i] = bb;
#pragma unroll 2
        for (int k = 0; k < C1; k += 4) {
            const float4 w0 = *(const float4*)&W2[(size_t)(k + 0) * C2 + c0];
            const float4 w1 = *(const float4*)&W2[(size_t)(k + 1) * C2 + c0];
            const float4 w2 = *(const float4*)&W2[(size_t)(k + 2) * C2 + c0];
            const float4 w3 = *(const float4*)&W2[(size_t)(k + 3) * C2 + c0];
#pragma unroll
            for (int i = 0; i < PTSB; ++i) {
                const float4 h = *(const float4*)&h1s[p0 + i][k];
                fma4(ac[i], h.x, w0); fma4(ac[i], h.y, w1);
                fma4(ac[i], h.z, w2); fma4(ac[i], h.w, w3);
            }
        }
        float4 m = make_float4(0.f, 0.f, 0.f, 0.f);   // relu>=0
#pragma unroll
        for (int i = 0; i < PTSB; ++i) {
            m.x = fmaxf(m.x, ac[i].x); m.y = fmaxf(m.y, ac[i].y);
            m.z = fmaxf(m.z, ac[i].z); m.w = fmaxf(m.w, ac[i].w);
        }
        if constexpr (GRP == 1) {
            *(float4*)&outf[(size_t)g * C2 + c0] = m;
        } else {
            *(float4*)&mpart[pb * C2 + c0] = m;
            __syncthreads();
            for (int c = tid; c < C2; c += T) {
                float mm = mpart[c];
#pragma unroll
                for (int q = 1; q < GRP; ++q) mm = fmaxf(mm, mpart[q * C2 + c]);
                outf[(size_t)g * C2 + c] = mm;
            }
        }
    }
}

// ---------------- Head part 1: 4 points per block, 515->512->1024 MLP ----
__global__ __launch_bounds__(256)
void head1_kernel(const float* __restrict__ nxyz3, const float* __restrict__ feats3,
                  const float* __restrict__ w4a, const float* __restrict__ b4a,
                  const float* __restrict__ w4b, const float* __restrict__ b4b,
                  float* __restrict__ h4)
{
    const int g0  = blockIdx.x * 4;   // 4 consecutive (b,point) groups
    const int tid = threadIdx.x;
    __shared__ float xrow[4][516];
    __shared__ float h1s[4][512];
    for (int i = tid; i < 4 * 515; i += 256) {
        const int p = i / 515, k = i - p * 515;
        xrow[p][k] = (k < 3) ? nxyz3[(size_t)(g0 + p) * 3 + k]
                             : feats3[(size_t)(g0 + p) * 512 + (k - 3)];
    }
    __syncthreads();
#pragma unroll
    for (int cc = 0; cc < 2; ++cc) {
        const int c = tid + cc * 256;
        const float bb = b4a[c];
        float a0 = bb, a1 = bb, a2 = bb, a3 = bb;
#pragma unroll 4
        for (int k = 0; k < 515; ++k) {
            const float w = w4a[(size_t)k * 512 + c];
            a0 = fmaf(xrow[0][k], w, a0);
            a1 = fmaf(xrow[1][k], w, a1);
            a2 = fmaf(xrow[2][k], w, a2);
            a3 = fmaf(xrow[3][k], w, a3);
        }
        h1s[0][c] = fmaxf(a0, 0.f); h1s[1][c] = fmaxf(a1, 0.f);
        h1s[2][c] = fmaxf(a2, 0.f); h1s[3][c] = fmaxf(a3, 0.f);
    }
    __syncthreads();
    {
        const int c0 = tid * 4;
        const float4 bb = *(const float4*)&b4b[c0];
        float4 a0 = bb, a1 = bb, a2 = bb, a3 = bb;
#pragma unroll 4
        for (int k = 0; k < 512; ++k) {
            const float4 w = *(const float4*)&w4b[(size_t)k * 1024 + c0];
            fma4(a0, h1s[0][k], w);
            fma4(a1, h1s[1][k], w);
            fma4(a2, h1s[2][k], w);
            fma4(a3, h1s[3][k], w);
        }
        float4 r;
        r.x = fmaxf(a0.x, 0.f); r.y = fmaxf(a0.y, 0.f); r.z = fmaxf(a0.z, 0.f); r.w = fmaxf(a0.w, 0.f);
        *(float4*)&h4[(size_t)(g0 + 0) * 1024 + c0] = r;
        r.x = fmaxf(a1.x, 0.f); r.y = fmaxf(a1.y, 0.f); r.z = fmaxf(a1.z, 0.f); r.w = fmaxf(a1.w, 0.f);
        *(float4*)&h4[(size_t)(g0 + 1) * 1024 + c0] = r;
        r.x = fmaxf(a2.x, 0.f); r.y = fmaxf(a2.y, 0.f); r.z = fmaxf(a2.z, 0.f); r.w = fmaxf(a2.w, 0.f);
        *(float4*)&h4[(size_t)(g0 + 2) * 1024 + c0] = r;
        r.x = fmaxf(a3.x, 0.f); r.y = fmaxf(a3.y, 0.f); r.z = fmaxf(a3.z, 0.f); r.w = fmaxf(a3.w, 0.f);
        *(float4*)&h4[(size_t)(g0 + 3) * 1024 + c0] = r;
    }
}

// ---------------- Head part 2: maxpool(16) -> fc1(relu) -> fc2 -> bn-ish ----
__global__ __launch_bounds__(256)
void head2_kernel(const float* __restrict__ h4,
                  const float* __restrict__ fc1w, const float* __restrict__ fc1b,
                  const float* __restrict__ fc2w, const float* __restrict__ fc2b,
                  const float* __restrict__ gamma, const float* __restrict__ beta,
                  float* __restrict__ out)
{
    const int b   = blockIdx.x;
    const int tid = threadIdx.x;
    __shared__ float gm[1024], g1[1024];
    {
        const int c0 = tid * 4;
        float4 m = *(const float4*)&h4[((size_t)b * 16 + 0) * 1024 + c0];
#pragma unroll
        for (int p = 1; p < 16; ++p) {
            const float4 v = *(const float4*)&h4[((size_t)b * 16 + p) * 1024 + c0];
            m.x = fmaxf(m.x, v.x); m.y = fmaxf(m.y, v.y);
            m.z = fmaxf(m.z, v.z); m.w = fmaxf(m.w, v.w);
        }
        *(float4*)&gm[c0] = m;
    }
    __syncthreads();
    {
        const int c0 = tid * 4;
        float4 a = *(const float4*)&fc1b[c0];
#pragma unroll 4
        for (int k = 0; k < 1024; ++k) {
            const float4 w = *(const float4*)&fc1w[(size_t)k * 1024 + c0];
            fma4(a, gm[k], w);
        }
        g1[c0 + 0] = fmaxf(a.x, 0.f); g1[c0 + 1] = fmaxf(a.y, 0.f);
        g1[c0 + 2] = fmaxf(a.z, 0.f); g1[c0 + 3] = fmaxf(a.w, 0.f);
    }
    __syncthreads();
    if (tid < 128) {
        const float s = sqrtf(1.00001f);
        const int c = tid;
        float a = fc2b[c];
#pragma unroll 4
        for (int k = 0; k < 1024; ++k) a = fmaf(g1[k], fc2w[(size_t)k * 128 + c], a);
        out[(size_t)b * 128 + c] = (a / s) * gamma[c] + beta[c];
    }
}

// ---------------------------------------------------------------------------
extern "C" void kernel_launch(void* const* d_in, const int* in_sizes, int n_in,
                              void* d_out, int out_size, void* d_ws, size_t ws_size,
                              hipStream_t stream)
{
    const float* pc   = (const float*)d_in[0];
    const float* w1a  = (const float*)d_in[1];  const float* b1a = (const float*)d_in[2];
    const float* w1b  = (const float*)d_in[3];  const float* b1b = (const float*)d_in[4];
    const float* w2a  = (const float*)d_in[5];  const float* b2a = (const float*)d_in[6];
    const float* w2b  = (const float*)d_in[7];  const float* b2b = (const float*)d_in[8];
    const float* w3a  = (const float*)d_in[9];  const float* b3a = (const float*)d_in[10];
    const float* w3b  = (const float*)d_in[11]; const float* b3b = (const float*)d_in[12];
    const float* w4a  = (const float*)d_in[13]; const float* b4a = (const float*)d_in[14];
    const float* w4b  = (const float*)d_in[15]; const float* b4b = (const float*)d_in[16];
    const float* fc1w = (const float*)d_in[17]; const float* fc1b = (const float*)d_in[18];
    const float* fc2w = (const float*)d_in[19]; const float* fc2b = (const float*)d_in[20];
    const float* gam  = (const float*)d_in[21]; const float* bet  = (const float*)d_in[22];
    float* out = (float*)d_out;

    char* ws = (char*)d_ws;
    size_t off = 0;
    auto alloc = [&](size_t bytes) -> void* {
        void* p = ws + off;
        off = (off + bytes + 255) & ~(size_t)255;
        return p;
    };
    float* nxyz1  = (float*)alloc((size_t)32 * 256 * 3 * 4);
    int*   gidx1  = (int*)  alloc((size_t)32 * 256 * 64 * 4);
    float* feats1 = (float*)alloc((size_t)32 * 256 * 128 * 4);
    float* nxyz2  = (float*)alloc((size_t)32 * 64 * 3 * 4);
    int*   gidx2  = (int*)  alloc((size_t)32 * 64 * 64 * 4);
    float* feats2 = (float*)alloc((size_t)32 * 64 * 256 * 4);
    float* nxyz3  = (float*)alloc((size_t)32 * 16 * 3 * 4);
    int*   gidx3  = (int*)  alloc((size_t)32 * 16 * 32 * 4);
    float* feats3 = (float*)alloc((size_t)32 * 16 * 512 * 4);
    float* h4     = (float*)alloc((size_t)32 * 16 * 1024 * 4);

    const float r2a = (float)(0.1 * 0.1);
    const float r2b = (float)(0.2 * 0.2);
    const float r2c = (float)(0.4 * 0.4);

    // ---- All three FPS stages fused (one block per batch, 4-wave config) ----
    fps_fused_kernel<<<32, 256, 0, stream>>>(pc, nxyz1, nxyz2, nxyz3);

    // ---- Ball queries ----
    bq_kernel<4096, 64, 6><<<(32 * 256 + 3) / 4, 256, 0, stream>>>(pc, nxyz1, gidx1, r2a, 256, 32 * 256);
    bq_kernel<256, 64, 3><<<(32 * 64 + 3) / 4, 256, 0, stream>>>(nxyz1, nxyz2, gidx2, r2b, 64, 32 * 64);
    bq_kernel<64, 32, 3><<<(32 * 16 + 3) / 4, 256, 0, stream>>>(nxyz2, nxyz3, gidx3, r2c, 16, 32 * 16);

    // ---- SA MLPs ----
    sa_mlp2_kernel<64, 9, 64, 128, 4096, 0><<<32 * 256, 256, 0, stream>>>(
        pc, pc, nxyz1, gidx1, w1a, b1a, w1b, b1b, feats1, 256);
    sa_mlp2_kernel<64, 131, 128, 256, 256, 1><<<32 * 64, 256, 0, stream>>>(
        nxyz1, feats1, nxyz2, gidx2, w2a, b2a, w2b, b2b, feats2, 64);
    sa_mlp2_kernel<32, 259, 256, 512, 64, 1><<<32 * 16, 256, 0, stream>>>(
        nxyz2, feats2, nxyz3, gidx3, w3a, b3a, w3b, b3b, feats3, 16);

    // ---- Head: 4 points per block (128 blocks), then maxpool+fc in head2
    head1_kernel<<<32 * 16 / 4, 256, 0, stream>>>(nxyz3, feats3, w4a, b4a, w4b, b4b, h4);
    head2_kernel<<<32, 256, 0, stream>>>(h4, fc1w, fc1b, fc2w, fc2b, gam, bet, out);
}

// Round 17
// 937.542 us; speedup vs baseline: 1.3083x; 1.0862x over previous
//
#include <hip/hip_runtime.h>

#define DEV static __device__ __forceinline__

using bf16x8 = __attribute__((ext_vector_type(8))) short;   // 8 bf16 (4 VGPRs)
using f32x4  = __attribute__((ext_vector_type(4))) float;

DEV float sqdist(float dx, float dy, float dz) {
    // ((dx*dx + dy*dy) + dz*dz) with no FMA contraction — must match numpy f32
    return __fadd_rn(__fadd_rn(__fmul_rn(dx, dx), __fmul_rn(dy, dy)), __fmul_rn(dz, dz));
}

DEV void fma4(float4& acc, float h, const float4& w) {
    acc.x = fmaf(h, w.x, acc.x); acc.y = fmaf(h, w.y, acc.y);
    acc.z = fmaf(h, w.z, acc.z); acc.w = fmaf(h, w.w, acc.w);
}

DEV unsigned short f2bf_rne(float f) {   // fp32 -> bf16, round-nearest-even
    unsigned u = __builtin_bit_cast(unsigned, f);
    return (unsigned short)((u + 0x7FFFu + ((u >> 16) & 1u)) >> 16);
}

// ---- argmax combine steps (value desc, index asc on ties) ----
template<int CTRL>
DEV int dpp_mov(int v) {
    return __builtin_amdgcn_update_dpp(v, v, CTRL, 0xF, 0xF, false);
}
template<int CTRL>
DEV void red_step_dpp(float& bv, int& bi) {
    float ov = __builtin_bit_cast(float, dpp_mov<CTRL>(__builtin_bit_cast(int, bv)));
    int   oi = dpp_mov<CTRL>(bi);
    if (ov > bv || (ov == bv && oi < bi)) { bv = ov; bi = oi; }
}
// full 64-lane argmax; result valid in lane 63
DEV void wave_argmax(float& bv, int& bi) {
    red_step_dpp<0xB1>(bv, bi);    // quad_perm xor 1
    red_step_dpp<0x4E>(bv, bi);    // quad_perm xor 2
    red_step_dpp<0x141>(bv, bi);   // row_half_mirror (xor 4)
    red_step_dpp<0x140>(bv, bi);   // row_mirror (xor 8)
    red_step_dpp<0x142>(bv, bi);   // row_bcast15
    red_step_dpp<0x143>(bv, bi);   // row_bcast31 -> lane 63 has full result
}

// ---- single-wave FPS over LDS points (no barriers) ----
template<int N, int NPOINT>
DEV void fps_wave64(const float4* pts, float* sout, int lane) {
    constexpr int K = (N + 63) / 64;
    float rx[K], ry[K], rz[K], d[K];
#pragma unroll
    for (int k = 0; k < K; ++k) {
        const float4 c = pts[lane + k * 64];
        rx[k] = c.x; ry[k] = c.y; rz[k] = c.z; d[k] = 1e10f;
    }
    const float4 c0 = pts[0];
    float cx = c0.x, cy = c0.y, cz = c0.z;
    for (int s = 0; s < NPOINT; ++s) {
        if (lane == 0) { sout[s * 3 + 0] = cx; sout[s * 3 + 1] = cy; sout[s * 3 + 2] = cz; }
        float bestv = -1.0f; int besti = 0x7fffffff;
#pragma unroll
        for (int k = 0; k < K; ++k) {
            float d2 = sqdist(rx[k] - cx, ry[k] - cy, rz[k] - cz);
            d[k] = fminf(d[k], d2);
            if (d[k] > bestv) { bestv = d[k]; besti = lane + k * 64; }
        }
        wave_argmax(bestv, besti);
        const int far = __builtin_amdgcn_readlane(besti, 63);
        const float4 c = pts[far];
        cx = c.x; cy = c.y; cz = c.z;
    }
}

// ---------------- Fused FPS (all 3 stages) — measured-floor config ----
__global__ __launch_bounds__(256)
void fps_fused_kernel(const float* __restrict__ pc,
                      float* __restrict__ nxyz1, float* __restrict__ nxyz2,
                      float* __restrict__ nxyz3)
{
    constexpr int N1 = 4096, NP1 = 256, NP2 = 64, NP3 = 16, T = 256, NW = T / 64;
    constexpr int K = N1 / T;
    __shared__ float4 pxyz[N1];
    __shared__ float  sout1[NP1 * 3];
    __shared__ float  sout2[NP2 * 3];
    __shared__ float  sout3[NP3 * 3];
    __shared__ float  rv[2][NW];
    __shared__ int    ri[2][NW];

    const int b = blockIdx.x, tid = threadIdx.x;
    const int w = tid >> 6, lane = tid & 63;
    const float* base = pc + (size_t)b * N1 * 6;

    float rx[K], ry[K], rz[K], d[K];
#pragma unroll
    for (int k = 0; k < K; ++k) {
        const int p = tid + k * T;
        const float x = base[p * 6 + 0];
        const float y = base[p * 6 + 1];
        const float z = base[p * 6 + 2];
        pxyz[p] = make_float4(x, y, z, 0.f);
        rx[k] = x; ry[k] = y; rz[k] = z;
        d[k] = 1e10f;
    }
    __syncthreads();

    // ---- stage 1 ----
    {
        const float4 c0 = pxyz[0];
        float cx = c0.x, cy = c0.y, cz = c0.z;
        for (int s = 0; s < NP1; ++s) {
            if (tid == 0) { sout1[s * 3 + 0] = cx; sout1[s * 3 + 1] = cy; sout1[s * 3 + 2] = cz; }
            float bestv = -1.0f; int besti = 0x7fffffff;
#pragma unroll
            for (int k = 0; k < K; ++k) {
                float d2 = sqdist(rx[k] - cx, ry[k] - cy, rz[k] - cz);
                d[k] = fminf(d[k], d2);
                if (d[k] > bestv) { bestv = d[k]; besti = tid + k * T; }  // k asc => lowest p
            }
            wave_argmax(bestv, besti);

            const int par = s & 1;
            if (lane == 63) { rv[par][w] = bestv; ri[par][w] = besti; }
            __syncthreads();
            float bvv = rv[par][0]; int bii = ri[par][0];
#pragma unroll
            for (int q = 1; q < NW; ++q) {
                const float qv = rv[par][q]; const int qi = ri[par][q];
                if (qv > bvv || (qv == bvv && qi < bii)) { bvv = qv; bii = qi; }
            }
            const float4 c = pxyz[bii];
            cx = c.x; cy = c.y; cz = c.z;
        }
    }

    // ---- stages 2 + 3 on wave 0 ----
    if (w == 0) {
        for (int i = lane; i < NP1; i += 64)
            pxyz[i] = make_float4(sout1[i * 3 + 0], sout1[i * 3 + 1], sout1[i * 3 + 2], 0.f);
        fps_wave64<NP1, NP2>(pxyz, sout2, lane);
        for (int i = lane; i < NP2; i += 64)
            pxyz[i] = make_float4(sout2[i * 3 + 0], sout2[i * 3 + 1], sout2[i * 3 + 2], 0.f);
        fps_wave64<NP2, NP3>(pxyz, sout3, lane);
    }
    __syncthreads();

    float* o1 = nxyz1 + (size_t)b * NP1 * 3;
    for (int i = tid; i < NP1 * 3; i += T) o1[i] = sout1[i];
    float* o2 = nxyz2 + (size_t)b * NP2 * 3;
    if (tid < NP2 * 3) o2[tid] = sout2[tid];
    float* o3 = nxyz3 + (size_t)b * NP3 * 3;
    if (tid < NP3 * 3) o3[tid] = sout3[tid];
}

// ---------------- Ball query -----------------
template<int N, int NSAMP, int STRIDE>
__global__ __launch_bounds__(256)
void bq_kernel(const float* __restrict__ xyz, const float* __restrict__ newxyz,
               int* __restrict__ gidx, float r2, int S, int total)
{
    const int wid = blockIdx.x * 4 + (threadIdx.x >> 6);
    if (wid >= total) return;
    const int lane = threadIdx.x & 63;
    const int b = wid / S;
    const float cx = newxyz[(size_t)wid * 3 + 0];
    const float cy = newxyz[(size_t)wid * 3 + 1];
    const float cz = newxyz[(size_t)wid * 3 + 2];
    const float* base = xyz + (size_t)b * N * STRIDE;
    int* out = gidx + (size_t)wid * NSAMP;

    int count = 0, first = N - 1;
    constexpr int NCH = (N + 63) / 64;
    for (int ch = 0; ch < NCH; ++ch) {
        int p = ch * 64 + lane;
        bool pred = false;
        if (N % 64 == 0 || p < N) {
            float dx = base[p * STRIDE + 0] - cx;
            float dy = base[p * STRIDE + 1] - cy;
            float dz = base[p * STRIDE + 2] - cz;
            pred = sqdist(dx, dy, dz) < r2;
        }
        unsigned long long m = __ballot(pred);
        if (m) {
            if (count == 0) first = ch * 64 + __builtin_ctzll(m);
            int pos = count + __popcll(m & ((1ull << lane) - 1ull));
            if (pred && pos < NSAMP) out[pos] = p;
            count += __popcll(m);
            if (count >= NSAMP) break;
        }
    }
    if (count > NSAMP) count = NSAMP;
    for (int pos = count + lane; pos < NSAMP; pos += 64) out[pos] = first;
}

// ---------------- Grouped 2-layer MLP + maxpool -----------------
// MODE 0: stage1 (xyz stride 6, feats = pc permuted). MODE 1: feats array.
// MFMAB: phase B via mfma_f32_16x16x32_bf16 (bf16 inputs, fp32 accumulate),
// fused bias-init + maxpool via shfl_xor; requires T=256, NS%16==0,
// C1%32==0, C2%64==0.
template<int NS, int CIN, int C1, int C2, int NSRC, int MODE, bool MFMAB = false>
__global__ __launch_bounds__(256)
void sa_mlp2_kernel(const float* __restrict__ sxyz, const float* __restrict__ sfeat,
                    const float* __restrict__ newxyz, const int* __restrict__ gidx,
                    const float* __restrict__ W1, const float* __restrict__ B1v,
                    const float* __restrict__ W2, const float* __restrict__ B2v,
                    float* __restrict__ outf, int S)
{
    constexpr int T    = 256;
    constexpr int KCC  = (CIN < 32) ? CIN : 32;            // k-chunk length
    constexpr int KCP0 = ((KCC + 3) / 4) * 4 + 4;
    constexpr int KCP  = ((KCP0 / 4) % 2 == 0) ? KCP0 + 4 : KCP0;  // odd quad stride
    constexpr int NPT  = NS / 4;
    constexpr int NCT1 = C1 / 4;
    constexpr int TPT  = (NPT * NCT1) / T;                 // phase-A tiles per thread
    constexpr int C1P  = C1 + 4;
    constexpr int LDHB = C1 + 8;                           // bf16 h1 row stride (16B mult)
    constexpr int CT2  = C2 / 4;                           // fp32 phase-B: 4 ch/thread
    constexpr int GRP  = T / CT2;
    constexpr int PTSB = NS / GRP;
    constexpr int XS   = (MODE == 0) ? 6 : 3;
    constexpr int CF   = CIN - 3;
    constexpr size_t H1B = MFMAB ? (size_t)NS * LDHB * 2 : (size_t)NS * C1P * 4;
    constexpr int MPSZ = (!MFMAB && GRP > 1) ? GRP * C2 : 4;
    static_assert(NS % 4 == 0 && C1 % 4 == 0 && C2 % 4 == 0, "");
    static_assert((NPT * NCT1) % T == 0 && TPT >= 1, "");
    static_assert(MFMAB || (T % CT2 == 0 && NS % GRP == 0 && PTSB >= 1), "");
    static_assert(!MFMAB || (NS % 16 == 0 && C1 % 32 == 0 && C2 % 64 == 0), "");

    __shared__ float xgc[NS][KCP];
    __shared__ __align__(16) char h1raw[H1B];
    __shared__ int   gix[NS];
    __shared__ float mpart[MPSZ];

    float (*h1s)[C1P] = (float(*)[C1P])h1raw;          // fp32 path view
    unsigned short* h1b = (unsigned short*)h1raw;      // bf16 path view

    const int g   = blockIdx.x;
    const int b   = g / S;
    const int tid = threadIdx.x;

    float ctr0 = 0.f, ctr1 = 0.f, ctr2 = 0.f;
    ctr0 = newxyz[(size_t)g * 3 + 0];
    ctr1 = newxyz[(size_t)g * 3 + 1];
    ctr2 = newxyz[(size_t)g * 3 + 2];
    for (int i = tid; i < NS; i += T) gix[i] = gidx[(size_t)g * NS + i];
    __syncthreads();

    // ---- Phase A: layer 1, K-chunked, accumulators in registers (fp32) ----
    float4 acc[TPT][4];
#pragma unroll
    for (int j = 0; j < TPT; ++j) {
        const int tl = tid + j * T;
        const int ct = tl % NCT1;
        const float4 bb = *(const float4*)&B1v[ct * 4];
#pragma unroll
        for (int i = 0; i < 4; ++i) acc[j][i] = bb;
    }

    const int nchunk = (CIN + KCC - 1) / KCC;
    for (int cch = 0; cch < nchunk; ++cch) {
        const int k0 = cch * KCC;
        const int kcLen = (CIN - k0 < KCC) ? (CIN - k0) : KCC;
        if (cch > 0) __syncthreads();
        // gather chunk
        for (int idx = tid; idx < NS * kcLen; idx += T) {
            const int p = idx / kcLen, kk = idx - p * kcLen, k = k0 + kk;
            float v;
            const int gi = gix[p];
            if (k < 3) {
                const float c = (k == 0) ? ctr0 : ((k == 1) ? ctr1 : ctr2);
                v = sxyz[((size_t)b * NSRC + gi) * XS + k] - c;
            } else if constexpr (MODE == 0) {
                const int j2 = k - 3;
                v = sfeat[((size_t)b * NSRC + gi) * 6 + (j2 < 3 ? 3 + j2 : j2 - 3)];
            } else {
                v = sfeat[((size_t)b * NSRC + gi) * CF + (k - 3)];
            }
            xgc[p][kk] = v;
        }
        __syncthreads();
        // compute chunk
#pragma unroll
        for (int j = 0; j < TPT; ++j) {
            const int tl = tid + j * T;
            const int pt = tl / NCT1, ct = tl % NCT1;
            const int p0 = pt * 4, c0 = ct * 4;
            int kk = 0;
            for (; kk + 4 <= kcLen; kk += 4) {
                const float4 xa = *(const float4*)&xgc[p0 + 0][kk];
                const float4 xb = *(const float4*)&xgc[p0 + 1][kk];
                const float4 xc = *(const float4*)&xgc[p0 + 2][kk];
                const float4 xd = *(const float4*)&xgc[p0 + 3][kk];
                const float4 w0 = *(const float4*)&W1[(size_t)(k0 + kk + 0) * C1 + c0];
                const float4 w1 = *(const float4*)&W1[(size_t)(k0 + kk + 1) * C1 + c0];
                const float4 w2 = *(const float4*)&W1[(size_t)(k0 + kk + 2) * C1 + c0];
                const float4 w3 = *(const float4*)&W1[(size_t)(k0 + kk + 3) * C1 + c0];
                fma4(acc[j][0], xa.x, w0); fma4(acc[j][0], xa.y, w1); fma4(acc[j][0], xa.z, w2); fma4(acc[j][0], xa.w, w3);
                fma4(acc[j][1], xb.x, w0); fma4(acc[j][1], xb.y, w1); fma4(acc[j][1], xb.z, w2); fma4(acc[j][1], xb.w, w3);
                fma4(acc[j][2], xc.x, w0); fma4(acc[j][2], xc.y, w1); fma4(acc[j][2], xc.z, w2); fma4(acc[j][2], xc.w, w3);
                fma4(acc[j][3], xd.x, w0); fma4(acc[j][3], xd.y, w1); fma4(acc[j][3], xd.z, w2); fma4(acc[j][3], xd.w, w3);
            }
            for (; kk < kcLen; ++kk) {
                const float4 w = *(const float4*)&W1[(size_t)(k0 + kk) * C1 + c0];
                fma4(acc[j][0], xgc[p0 + 0][kk], w);
                fma4(acc[j][1], xgc[p0 + 1][kk], w);
                fma4(acc[j][2], xgc[p0 + 2][kk], w);
                fma4(acc[j][3], xgc[p0 + 3][kk], w);
            }
        }
    }
    // write h1 (relu) — fp32 or bf16 depending on phase-B mode
    __syncthreads();
#pragma unroll
    for (int j = 0; j < TPT; ++j) {
        const int tl = tid + j * T;
        const int pt = tl / NCT1, ct = tl % NCT1;
        const int p0 = pt * 4, c0 = ct * 4;
#pragma unroll
        for (int i = 0; i < 4; ++i) {
            const float r0 = fmaxf(acc[j][i].x, 0.f);
            const float r1 = fmaxf(acc[j][i].y, 0.f);
            const float r2 = fmaxf(acc[j][i].z, 0.f);
            const float r3 = fmaxf(acc[j][i].w, 0.f);
            if constexpr (MFMAB) {
                unsigned short* row = &h1b[(size_t)(p0 + i) * LDHB + c0];
                row[0] = f2bf_rne(r0); row[1] = f2bf_rne(r1);
                row[2] = f2bf_rne(r2); row[3] = f2bf_rne(r3);
            } else {
                float4 r; r.x = r0; r.y = r1; r.z = r2; r.w = r3;
                *(float4*)&h1s[p0 + i][c0] = r;
            }
        }
    }
    __syncthreads();

    // ---- Phase B ----
    if constexpr (MFMAB) {
        // MFMA path: D[p][c] = sum_k h1[p][k]*W2[k][c] + b2[c], maxpool over p.
        constexpr int NMT = NS / 16;       // M-tiles (points)
        constexpr int NKB = C1 / 32;       // K-blocks
        constexpr int NNT = C2 / 16;       // N-tiles total
        constexpr int NTW = NNT / 4;       // N-tiles per wave (4 waves)
        const int w    = tid >> 6;
        const int lane = tid & 63;
        const int lr   = lane & 15;        // row (A) / col (B, C/D)
        const int lg   = lane >> 4;        // k-group (A,B) / row-group (C/D)

        // A-fragments from bf16 h1 in LDS: lane holds h1[mt*16+lr][kb*32+lg*8 .. +7]
        bf16x8 af[NMT][NKB];
#pragma unroll
        for (int mt = 0; mt < NMT; ++mt)
#pragma unroll
            for (int kb = 0; kb < NKB; ++kb)
                af[mt][kb] = *(const bf16x8*)&h1b[(size_t)(mt * 16 + lr) * LDHB + kb * 32 + lg * 8];

#pragma unroll
        for (int q = 0; q < NTW; ++q) {
            const int nt = w * NTW + q;
            const int c  = nt * 16 + lr;
            // B-fragments from fp32 W2 (global): lane holds W2[kb*32+lg*8+j][c]
            bf16x8 bfr[NKB];
#pragma unroll
            for (int kb = 0; kb < NKB; ++kb) {
#pragma unroll
                for (int j = 0; j < 8; ++j) {
                    const float wv = W2[(size_t)(kb * 32 + lg * 8 + j) * C2 + c];
                    bfr[kb][j] = (short)f2bf_rne(wv);
                }
            }
            const float bb = B2v[c];
            float colmax = 0.f;   // relu >= 0
#pragma unroll
            for (int mt = 0; mt < NMT; ++mt) {
                f32x4 ac = {bb, bb, bb, bb};
#pragma unroll
                for (int kb = 0; kb < NKB; ++kb)
                    ac = __builtin_amdgcn_mfma_f32_16x16x32_bf16(af[mt][kb], bfr[kb], ac, 0, 0, 0);
                float pm = fmaxf(fmaxf(ac[0], ac[1]), fmaxf(ac[2], ac[3]));
                pm = fmaxf(pm, __shfl_xor(pm, 16));
                pm = fmaxf(pm, __shfl_xor(pm, 32));
                colmax = fmaxf(colmax, pm);
            }
            if (lg == 0) outf[(size_t)g * C2 + c] = colmax;
        }
    } else {
        // fp32 path: PTSB pts x 4 ch per thread (R11/R14 structure)
        const int ct = tid % CT2, pb = tid / CT2;
        const int c0 = ct * 4;
        const int p0 = pb * PTSB;
        const float4 bb = *(const float4*)&B2v[c0];
        float4 ac[PTSB];
#pragma unroll
        for (int i = 0; i < PTSB; ++i) ac[i] = bb;
#pragma unroll 2
        for (int k = 0; k < C1; k += 4) {
            const float4 w0 = *(const float4*)&W2[(size_t)(k + 0) * C2 + c0];
            const float4 w1 = *(const float4*)&W2[(size_t)(k + 1) * C2 + c0];
            const float4 w2 = *(const float4*)&W2[(size_t)(k + 2) * C2 + c0];
            const float4 w3 = *(const float4*)&W2[(size_t)(k + 3) * C2 + c0];
#pragma unroll
            for (int i = 0; i < PTSB; ++i) {
                const float4 h = *(const float4*)&h1s[p0 + i][k];
                fma4(ac[i], h.x, w0); fma4(ac[i], h.y, w1);
                fma4(ac[i], h.z, w2); fma4(ac[i], h.w, w3);
            }
        }
        float4 m = make_float4(0.f, 0.f, 0.f, 0.f);   // relu>=0
#pragma unroll
        for (int i = 0; i < PTSB; ++i) {
            m.x = fmaxf(m.x, ac[i].x); m.y = fmaxf(m.y, ac[i].y);
            m.z = fmaxf(m.z, ac[i].z); m.w = fmaxf(m.w, ac[i].w);
        }
        if constexpr (GRP == 1) {
            *(float4*)&outf[(size_t)g * C2 + c0] = m;
        } else {
            *(float4*)&mpart[pb * C2 + c0] = m;
            __syncthreads();
            for (int c = tid; c < C2; c += T) {
                float mm = mpart[c];
#pragma unroll
                for (int q = 1; q < GRP; ++q) mm = fmaxf(mm, mpart[q * C2 + c]);
                outf[(size_t)g * C2 + c] = mm;
            }
        }
    }
}

// ---------------- Head part 1: 4 points per block, 515->512->1024 MLP ----
__global__ __launch_bounds__(256)
void head1_kernel(const float* __restrict__ nxyz3, const float* __restrict__ feats3,
                  const float* __restrict__ w4a, const float* __restrict__ b4a,
                  const float* __restrict__ w4b, const float* __restrict__ b4b,
                  float* __restrict__ h4)
{
    const int g0  = blockIdx.x * 4;   // 4 consecutive (b,point) groups
    const int tid = threadIdx.x;
    __shared__ float xrow[4][516];
    __shared__ float h1s[4][512];
    for (int i = tid; i < 4 * 515; i += 256) {
        const int p = i / 515, k = i - p * 515;
        xrow[p][k] = (k < 3) ? nxyz3[(size_t)(g0 + p) * 3 + k]
                             : feats3[(size_t)(g0 + p) * 512 + (k - 3)];
    }
    __syncthreads();
#pragma unroll
    for (int cc = 0; cc < 2; ++cc) {
        const int c = tid + cc * 256;
        const float bb = b4a[c];
        float a0 = bb, a1 = bb, a2 = bb, a3 = bb;
#pragma unroll 4
        for (int k = 0; k < 515; ++k) {
            const float w = w4a[(size_t)k * 512 + c];
            a0 = fmaf(xrow[0][k], w, a0);
            a1 = fmaf(xrow[1][k], w, a1);
            a2 = fmaf(xrow[2][k], w, a2);
            a3 = fmaf(xrow[3][k], w, a3);
        }
        h1s[0][c] = fmaxf(a0, 0.f); h1s[1][c] = fmaxf(a1, 0.f);
        h1s[2][c] = fmaxf(a2, 0.f); h1s[3][c] = fmaxf(a3, 0.f);
    }
    __syncthreads();
    {
        const int c0 = tid * 4;
        const float4 bb = *(const float4*)&b4b[c0];
        float4 a0 = bb, a1 = bb, a2 = bb, a3 = bb;
#pragma unroll 4
        for (int k = 0; k < 512; ++k) {
            const float4 w = *(const float4*)&w4b[(size_t)k * 1024 + c0];
            fma4(a0, h1s[0][k], w);
            fma4(a1, h1s[1][k], w);
            fma4(a2, h1s[2][k], w);
            fma4(a3, h1s[3][k], w);
        }
        float4 r;
        r.x = fmaxf(a0.x, 0.f); r.y = fmaxf(a0.y, 0.f); r.z = fmaxf(a0.z, 0.f); r.w = fmaxf(a0.w, 0.f);
        *(float4*)&h4[(size_t)(g0 + 0) * 1024 + c0] = r;
        r.x = fmaxf(a1.x, 0.f); r.y = fmaxf(a1.y, 0.f); r.z = fmaxf(a1.z, 0.f); r.w = fmaxf(a1.w, 0.f);
        *(float4*)&h4[(size_t)(g0 + 1) * 1024 + c0] = r;
        r.x = fmaxf(a2.x, 0.f); r.y = fmaxf(a2.y, 0.f); r.z = fmaxf(a2.z, 0.f); r.w = fmaxf(a2.w, 0.f);
        *(float4*)&h4[(size_t)(g0 + 2) * 1024 + c0] = r;
        r.x = fmaxf(a3.x, 0.f); r.y = fmaxf(a3.y, 0.f); r.z = fmaxf(a3.z, 0.f); r.w = fmaxf(a3.w, 0.f);
        *(float4*)&h4[(size_t)(g0 + 3) * 1024 + c0] = r;
    }
}

// ---------------- Head part 2: maxpool(16) -> fc1(relu) -> fc2 -> bn-ish ----
__global__ __launch_bounds__(256)
void head2_kernel(const float* __restrict__ h4,
                  const float* __restrict__ fc1w, const float* __restrict__ fc1b,
                  const float* __restrict__ fc2w, const float* __restrict__ fc2b,
                  const float* __restrict__ gamma, const float* __restrict__ beta,
                  float* __restrict__ out)
{
    const int b   = blockIdx.x;
    const int tid = threadIdx.x;
    __shared__ float gm[1024], g1[1024];
    {
        const int c0 = tid * 4;
        float4 m = *(const float4*)&h4[((size_t)b * 16 + 0) * 1024 + c0];
#pragma unroll
        for (int p = 1; p < 16; ++p) {
            const float4 v = *(const float4*)&h4[((size_t)b * 16 + p) * 1024 + c0];
            m.x = fmaxf(m.x, v.x); m.y = fmaxf(m.y, v.y);
            m.z = fmaxf(m.z, v.z); m.w = fmaxf(m.w, v.w);
        }
        *(float4*)&gm[c0] = m;
    }
    __syncthreads();
    {
        const int c0 = tid * 4;
        float4 a = *(const float4*)&fc1b[c0];
#pragma unroll 4
        for (int k = 0; k < 1024; ++k) {
            const float4 w = *(const float4*)&fc1w[(size_t)k * 1024 + c0];
            fma4(a, gm[k], w);
        }
        g1[c0 + 0] = fmaxf(a.x, 0.f); g1[c0 + 1] = fmaxf(a.y, 0.f);
        g1[c0 + 2] = fmaxf(a.z, 0.f); g1[c0 + 3] = fmaxf(a.w, 0.f);
    }
    __syncthreads();
    if (tid < 128) {
        const float s = sqrtf(1.00001f);
        const int c = tid;
        float a = fc2b[c];
#pragma unroll 4
        for (int k = 0; k < 1024; ++k) a = fmaf(g1[k], fc2w[(size_t)k * 128 + c], a);
        out[(size_t)b * 128 + c] = (a / s) * gamma[c] + beta[c];
    }
}

// ---------------------------------------------------------------------------
extern "C" void kernel_launch(void* const* d_in, const int* in_sizes, int n_in,
                              void* d_out, int out_size, void* d_ws, size_t ws_size,
                              hipStream_t stream)
{
    const float* pc   = (const float*)d_in[0];
    const float* w1a  = (const float*)d_in[1];  const float* b1a = (const float*)d_in[2];
    const float* w1b  = (const float*)d_in[3];  const float* b1b = (const float*)d_in[4];
    const float* w2a  = (const float*)d_in[5];  const float* b2a = (const float*)d_in[6];
    const float* w2b  = (const float*)d_in[7];  const float* b2b = (const float*)d_in[8];
    const float* w3a  = (const float*)d_in[9];  const float* b3a = (const float*)d_in[10];
    const float* w3b  = (const float*)d_in[11]; const float* b3b = (const float*)d_in[12];
    const float* w4a  = (const float*)d_in[13]; const float* b4a = (const float*)d_in[14];
    const float* w4b  = (const float*)d_in[15]; const float* b4b = (const float*)d_in[16];
    const float* fc1w = (const float*)d_in[17]; const float* fc1b = (const float*)d_in[18];
    const float* fc2w = (const float*)d_in[19]; const float* fc2b = (const float*)d_in[20];
    const float* gam  = (const float*)d_in[21]; const float* bet  = (const float*)d_in[22];
    float* out = (float*)d_out;

    char* ws = (char*)d_ws;
    size_t off = 0;
    auto alloc = [&](size_t bytes) -> void* {
        void* p = ws + off;
        off = (off + bytes + 255) & ~(size_t)255;
        return p;
    };
    float* nxyz1  = (float*)alloc((size_t)32 * 256 * 3 * 4);
    int*   gidx1  = (int*)  alloc((size_t)32 * 256 * 64 * 4);
    float* feats1 = (float*)alloc((size_t)32 * 256 * 128 * 4);
    float* nxyz2  = (float*)alloc((size_t)32 * 64 * 3 * 4);
    int*   gidx2  = (int*)  alloc((size_t)32 * 64 * 64 * 4);
    float* feats2 = (float*)alloc((size_t)32 * 64 * 256 * 4);
    float* nxyz3  = (float*)alloc((size_t)32 * 16 * 3 * 4);
    int*   gidx3  = (int*)  alloc((size_t)32 * 16 * 32 * 4);
    float* feats3 = (float*)alloc((size_t)32 * 16 * 512 * 4);
    float* h4     = (float*)alloc((size_t)32 * 16 * 1024 * 4);

    const float r2a = (float)(0.1 * 0.1);
    const float r2b = (float)(0.2 * 0.2);
    const float r2c = (float)(0.4 * 0.4);

    // ---- All three FPS stages fused (one block per batch, 4-wave config) ----
    fps_fused_kernel<<<32, 256, 0, stream>>>(pc, nxyz1, nxyz2, nxyz3);

    // ---- Ball queries ----
    bq_kernel<4096, 64, 6><<<(32 * 256 + 3) / 4, 256, 0, stream>>>(pc, nxyz1, gidx1, r2a, 256, 32 * 256);
    bq_kernel<256, 64, 3><<<(32 * 64 + 3) / 4, 256, 0, stream>>>(nxyz1, nxyz2, gidx2, r2b, 64, 32 * 64);
    bq_kernel<64, 32, 3><<<(32 * 16 + 3) / 4, 256, 0, stream>>>(nxyz2, nxyz3, gidx3, r2c, 16, 32 * 16);

    // ---- SA MLPs (stage 2 phase-B via bf16 MFMA) ----
    sa_mlp2_kernel<64, 9, 64, 128, 4096, 0><<<32 * 256, 256, 0, stream>>>(
        pc, pc, nxyz1, gidx1, w1a, b1a, w1b, b1b, feats1, 256);
    sa_mlp2_kernel<64, 131, 128, 256, 256, 1, true><<<32 * 64, 256, 0, stream>>>(
        nxyz1, feats1, nxyz2, gidx2, w2a, b2a, w2b, b2b, feats2, 64);
    sa_mlp2_kernel<32, 259, 256, 512, 64, 1><<<32 * 16, 256, 0, stream>>>(
        nxyz2, feats2, nxyz3, gidx3, w3a, b3a, w3b, b3b, feats3, 16);

    // ---- Head: 4 points per block (128 blocks), then maxpool+fc in head2
    head1_kernel<<<32 * 16 / 4, 256, 0, stream>>>(nxyz3, feats3, w4a, b4a, w4b, b4b, h4);
    head2_kernel<<<32, 256, 0, stream>>>(h4, fc1w, fc1b, fc2w, fc2b, gam, bet, out);
}

// Round 18
// 842.523 us; speedup vs baseline: 1.4559x; 1.1128x over previous
//
#include <hip/hip_runtime.h>

#define DEV static __device__ __forceinline__

using bf16x8 = __attribute__((ext_vector_type(8))) short;   // 8 bf16 (4 VGPRs)
using f32x4  = __attribute__((ext_vector_type(4))) float;

DEV float sqdist(float dx, float dy, float dz) {
    // ((dx*dx + dy*dy) + dz*dz) with no FMA contraction — must match numpy f32
    return __fadd_rn(__fadd_rn(__fmul_rn(dx, dx), __fmul_rn(dy, dy)), __fmul_rn(dz, dz));
}

DEV void fma4(float4& acc, float h, const float4& w) {
    acc.x = fmaf(h, w.x, acc.x); acc.y = fmaf(h, w.y, acc.y);
    acc.z = fmaf(h, w.z, acc.z); acc.w = fmaf(h, w.w, acc.w);
}

DEV unsigned short f2bf_rne(float f) {   // fp32 -> bf16, round-nearest-even
    unsigned u = __builtin_bit_cast(unsigned, f);
    return (unsigned short)((u + 0x7FFFu + ((u >> 16) & 1u)) >> 16);
}

// ---- argmax combine steps (value desc, index asc on ties) ----
template<int CTRL>
DEV int dpp_mov(int v) {
    return __builtin_amdgcn_update_dpp(v, v, CTRL, 0xF, 0xF, false);
}
template<int CTRL>
DEV void red_step_dpp(float& bv, int& bi) {
    float ov = __builtin_bit_cast(float, dpp_mov<CTRL>(__builtin_bit_cast(int, bv)));
    int   oi = dpp_mov<CTRL>(bi);
    if (ov > bv || (ov == bv && oi < bi)) { bv = ov; bi = oi; }
}
// full 64-lane argmax; result valid in lane 63
DEV void wave_argmax(float& bv, int& bi) {
    red_step_dpp<0xB1>(bv, bi);    // quad_perm xor 1
    red_step_dpp<0x4E>(bv, bi);    // quad_perm xor 2
    red_step_dpp<0x141>(bv, bi);   // row_half_mirror (xor 4)
    red_step_dpp<0x140>(bv, bi);   // row_mirror (xor 8)
    red_step_dpp<0x142>(bv, bi);   // row_bcast15
    red_step_dpp<0x143>(bv, bi);   // row_bcast31 -> lane 63 has full result
}

// ---- single-wave FPS over LDS points (no barriers) ----
template<int N, int NPOINT>
DEV void fps_wave64(const float4* pts, float* sout, int lane) {
    constexpr int K = (N + 63) / 64;
    float rx[K], ry[K], rz[K], d[K];
#pragma unroll
    for (int k = 0; k < K; ++k) {
        const float4 c = pts[lane + k * 64];
        rx[k] = c.x; ry[k] = c.y; rz[k] = c.z; d[k] = 1e10f;
    }
    const float4 c0 = pts[0];
    float cx = c0.x, cy = c0.y, cz = c0.z;
    for (int s = 0; s < NPOINT; ++s) {
        if (lane == 0) { sout[s * 3 + 0] = cx; sout[s * 3 + 1] = cy; sout[s * 3 + 2] = cz; }
        float bestv = -1.0f; int besti = 0x7fffffff;
#pragma unroll
        for (int k = 0; k < K; ++k) {
            float d2 = sqdist(rx[k] - cx, ry[k] - cy, rz[k] - cz);
            d[k] = fminf(d[k], d2);
            if (d[k] > bestv) { bestv = d[k]; besti = lane + k * 64; }
        }
        wave_argmax(bestv, besti);
        const int far = __builtin_amdgcn_readlane(besti, 63);
        const float4 c = pts[far];
        cx = c.x; cy = c.y; cz = c.z;
    }
}

// ---------------- Fused FPS (all 3 stages) — measured-floor config ----
__global__ __launch_bounds__(256)
void fps_fused_kernel(const float* __restrict__ pc,
                      float* __restrict__ nxyz1, float* __restrict__ nxyz2,
                      float* __restrict__ nxyz3)
{
    constexpr int N1 = 4096, NP1 = 256, NP2 = 64, NP3 = 16, T = 256, NW = T / 64;
    constexpr int K = N1 / T;
    __shared__ float4 pxyz[N1];
    __shared__ float  sout1[NP1 * 3];
    __shared__ float  sout2[NP2 * 3];
    __shared__ float  sout3[NP3 * 3];
    __shared__ float  rv[2][NW];
    __shared__ int    ri[2][NW];

    const int b = blockIdx.x, tid = threadIdx.x;
    const int w = tid >> 6, lane = tid & 63;
    const float* base = pc + (size_t)b * N1 * 6;

    float rx[K], ry[K], rz[K], d[K];
#pragma unroll
    for (int k = 0; k < K; ++k) {
        const int p = tid + k * T;
        const float x = base[p * 6 + 0];
        const float y = base[p * 6 + 1];
        const float z = base[p * 6 + 2];
        pxyz[p] = make_float4(x, y, z, 0.f);
        rx[k] = x; ry[k] = y; rz[k] = z;
        d[k] = 1e10f;
    }
    __syncthreads();

    // ---- stage 1 ----
    {
        const float4 c0 = pxyz[0];
        float cx = c0.x, cy = c0.y, cz = c0.z;
        for (int s = 0; s < NP1; ++s) {
            if (tid == 0) { sout1[s * 3 + 0] = cx; sout1[s * 3 + 1] = cy; sout1[s * 3 + 2] = cz; }
            float bestv = -1.0f; int besti = 0x7fffffff;
#pragma unroll
            for (int k = 0; k < K; ++k) {
                float d2 = sqdist(rx[k] - cx, ry[k] - cy, rz[k] - cz);
                d[k] = fminf(d[k], d2);
                if (d[k] > bestv) { bestv = d[k]; besti = tid + k * T; }  // k asc => lowest p
            }
            wave_argmax(bestv, besti);

            const int par = s & 1;
            if (lane == 63) { rv[par][w] = bestv; ri[par][w] = besti; }
            __syncthreads();
            float bvv = rv[par][0]; int bii = ri[par][0];
#pragma unroll
            for (int q = 1; q < NW; ++q) {
                const float qv = rv[par][q]; const int qi = ri[par][q];
                if (qv > bvv || (qv == bvv && qi < bii)) { bvv = qv; bii = qi; }
            }
            const float4 c = pxyz[bii];
            cx = c.x; cy = c.y; cz = c.z;
        }
    }

    // ---- stages 2 + 3 on wave 0 ----
    if (w == 0) {
        for (int i = lane; i < NP1; i += 64)
            pxyz[i] = make_float4(sout1[i * 3 + 0], sout1[i * 3 + 1], sout1[i * 3 + 2], 0.f);
        fps_wave64<NP1, NP2>(pxyz, sout2, lane);
        for (int i = lane; i < NP2; i += 64)
            pxyz[i] = make_float4(sout2[i * 3 + 0], sout2[i * 3 + 1], sout2[i * 3 + 2], 0.f);
        fps_wave64<NP2, NP3>(pxyz, sout3, lane);
    }
    __syncthreads();

    float* o1 = nxyz1 + (size_t)b * NP1 * 3;
    for (int i = tid; i < NP1 * 3; i += T) o1[i] = sout1[i];
    float* o2 = nxyz2 + (size_t)b * NP2 * 3;
    if (tid < NP2 * 3) o2[tid] = sout2[tid];
    float* o3 = nxyz3 + (size_t)b * NP3 * 3;
    if (tid < NP3 * 3) o3[tid] = sout3[tid];
}

// ---------------- Ball query -----------------
template<int N, int NSAMP, int STRIDE>
__global__ __launch_bounds__(256)
void bq_kernel(const float* __restrict__ xyz, const float* __restrict__ newxyz,
               int* __restrict__ gidx, float r2, int S, int total)
{
    const int wid = blockIdx.x * 4 + (threadIdx.x >> 6);
    if (wid >= total) return;
    const int lane = threadIdx.x & 63;
    const int b = wid / S;
    const float cx = newxyz[(size_t)wid * 3 + 0];
    const float cy = newxyz[(size_t)wid * 3 + 1];
    const float cz = newxyz[(size_t)wid * 3 + 2];
    const float* base = xyz + (size_t)b * N * STRIDE;
    int* out = gidx + (size_t)wid * NSAMP;

    int count = 0, first = N - 1;
    constexpr int NCH = (N + 63) / 64;
    for (int ch = 0; ch < NCH; ++ch) {
        int p = ch * 64 + lane;
        bool pred = false;
        if (N % 64 == 0 || p < N) {
            float dx = base[p * STRIDE + 0] - cx;
            float dy = base[p * STRIDE + 1] - cy;
            float dz = base[p * STRIDE + 2] - cz;
            pred = sqdist(dx, dy, dz) < r2;
        }
        unsigned long long m = __ballot(pred);
        if (m) {
            if (count == 0) first = ch * 64 + __builtin_ctzll(m);
            int pos = count + __popcll(m & ((1ull << lane) - 1ull));
            if (pred && pos < NSAMP) out[pos] = p;
            count += __popcll(m);
            if (count >= NSAMP) break;
        }
    }
    if (count > NSAMP) count = NSAMP;
    for (int pos = count + lane; pos < NSAMP; pos += 64) out[pos] = first;
}

// ---------------- Grouped 2-layer MLP + maxpool -----------------
// MODE 0: stage1 (xyz stride 6, feats = pc permuted). MODE 1: feats array.
// MFMAB: phase B via mfma_f32_16x16x32_bf16 (bf16 inputs, fp32 accumulate),
// fused bias-init + maxpool via shfl_xor; requires T=256, NS%16==0,
// C1%32==0, C2%64==0.
template<int NS, int CIN, int C1, int C2, int NSRC, int MODE, bool MFMAB = false>
__global__ __launch_bounds__(256)
void sa_mlp2_kernel(const float* __restrict__ sxyz, const float* __restrict__ sfeat,
                    const float* __restrict__ newxyz, const int* __restrict__ gidx,
                    const float* __restrict__ W1, const float* __restrict__ B1v,
                    const float* __restrict__ W2, const float* __restrict__ B2v,
                    float* __restrict__ outf, int S)
{
    constexpr int T    = 256;
    constexpr int KCC  = (CIN < 32) ? CIN : 32;            // k-chunk length
    constexpr int KCP0 = ((KCC + 3) / 4) * 4 + 4;
    constexpr int KCP  = ((KCP0 / 4) % 2 == 0) ? KCP0 + 4 : KCP0;  // odd quad stride
    constexpr int NPT  = NS / 4;
    constexpr int NCT1 = C1 / 4;
    constexpr int TPT  = (NPT * NCT1) / T;                 // phase-A tiles per thread
    constexpr int C1P  = C1 + 4;
    constexpr int LDHB = C1 + 8;                           // bf16 h1 row stride (16B mult)
    constexpr int CT2  = C2 / 4;                           // fp32 phase-B: 4 ch/thread
    constexpr int GRP  = T / CT2;
    constexpr int PTSB = NS / GRP;
    constexpr int XS   = (MODE == 0) ? 6 : 3;
    constexpr int CF   = CIN - 3;
    constexpr size_t H1B = MFMAB ? (size_t)NS * LDHB * 2 : (size_t)NS * C1P * 4;
    constexpr int MPSZ = (!MFMAB && GRP > 1) ? GRP * C2 : 4;
    static_assert(NS % 4 == 0 && C1 % 4 == 0 && C2 % 4 == 0, "");
    static_assert((NPT * NCT1) % T == 0 && TPT >= 1, "");
    static_assert(MFMAB || (T % CT2 == 0 && NS % GRP == 0 && PTSB >= 1), "");
    static_assert(!MFMAB || (NS % 16 == 0 && C1 % 32 == 0 && C2 % 64 == 0), "");

    __shared__ float xgc[NS][KCP];
    __shared__ __align__(16) char h1raw[H1B];
    __shared__ int   gix[NS];
    __shared__ float mpart[MPSZ];

    float (*h1s)[C1P] = (float(*)[C1P])h1raw;          // fp32 path view
    unsigned short* h1b = (unsigned short*)h1raw;      // bf16 path view

    const int g   = blockIdx.x;
    const int b   = g / S;
    const int tid = threadIdx.x;

    float ctr0 = 0.f, ctr1 = 0.f, ctr2 = 0.f;
    ctr0 = newxyz[(size_t)g * 3 + 0];
    ctr1 = newxyz[(size_t)g * 3 + 1];
    ctr2 = newxyz[(size_t)g * 3 + 2];
    for (int i = tid; i < NS; i += T) gix[i] = gidx[(size_t)g * NS + i];
    __syncthreads();

    // ---- Phase A: layer 1, K-chunked, accumulators in registers (fp32) ----
    float4 acc[TPT][4];
#pragma unroll
    for (int j = 0; j < TPT; ++j) {
        const int tl = tid + j * T;
        const int ct = tl % NCT1;
        const float4 bb = *(const float4*)&B1v[ct * 4];
#pragma unroll
        for (int i = 0; i < 4; ++i) acc[j][i] = bb;
    }

    const int nchunk = (CIN + KCC - 1) / KCC;
    for (int cch = 0; cch < nchunk; ++cch) {
        const int k0 = cch * KCC;
        const int kcLen = (CIN - k0 < KCC) ? (CIN - k0) : KCC;
        if (cch > 0) __syncthreads();
        // gather chunk
        for (int idx = tid; idx < NS * kcLen; idx += T) {
            const int p = idx / kcLen, kk = idx - p * kcLen, k = k0 + kk;
            float v;
            const int gi = gix[p];
            if (k < 3) {
                const float c = (k == 0) ? ctr0 : ((k == 1) ? ctr1 : ctr2);
                v = sxyz[((size_t)b * NSRC + gi) * XS + k] - c;
            } else if constexpr (MODE == 0) {
                const int j2 = k - 3;
                v = sfeat[((size_t)b * NSRC + gi) * 6 + (j2 < 3 ? 3 + j2 : j2 - 3)];
            } else {
                v = sfeat[((size_t)b * NSRC + gi) * CF + (k - 3)];
            }
            xgc[p][kk] = v;
        }
        __syncthreads();
        // compute chunk
#pragma unroll
        for (int j = 0; j < TPT; ++j) {
            const int tl = tid + j * T;
            const int pt = tl / NCT1, ct = tl % NCT1;
            const int p0 = pt * 4, c0 = ct * 4;
            int kk = 0;
            for (; kk + 4 <= kcLen; kk += 4) {
                const float4 xa = *(const float4*)&xgc[p0 + 0][kk];
                const float4 xb = *(const float4*)&xgc[p0 + 1][kk];
                const float4 xc = *(const float4*)&xgc[p0 + 2][kk];
                const float4 xd = *(const float4*)&xgc[p0 + 3][kk];
                const float4 w0 = *(const float4*)&W1[(size_t)(k0 + kk + 0) * C1 + c0];
                const float4 w1 = *(const float4*)&W1[(size_t)(k0 + kk + 1) * C1 + c0];
                const float4 w2 = *(const float4*)&W1[(size_t)(k0 + kk + 2) * C1 + c0];
                const float4 w3 = *(const float4*)&W1[(size_t)(k0 + kk + 3) * C1 + c0];
                fma4(acc[j][0], xa.x, w0); fma4(acc[j][0], xa.y, w1); fma4(acc[j][0], xa.z, w2); fma4(acc[j][0], xa.w, w3);
                fma4(acc[j][1], xb.x, w0); fma4(acc[j][1], xb.y, w1); fma4(acc[j][1], xb.z, w2); fma4(acc[j][1], xb.w, w3);
                fma4(acc[j][2], xc.x, w0); fma4(acc[j][2], xc.y, w1); fma4(acc[j][2], xc.z, w2); fma4(acc[j][2], xc.w, w3);
                fma4(acc[j][3], xd.x, w0); fma4(acc[j][3], xd.y, w1); fma4(acc[j][3], xd.z, w2); fma4(acc[j][3], xd.w, w3);
            }
            for (; kk < kcLen; ++kk) {
                const float4 w = *(const float4*)&W1[(size_t)(k0 + kk) * C1 + c0];
                fma4(acc[j][0], xgc[p0 + 0][kk], w);
                fma4(acc[j][1], xgc[p0 + 1][kk], w);
                fma4(acc[j][2], xgc[p0 + 2][kk], w);
                fma4(acc[j][3], xgc[p0 + 3][kk], w);
            }
        }
    }
    // write h1 (relu) — fp32 or bf16 depending on phase-B mode
    __syncthreads();
#pragma unroll
    for (int j = 0; j < TPT; ++j) {
        const int tl = tid + j * T;
        const int pt = tl / NCT1, ct = tl % NCT1;
        const int p0 = pt * 4, c0 = ct * 4;
#pragma unroll
        for (int i = 0; i < 4; ++i) {
            const float r0 = fmaxf(acc[j][i].x, 0.f);
            const float r1 = fmaxf(acc[j][i].y, 0.f);
            const float r2 = fmaxf(acc[j][i].z, 0.f);
            const float r3 = fmaxf(acc[j][i].w, 0.f);
            if constexpr (MFMAB) {
                unsigned short* row = &h1b[(size_t)(p0 + i) * LDHB + c0];
                row[0] = f2bf_rne(r0); row[1] = f2bf_rne(r1);
                row[2] = f2bf_rne(r2); row[3] = f2bf_rne(r3);
            } else {
                float4 r; r.x = r0; r.y = r1; r.z = r2; r.w = r3;
                *(float4*)&h1s[p0 + i][c0] = r;
            }
        }
    }
    __syncthreads();

    // ---- Phase B ----
    if constexpr (MFMAB) {
        // MFMA path: D[p][c] = sum_k h1[p][k]*W2[k][c] + b2[c], maxpool over p.
        constexpr int NMT = NS / 16;       // M-tiles (points)
        constexpr int NKB = C1 / 32;       // K-blocks
        constexpr int NNT = C2 / 16;       // N-tiles total
        constexpr int NTW = NNT / 4;       // N-tiles per wave (4 waves)
        const int w    = tid >> 6;
        const int lane = tid & 63;
        const int lr   = lane & 15;        // row (A) / col (B, C/D)
        const int lg   = lane >> 4;        // k-group (A,B) / row-group (C/D)

        // A-fragments from bf16 h1 in LDS: lane holds h1[mt*16+lr][kb*32+lg*8 .. +7]
        bf16x8 af[NMT][NKB];
#pragma unroll
        for (int mt = 0; mt < NMT; ++mt)
#pragma unroll
            for (int kb = 0; kb < NKB; ++kb)
                af[mt][kb] = *(const bf16x8*)&h1b[(size_t)(mt * 16 + lr) * LDHB + kb * 32 + lg * 8];

#pragma unroll
        for (int q = 0; q < NTW; ++q) {
            const int nt = w * NTW + q;
            const int c  = nt * 16 + lr;
            // B-fragments from fp32 W2 (global): lane holds W2[kb*32+lg*8+j][c]
            bf16x8 bfr[NKB];
#pragma unroll
            for (int kb = 0; kb < NKB; ++kb) {
#pragma unroll
                for (int j = 0; j < 8; ++j) {
                    const float wv = W2[(size_t)(kb * 32 + lg * 8 + j) * C2 + c];
                    bfr[kb][j] = (short)f2bf_rne(wv);
                }
            }
            const float bb = B2v[c];
            float colmax = 0.f;   // relu >= 0
#pragma unroll
            for (int mt = 0; mt < NMT; ++mt) {
                f32x4 ac = {bb, bb, bb, bb};
#pragma unroll
                for (int kb = 0; kb < NKB; ++kb)
                    ac = __builtin_amdgcn_mfma_f32_16x16x32_bf16(af[mt][kb], bfr[kb], ac, 0, 0, 0);
                float pm = fmaxf(fmaxf(ac[0], ac[1]), fmaxf(ac[2], ac[3]));
                pm = fmaxf(pm, __shfl_xor(pm, 16));
                pm = fmaxf(pm, __shfl_xor(pm, 32));
                colmax = fmaxf(colmax, pm);
            }
            if (lg == 0) outf[(size_t)g * C2 + c] = colmax;
        }
    } else {
        // fp32 path: PTSB pts x 4 ch per thread (R11/R14 structure)
        const int ct = tid % CT2, pb = tid / CT2;
        const int c0 = ct * 4;
        const int p0 = pb * PTSB;
        const float4 bb = *(const float4*)&B2v[c0];
        float4 ac[PTSB];
#pragma unroll
        for (int i = 0; i < PTSB; ++i) ac[i] = bb;
#pragma unroll 2
        for (int k = 0; k < C1; k += 4) {
            const float4 w0 = *(const float4*)&W2[(size_t)(k + 0) * C2 + c0];
            const float4 w1 = *(const float4*)&W2[(size_t)(k + 1) * C2 + c0];
            const float4 w2 = *(const float4*)&W2[(size_t)(k + 2) * C2 + c0];
            const float4 w3 = *(const float4*)&W2[(size_t)(k + 3) * C2 + c0];
#pragma unroll
            for (int i = 0; i < PTSB; ++i) {
                const float4 h = *(const float4*)&h1s[p0 + i][k];
                fma4(ac[i], h.x, w0); fma4(ac[i], h.y, w1);
                fma4(ac[i], h.z, w2); fma4(ac[i], h.w, w3);
            }
        }
        float4 m = make_float4(0.f, 0.f, 0.f, 0.f);   // relu>=0
#pragma unroll
        for (int i = 0; i < PTSB; ++i) {
            m.x = fmaxf(m.x, ac[i].x); m.y = fmaxf(m.y, ac[i].y);
            m.z = fmaxf(m.z, ac[i].z); m.w = fmaxf(m.w, ac[i].w);
        }
        if constexpr (GRP == 1) {
            *(float4*)&outf[(size_t)g * C2 + c0] = m;
        } else {
            *(float4*)&mpart[pb * C2 + c0] = m;
            __syncthreads();
            for (int c = tid; c < C2; c += T) {
                float mm = mpart[c];
#pragma unroll
                for (int q = 1; q < GRP; ++q) mm = fmaxf(mm, mpart[q * C2 + c]);
                outf[(size_t)g * C2 + c] = mm;
            }
        }
    }
}

// ---------------- Head part 1: 4 points per block, 515->512->1024 MLP ----
__global__ __launch_bounds__(256)
void head1_kernel(const float* __restrict__ nxyz3, const float* __restrict__ feats3,
                  const float* __restrict__ w4a, const float* __restrict__ b4a,
                  const float* __restrict__ w4b, const float* __restrict__ b4b,
                  float* __restrict__ h4)
{
    const int g0  = blockIdx.x * 4;   // 4 consecutive (b,point) groups
    const int tid = threadIdx.x;
    __shared__ float xrow[4][516];
    __shared__ float h1s[4][512];
    for (int i = tid; i < 4 * 515; i += 256) {
        const int p = i / 515, k = i - p * 515;
        xrow[p][k] = (k < 3) ? nxyz3[(size_t)(g0 + p) * 3 + k]
                             : feats3[(size_t)(g0 + p) * 512 + (k - 3)];
    }
    __syncthreads();
#pragma unroll
    for (int cc = 0; cc < 2; ++cc) {
        const int c = tid + cc * 256;
        const float bb = b4a[c];
        float a0 = bb, a1 = bb, a2 = bb, a3 = bb;
#pragma unroll 4
        for (int k = 0; k < 515; ++k) {
            const float w = w4a[(size_t)k * 512 + c];
            a0 = fmaf(xrow[0][k], w, a0);
            a1 = fmaf(xrow[1][k], w, a1);
            a2 = fmaf(xrow[2][k], w, a2);
            a3 = fmaf(xrow[3][k], w, a3);
        }
        h1s[0][c] = fmaxf(a0, 0.f); h1s[1][c] = fmaxf(a1, 0.f);
        h1s[2][c] = fmaxf(a2, 0.f); h1s[3][c] = fmaxf(a3, 0.f);
    }
    __syncthreads();
    {
        const int c0 = tid * 4;
        const float4 bb = *(const float4*)&b4b[c0];
        float4 a0 = bb, a1 = bb, a2 = bb, a3 = bb;
#pragma unroll 4
        for (int k = 0; k < 512; ++k) {
            const float4 w = *(const float4*)&w4b[(size_t)k * 1024 + c0];
            fma4(a0, h1s[0][k], w);
            fma4(a1, h1s[1][k], w);
            fma4(a2, h1s[2][k], w);
            fma4(a3, h1s[3][k], w);
        }
        float4 r;
        r.x = fmaxf(a0.x, 0.f); r.y = fmaxf(a0.y, 0.f); r.z = fmaxf(a0.z, 0.f); r.w = fmaxf(a0.w, 0.f);
        *(float4*)&h4[(size_t)(g0 + 0) * 1024 + c0] = r;
        r.x = fmaxf(a1.x, 0.f); r.y = fmaxf(a1.y, 0.f); r.z = fmaxf(a1.z, 0.f); r.w = fmaxf(a1.w, 0.f);
        *(float4*)&h4[(size_t)(g0 + 1) * 1024 + c0] = r;
        r.x = fmaxf(a2.x, 0.f); r.y = fmaxf(a2.y, 0.f); r.z = fmaxf(a2.z, 0.f); r.w = fmaxf(a2.w, 0.f);
        *(float4*)&h4[(size_t)(g0 + 2) * 1024 + c0] = r;
        r.x = fmaxf(a3.x, 0.f); r.y = fmaxf(a3.y, 0.f); r.z = fmaxf(a3.z, 0.f); r.w = fmaxf(a3.w, 0.f);
        *(float4*)&h4[(size_t)(g0 + 3) * 1024 + c0] = r;
    }
}

// ---------------- Head part 2: maxpool(16) -> fc1(relu) -> fc2 -> bn-ish ----
__global__ __launch_bounds__(256)
void head2_kernel(const float* __restrict__ h4,
                  const float* __restrict__ fc1w, const float* __restrict__ fc1b,
                  const float* __restrict__ fc2w, const float* __restrict__ fc2b,
                  const float* __restrict__ gamma, const float* __restrict__ beta,
                  float* __restrict__ out)
{
    const int b   = blockIdx.x;
    const int tid = threadIdx.x;
    __shared__ float gm[1024], g1[1024];
    {
        const int c0 = tid * 4;
        float4 m = *(const float4*)&h4[((size_t)b * 16 + 0) * 1024 + c0];
#pragma unroll
        for (int p = 1; p < 16; ++p) {
            const float4 v = *(const float4*)&h4[((size_t)b * 16 + p) * 1024 + c0];
            m.x = fmaxf(m.x, v.x); m.y = fmaxf(m.y, v.y);
            m.z = fmaxf(m.z, v.z); m.w = fmaxf(m.w, v.w);
        }
        *(float4*)&gm[c0] = m;
    }
    __syncthreads();
    {
        const int c0 = tid * 4;
        float4 a = *(const float4*)&fc1b[c0];
#pragma unroll 4
        for (int k = 0; k < 1024; ++k) {
            const float4 w = *(const float4*)&fc1w[(size_t)k * 1024 + c0];
            fma4(a, gm[k], w);
        }
        g1[c0 + 0] = fmaxf(a.x, 0.f); g1[c0 + 1] = fmaxf(a.y, 0.f);
        g1[c0 + 2] = fmaxf(a.z, 0.f); g1[c0 + 3] = fmaxf(a.w, 0.f);
    }
    __syncthreads();
    if (tid < 128) {
        const float s = sqrtf(1.00001f);
        const int c = tid;
        float a = fc2b[c];
#pragma unroll 4
        for (int k = 0; k < 1024; ++k) a = fmaf(g1[k], fc2w[(size_t)k * 128 + c], a);
        out[(size_t)b * 128 + c] = (a / s) * gamma[c] + beta[c];
    }
}

// ---------------------------------------------------------------------------
extern "C" void kernel_launch(void* const* d_in, const int* in_sizes, int n_in,
                              void* d_out, int out_size, void* d_ws, size_t ws_size,
                              hipStream_t stream)
{
    const float* pc   = (const float*)d_in[0];
    const float* w1a  = (const float*)d_in[1];  const float* b1a = (const float*)d_in[2];
    const float* w1b  = (const float*)d_in[3];  const float* b1b = (const float*)d_in[4];
    const float* w2a  = (const float*)d_in[5];  const float* b2a = (const float*)d_in[6];
    const float* w2b  = (const float*)d_in[7];  const float* b2b = (const float*)d_in[8];
    const float* w3a  = (const float*)d_in[9];  const float* b3a = (const float*)d_in[10];
    const float* w3b  = (const float*)d_in[11]; const float* b3b = (const float*)d_in[12];
    const float* w4a  = (const float*)d_in[13]; const float* b4a = (const float*)d_in[14];
    const float* w4b  = (const float*)d_in[15]; const float* b4b = (const float*)d_in[16];
    const float* fc1w = (const float*)d_in[17]; const float* fc1b = (const float*)d_in[18];
    const float* fc2w = (const float*)d_in[19]; const float* fc2b = (const float*)d_in[20];
    const float* gam  = (const float*)d_in[21]; const float* bet  = (const float*)d_in[22];
    float* out = (float*)d_out;

    char* ws = (char*)d_ws;
    size_t off = 0;
    auto alloc = [&](size_t bytes) -> void* {
        void* p = ws + off;
        off = (off + bytes + 255) & ~(size_t)255;
        return p;
    };
    float* nxyz1  = (float*)alloc((size_t)32 * 256 * 3 * 4);
    int*   gidx1  = (int*)  alloc((size_t)32 * 256 * 64 * 4);
    float* feats1 = (float*)alloc((size_t)32 * 256 * 128 * 4);
    float* nxyz2  = (float*)alloc((size_t)32 * 64 * 3 * 4);
    int*   gidx2  = (int*)  alloc((size_t)32 * 64 * 64 * 4);
    float* feats2 = (float*)alloc((size_t)32 * 64 * 256 * 4);
    float* nxyz3  = (float*)alloc((size_t)32 * 16 * 3 * 4);
    int*   gidx3  = (int*)  alloc((size_t)32 * 16 * 32 * 4);
    float* feats3 = (float*)alloc((size_t)32 * 16 * 512 * 4);
    float* h4     = (float*)alloc((size_t)32 * 16 * 1024 * 4);

    const float r2a = (float)(0.1 * 0.1);
    const float r2b = (float)(0.2 * 0.2);
    const float r2c = (float)(0.4 * 0.4);

    // ---- All three FPS stages fused (one block per batch, 4-wave config) ----
    fps_fused_kernel<<<32, 256, 0, stream>>>(pc, nxyz1, nxyz2, nxyz3);

    // ---- Ball queries ----
    bq_kernel<4096, 64, 6><<<(32 * 256 + 3) / 4, 256, 0, stream>>>(pc, nxyz1, gidx1, r2a, 256, 32 * 256);
    bq_kernel<256, 64, 3><<<(32 * 64 + 3) / 4, 256, 0, stream>>>(nxyz1, nxyz2, gidx2, r2b, 64, 32 * 64);
    bq_kernel<64, 32, 3><<<(32 * 16 + 3) / 4, 256, 0, stream>>>(nxyz2, nxyz3, gidx3, r2c, 16, 32 * 16);

    // ---- SA MLPs (all three phase-Bs via bf16 MFMA, fp32 accumulate) ----
    sa_mlp2_kernel<64, 9, 64, 128, 4096, 0, true><<<32 * 256, 256, 0, stream>>>(
        pc, pc, nxyz1, gidx1, w1a, b1a, w1b, b1b, feats1, 256);
    sa_mlp2_kernel<64, 131, 128, 256, 256, 1, true><<<32 * 64, 256, 0, stream>>>(
        nxyz1, feats1, nxyz2, gidx2, w2a, b2a, w2b, b2b, feats2, 64);
    sa_mlp2_kernel<32, 259, 256, 512, 64, 1, true><<<32 * 16, 256, 0, stream>>>(
        nxyz2, feats2, nxyz3, gidx3, w3a, b3a, w3b, b3b, feats3, 16);

    // ---- Head: 4 points per block (128 blocks), then maxpool+fc in head2
    head1_kernel<<<32 * 16 / 4, 256, 0, stream>>>(nxyz3, feats3, w4a, b4a, w4b, b4b, h4);
    head2_kernel<<<32, 256, 0, stream>>>(h4, fc1w, fc1b, fc2w, fc2b, gam, bet, out);
}

// Round 19
// 827.694 us; speedup vs baseline: 1.4819x; 1.0179x over previous
//
#include <hip/hip_runtime.h>

#define DEV static __device__ __forceinline__

using bf16x8 = __attribute__((ext_vector_type(8))) short;   // 8 bf16 (4 VGPRs)
using f32x4  = __attribute__((ext_vector_type(4))) float;

DEV float sqdist(float dx, float dy, float dz) {
    // ((dx*dx + dy*dy) + dz*dz) with no FMA contraction — must match numpy f32
    return __fadd_rn(__fadd_rn(__fmul_rn(dx, dx), __fmul_rn(dy, dy)), __fmul_rn(dz, dz));
}

DEV void fma4(float4& acc, float h, const float4& w) {
    acc.x = fmaf(h, w.x, acc.x); acc.y = fmaf(h, w.y, acc.y);
    acc.z = fmaf(h, w.z, acc.z); acc.w = fmaf(h, w.w, acc.w);
}

DEV unsigned short f2bf_rne(float f) {   // fp32 -> bf16, round-nearest-even
    unsigned u = __builtin_bit_cast(unsigned, f);
    return (unsigned short)((u + 0x7FFFu + ((u >> 16) & 1u)) >> 16);
}

// ---- argmax combine steps (value desc, index asc on ties) ----
template<int CTRL>
DEV int dpp_mov(int v) {
    return __builtin_amdgcn_update_dpp(v, v, CTRL, 0xF, 0xF, false);
}
template<int CTRL>
DEV void red_step_dpp(float& bv, int& bi) {
    float ov = __builtin_bit_cast(float, dpp_mov<CTRL>(__builtin_bit_cast(int, bv)));
    int   oi = dpp_mov<CTRL>(bi);
    if (ov > bv || (ov == bv && oi < bi)) { bv = ov; bi = oi; }
}
// full 64-lane argmax; result valid in lane 63
DEV void wave_argmax(float& bv, int& bi) {
    red_step_dpp<0xB1>(bv, bi);    // quad_perm xor 1
    red_step_dpp<0x4E>(bv, bi);    // quad_perm xor 2
    red_step_dpp<0x141>(bv, bi);   // row_half_mirror (xor 4)
    red_step_dpp<0x140>(bv, bi);   // row_mirror (xor 8)
    red_step_dpp<0x142>(bv, bi);   // row_bcast15
    red_step_dpp<0x143>(bv, bi);   // row_bcast31 -> lane 63 has full result
}

// ---- single-wave FPS over LDS points (no barriers) ----
template<int N, int NPOINT>
DEV void fps_wave64(const float4* pts, float* sout, int lane) {
    constexpr int K = (N + 63) / 64;
    float rx[K], ry[K], rz[K], d[K];
#pragma unroll
    for (int k = 0; k < K; ++k) {
        const float4 c = pts[lane + k * 64];
        rx[k] = c.x; ry[k] = c.y; rz[k] = c.z; d[k] = 1e10f;
    }
    const float4 c0 = pts[0];
    float cx = c0.x, cy = c0.y, cz = c0.z;
    for (int s = 0; s < NPOINT; ++s) {
        if (lane == 0) { sout[s * 3 + 0] = cx; sout[s * 3 + 1] = cy; sout[s * 3 + 2] = cz; }
        float bestv = -1.0f; int besti = 0x7fffffff;
#pragma unroll
        for (int k = 0; k < K; ++k) {
            float d2 = sqdist(rx[k] - cx, ry[k] - cy, rz[k] - cz);
            d[k] = fminf(d[k], d2);
            if (d[k] > bestv) { bestv = d[k]; besti = lane + k * 64; }
        }
        wave_argmax(bestv, besti);
        const int far = __builtin_amdgcn_readlane(besti, 63);
        const float4 c = pts[far];
        cx = c.x; cy = c.y; cz = c.z;
    }
}

// ---------------- Fused FPS (all 3 stages) — measured-floor config ----
__global__ __launch_bounds__(256)
void fps_fused_kernel(const float* __restrict__ pc,
                      float* __restrict__ nxyz1, float* __restrict__ nxyz2,
                      float* __restrict__ nxyz3)
{
    constexpr int N1 = 4096, NP1 = 256, NP2 = 64, NP3 = 16, T = 256, NW = T / 64;
    constexpr int K = N1 / T;
    __shared__ float4 pxyz[N1];
    __shared__ float  sout1[NP1 * 3];
    __shared__ float  sout2[NP2 * 3];
    __shared__ float  sout3[NP3 * 3];
    __shared__ float  rv[2][NW];
    __shared__ int    ri[2][NW];

    const int b = blockIdx.x, tid = threadIdx.x;
    const int w = tid >> 6, lane = tid & 63;
    const float* base = pc + (size_t)b * N1 * 6;

    float rx[K], ry[K], rz[K], d[K];
#pragma unroll
    for (int k = 0; k < K; ++k) {
        const int p = tid + k * T;
        const float x = base[p * 6 + 0];
        const float y = base[p * 6 + 1];
        const float z = base[p * 6 + 2];
        pxyz[p] = make_float4(x, y, z, 0.f);
        rx[k] = x; ry[k] = y; rz[k] = z;
        d[k] = 1e10f;
    }
    __syncthreads();

    // ---- stage 1 ----
    {
        const float4 c0 = pxyz[0];
        float cx = c0.x, cy = c0.y, cz = c0.z;
        for (int s = 0; s < NP1; ++s) {
            if (tid == 0) { sout1[s * 3 + 0] = cx; sout1[s * 3 + 1] = cy; sout1[s * 3 + 2] = cz; }
            float bestv = -1.0f; int besti = 0x7fffffff;
#pragma unroll
            for (int k = 0; k < K; ++k) {
                float d2 = sqdist(rx[k] - cx, ry[k] - cy, rz[k] - cz);
                d[k] = fminf(d[k], d2);
                if (d[k] > bestv) { bestv = d[k]; besti = tid + k * T; }  // k asc => lowest p
            }
            wave_argmax(bestv, besti);

            const int par = s & 1;
            if (lane == 63) { rv[par][w] = bestv; ri[par][w] = besti; }
            __syncthreads();
            float bvv = rv[par][0]; int bii = ri[par][0];
#pragma unroll
            for (int q = 1; q < NW; ++q) {
                const float qv = rv[par][q]; const int qi = ri[par][q];
                if (qv > bvv || (qv == bvv && qi < bii)) { bvv = qv; bii = qi; }
            }
            const float4 c = pxyz[bii];
            cx = c.x; cy = c.y; cz = c.z;
        }
    }

    // ---- stages 2 + 3 on wave 0 ----
    if (w == 0) {
        for (int i = lane; i < NP1; i += 64)
            pxyz[i] = make_float4(sout1[i * 3 + 0], sout1[i * 3 + 1], sout1[i * 3 + 2], 0.f);
        fps_wave64<NP1, NP2>(pxyz, sout2, lane);
        for (int i = lane; i < NP2; i += 64)
            pxyz[i] = make_float4(sout2[i * 3 + 0], sout2[i * 3 + 1], sout2[i * 3 + 2], 0.f);
        fps_wave64<NP2, NP3>(pxyz, sout3, lane);
    }
    __syncthreads();

    float* o1 = nxyz1 + (size_t)b * NP1 * 3;
    for (int i = tid; i < NP1 * 3; i += T) o1[i] = sout1[i];
    float* o2 = nxyz2 + (size_t)b * NP2 * 3;
    if (tid < NP2 * 3) o2[tid] = sout2[tid];
    float* o3 = nxyz3 + (size_t)b * NP3 * 3;
    if (tid < NP3 * 3) o3[tid] = sout3[tid];
}

// ---------------- Ball query -----------------
template<int N, int NSAMP, int STRIDE>
__global__ __launch_bounds__(256)
void bq_kernel(const float* __restrict__ xyz, const float* __restrict__ newxyz,
               int* __restrict__ gidx, float r2, int S, int total)
{
    const int wid = blockIdx.x * 4 + (threadIdx.x >> 6);
    if (wid >= total) return;
    const int lane = threadIdx.x & 63;
    const int b = wid / S;
    const float cx = newxyz[(size_t)wid * 3 + 0];
    const float cy = newxyz[(size_t)wid * 3 + 1];
    const float cz = newxyz[(size_t)wid * 3 + 2];
    const float* base = xyz + (size_t)b * N * STRIDE;
    int* out = gidx + (size_t)wid * NSAMP;

    int count = 0, first = N - 1;
    constexpr int NCH = (N + 63) / 64;
    for (int ch = 0; ch < NCH; ++ch) {
        int p = ch * 64 + lane;
        bool pred = false;
        if (N % 64 == 0 || p < N) {
            float dx = base[p * STRIDE + 0] - cx;
            float dy = base[p * STRIDE + 1] - cy;
            float dz = base[p * STRIDE + 2] - cz;
            pred = sqdist(dx, dy, dz) < r2;
        }
        unsigned long long m = __ballot(pred);
        if (m) {
            if (count == 0) first = ch * 64 + __builtin_ctzll(m);
            int pos = count + __popcll(m & ((1ull << lane) - 1ull));
            if (pred && pos < NSAMP) out[pos] = p;
            count += __popcll(m);
            if (count >= NSAMP) break;
        }
    }
    if (count > NSAMP) count = NSAMP;
    for (int pos = count + lane; pos < NSAMP; pos += 64) out[pos] = first;
}

// ---------------- Grouped 2-layer MLP + maxpool (hybrid: fp32 A / MFMA B) ----
// Used for stage 1 (CIN=9). MODE 0: xyz stride 6, feats = pc permuted.
template<int NS, int CIN, int C1, int C2, int NSRC, int MODE, bool MFMAB = false>
__global__ __launch_bounds__(256)
void sa_mlp2_kernel(const float* __restrict__ sxyz, const float* __restrict__ sfeat,
                    const float* __restrict__ newxyz, const int* __restrict__ gidx,
                    const float* __restrict__ W1, const float* __restrict__ B1v,
                    const float* __restrict__ W2, const float* __restrict__ B2v,
                    float* __restrict__ outf, int S)
{
    constexpr int T    = 256;
    constexpr int KCC  = (CIN < 32) ? CIN : 32;            // k-chunk length
    constexpr int KCP0 = ((KCC + 3) / 4) * 4 + 4;
    constexpr int KCP  = ((KCP0 / 4) % 2 == 0) ? KCP0 + 4 : KCP0;  // odd quad stride
    constexpr int NPT  = NS / 4;
    constexpr int NCT1 = C1 / 4;
    constexpr int TPT  = (NPT * NCT1) / T;                 // phase-A tiles per thread
    constexpr int C1P  = C1 + 4;
    constexpr int LDHB = C1 + 8;                           // bf16 h1 row stride (16B mult)
    constexpr int CT2  = C2 / 4;                           // fp32 phase-B: 4 ch/thread
    constexpr int GRP  = T / CT2;
    constexpr int PTSB = NS / GRP;
    constexpr int XS   = (MODE == 0) ? 6 : 3;
    constexpr int CF   = CIN - 3;
    constexpr size_t H1B = MFMAB ? (size_t)NS * LDHB * 2 : (size_t)NS * C1P * 4;
    constexpr int MPSZ = (!MFMAB && GRP > 1) ? GRP * C2 : 4;
    static_assert(NS % 4 == 0 && C1 % 4 == 0 && C2 % 4 == 0, "");
    static_assert((NPT * NCT1) % T == 0 && TPT >= 1, "");
    static_assert(MFMAB || (T % CT2 == 0 && NS % GRP == 0 && PTSB >= 1), "");
    static_assert(!MFMAB || (NS % 16 == 0 && C1 % 32 == 0 && C2 % 64 == 0), "");

    __shared__ float xgc[NS][KCP];
    __shared__ __align__(16) char h1raw[H1B];
    __shared__ int   gix[NS];
    __shared__ float mpart[MPSZ];

    float (*h1s)[C1P] = (float(*)[C1P])h1raw;          // fp32 path view
    unsigned short* h1b = (unsigned short*)h1raw;      // bf16 path view

    const int g   = blockIdx.x;
    const int b   = g / S;
    const int tid = threadIdx.x;

    float ctr0 = 0.f, ctr1 = 0.f, ctr2 = 0.f;
    ctr0 = newxyz[(size_t)g * 3 + 0];
    ctr1 = newxyz[(size_t)g * 3 + 1];
    ctr2 = newxyz[(size_t)g * 3 + 2];
    for (int i = tid; i < NS; i += T) gix[i] = gidx[(size_t)g * NS + i];
    __syncthreads();

    // ---- Phase A: layer 1, K-chunked, accumulators in registers (fp32) ----
    float4 acc[TPT][4];
#pragma unroll
    for (int j = 0; j < TPT; ++j) {
        const int tl = tid + j * T;
        const int ct = tl % NCT1;
        const float4 bb = *(const float4*)&B1v[ct * 4];
#pragma unroll
        for (int i = 0; i < 4; ++i) acc[j][i] = bb;
    }

    const int nchunk = (CIN + KCC - 1) / KCC;
    for (int cch = 0; cch < nchunk; ++cch) {
        const int k0 = cch * KCC;
        const int kcLen = (CIN - k0 < KCC) ? (CIN - k0) : KCC;
        if (cch > 0) __syncthreads();
        // gather chunk
        for (int idx = tid; idx < NS * kcLen; idx += T) {
            const int p = idx / kcLen, kk = idx - p * kcLen, k = k0 + kk;
            float v;
            const int gi = gix[p];
            if (k < 3) {
                const float c = (k == 0) ? ctr0 : ((k == 1) ? ctr1 : ctr2);
                v = sxyz[((size_t)b * NSRC + gi) * XS + k] - c;
            } else if constexpr (MODE == 0) {
                const int j2 = k - 3;
                v = sfeat[((size_t)b * NSRC + gi) * 6 + (j2 < 3 ? 3 + j2 : j2 - 3)];
            } else {
                v = sfeat[((size_t)b * NSRC + gi) * CF + (k - 3)];
            }
            xgc[p][kk] = v;
        }
        __syncthreads();
        // compute chunk
#pragma unroll
        for (int j = 0; j < TPT; ++j) {
            const int tl = tid + j * T;
            const int pt = tl / NCT1, ct = tl % NCT1;
            const int p0 = pt * 4, c0 = ct * 4;
            int kk = 0;
            for (; kk + 4 <= kcLen; kk += 4) {
                const float4 xa = *(const float4*)&xgc[p0 + 0][kk];
                const float4 xb = *(const float4*)&xgc[p0 + 1][kk];
                const float4 xc = *(const float4*)&xgc[p0 + 2][kk];
                const float4 xd = *(const float4*)&xgc[p0 + 3][kk];
                const float4 w0 = *(const float4*)&W1[(size_t)(k0 + kk + 0) * C1 + c0];
                const float4 w1 = *(const float4*)&W1[(size_t)(k0 + kk + 1) * C1 + c0];
                const float4 w2 = *(const float4*)&W1[(size_t)(k0 + kk + 2) * C1 + c0];
                const float4 w3 = *(const float4*)&W1[(size_t)(k0 + kk + 3) * C1 + c0];
                fma4(acc[j][0], xa.x, w0); fma4(acc[j][0], xa.y, w1); fma4(acc[j][0], xa.z, w2); fma4(acc[j][0], xa.w, w3);
                fma4(acc[j][1], xb.x, w0); fma4(acc[j][1], xb.y, w1); fma4(acc[j][1], xb.z, w2); fma4(acc[j][1], xb.w, w3);
                fma4(acc[j][2], xc.x, w0); fma4(acc[j][2], xc.y, w1); fma4(acc[j][2], xc.z, w2); fma4(acc[j][2], xc.w, w3);
                fma4(acc[j][3], xd.x, w0); fma4(acc[j][3], xd.y, w1); fma4(acc[j][3], xd.z, w2); fma4(acc[j][3], xd.w, w3);
            }
            for (; kk < kcLen; ++kk) {
                const float4 w = *(const float4*)&W1[(size_t)(k0 + kk) * C1 + c0];
                fma4(acc[j][0], xgc[p0 + 0][kk], w);
                fma4(acc[j][1], xgc[p0 + 1][kk], w);
                fma4(acc[j][2], xgc[p0 + 2][kk], w);
                fma4(acc[j][3], xgc[p0 + 3][kk], w);
            }
        }
    }
    // write h1 (relu) — fp32 or bf16 depending on phase-B mode
    __syncthreads();
#pragma unroll
    for (int j = 0; j < TPT; ++j) {
        const int tl = tid + j * T;
        const int pt = tl / NCT1, ct = tl % NCT1;
        const int p0 = pt * 4, c0 = ct * 4;
#pragma unroll
        for (int i = 0; i < 4; ++i) {
            const float r0 = fmaxf(acc[j][i].x, 0.f);
            const float r1 = fmaxf(acc[j][i].y, 0.f);
            const float r2 = fmaxf(acc[j][i].z, 0.f);
            const float r3 = fmaxf(acc[j][i].w, 0.f);
            if constexpr (MFMAB) {
                unsigned short* row = &h1b[(size_t)(p0 + i) * LDHB + c0];
                row[0] = f2bf_rne(r0); row[1] = f2bf_rne(r1);
                row[2] = f2bf_rne(r2); row[3] = f2bf_rne(r3);
            } else {
                float4 r; r.x = r0; r.y = r1; r.z = r2; r.w = r3;
                *(float4*)&h1s[p0 + i][c0] = r;
            }
        }
    }
    __syncthreads();

    // ---- Phase B ----
    if constexpr (MFMAB) {
        constexpr int NMT = NS / 16;       // M-tiles (points)
        constexpr int NKB = C1 / 32;       // K-blocks
        constexpr int NNT = C2 / 16;       // N-tiles total
        constexpr int NTW = NNT / 4;       // N-tiles per wave (4 waves)
        const int w    = tid >> 6;
        const int lane = tid & 63;
        const int lr   = lane & 15;        // row (A) / col (B, C/D)
        const int lg   = lane >> 4;        // k-group (A,B) / row-group (C/D)

        bf16x8 af[NMT][NKB];
#pragma unroll
        for (int mt = 0; mt < NMT; ++mt)
#pragma unroll
            for (int kb = 0; kb < NKB; ++kb)
                af[mt][kb] = *(const bf16x8*)&h1b[(size_t)(mt * 16 + lr) * LDHB + kb * 32 + lg * 8];

#pragma unroll
        for (int q = 0; q < NTW; ++q) {
            const int nt = w * NTW + q;
            const int c  = nt * 16 + lr;
            bf16x8 bfr[NKB];
#pragma unroll
            for (int kb = 0; kb < NKB; ++kb) {
#pragma unroll
                for (int j = 0; j < 8; ++j) {
                    const float wv = W2[(size_t)(kb * 32 + lg * 8 + j) * C2 + c];
                    bfr[kb][j] = (short)f2bf_rne(wv);
                }
            }
            const float bb = B2v[c];
            float colmax = 0.f;   // relu >= 0
#pragma unroll
            for (int mt = 0; mt < NMT; ++mt) {
                f32x4 ac = {bb, bb, bb, bb};
#pragma unroll
                for (int kb = 0; kb < NKB; ++kb)
                    ac = __builtin_amdgcn_mfma_f32_16x16x32_bf16(af[mt][kb], bfr[kb], ac, 0, 0, 0);
                float pm = fmaxf(fmaxf(ac[0], ac[1]), fmaxf(ac[2], ac[3]));
                pm = fmaxf(pm, __shfl_xor(pm, 16));
                pm = fmaxf(pm, __shfl_xor(pm, 32));
                colmax = fmaxf(colmax, pm);
            }
            if (lg == 0) outf[(size_t)g * C2 + c] = colmax;
        }
    } else {
        const int ct = tid % CT2, pb = tid / CT2;
        const int c0 = ct * 4;
        const int p0 = pb * PTSB;
        const float4 bb = *(const float4*)&B2v[c0];
        float4 ac[PTSB];
#pragma unroll
        for (int i = 0; i < PTSB; ++i) ac[i] = bb;
#pragma unroll 2
        for (int k = 0; k < C1; k += 4) {
            const float4 w0 = *(const float4*)&W2[(size_t)(k + 0) * C2 + c0];
            const float4 w1 = *(const float4*)&W2[(size_t)(k + 1) * C2 + c0];
            const float4 w2 = *(const float4*)&W2[(size_t)(k + 2) * C2 + c0];
            const float4 w3 = *(const float4*)&W2[(size_t)(k + 3) * C2 + c0];
#pragma unroll
            for (int i = 0; i < PTSB; ++i) {
                const float4 h = *(const float4*)&h1s[p0 + i][k];
                fma4(ac[i], h.x, w0); fma4(ac[i], h.y, w1);
                fma4(ac[i], h.z, w2); fma4(ac[i], h.w, w3);
            }
        }
        float4 m = make_float4(0.f, 0.f, 0.f, 0.f);   // relu>=0
#pragma unroll
        for (int i = 0; i < PTSB; ++i) {
            m.x = fmaxf(m.x, ac[i].x); m.y = fmaxf(m.y, ac[i].y);
            m.z = fmaxf(m.z, ac[i].z); m.w = fmaxf(m.w, ac[i].w);
        }
        if constexpr (GRP == 1) {
            *(float4*)&outf[(size_t)g * C2 + c0] = m;
        } else {
            *(float4*)&mpart[pb * C2 + c0] = m;
            __syncthreads();
            for (int c = tid; c < C2; c += T) {
                float mm = mpart[c];
#pragma unroll
                for (int q = 1; q < GRP; ++q) mm = fmaxf(mm, mpart[q * C2 + c]);
                outf[(size_t)g * C2 + c] = mm;
            }
        }
    }
}

// ---------------- Grouped 2-layer MLP + maxpool, FULL MFMA (stages 2/3) ----
// Both layers on mfma_f32_16x16x32_bf16 (bf16 inputs, fp32 accumulate).
// Gather all CIN at once (bf16, K zero-padded to KP), no K-chunking.
// MODE 1 semantics (feats array, xyz stride 3).
template<int NS, int CIN, int C1, int C2, int NSRC>
__global__ __launch_bounds__(256)
void sa_mlp_mfma_kernel(const float* __restrict__ sxyz, const float* __restrict__ sfeat,
                        const float* __restrict__ newxyz, const int* __restrict__ gidx,
                        const float* __restrict__ W1, const float* __restrict__ B1v,
                        const float* __restrict__ W2, const float* __restrict__ B2v,
                        float* __restrict__ outf, int S)
{
    constexpr int T    = 256;
    constexpr int KP   = ((CIN + 31) / 32) * 32;   // K padded
    constexpr int LDXB = KP + 8;                   // bf16 x row stride (16B mult)
    constexpr int KBA  = KP / 32;                  // phase-A K-blocks
    constexpr int NMT  = NS / 16;                  // M-tiles
    constexpr int NTA  = C1 / 16 / 4;              // phase-A N-tiles per wave
    constexpr int LDHB = C1 + 8;                   // bf16 h1 row stride
    constexpr int KBB  = C1 / 32;                  // phase-B K-blocks
    constexpr int NTB  = C2 / 16 / 4;              // phase-B N-tiles per wave
    constexpr int CF   = CIN - 3;
    static_assert(NS % 16 == 0 && C1 % 64 == 0 && C2 % 64 == 0, "");

    __shared__ __align__(16) unsigned short xb[NS * LDXB];
    __shared__ __align__(16) unsigned short h1b[NS * LDHB];
    __shared__ int gix[NS];

    const int g   = blockIdx.x;
    const int b   = g / S;
    const int tid = threadIdx.x;
    const int w    = tid >> 6;
    const int lane = tid & 63;
    const int lr   = lane & 15;        // row (A) / col (B, C/D)
    const int lg   = lane >> 4;        // k-group (A,B) / row-group (C/D)

    const float ctr0 = newxyz[(size_t)g * 3 + 0];
    const float ctr1 = newxyz[(size_t)g * 3 + 1];
    const float ctr2 = newxyz[(size_t)g * 3 + 2];
    for (int i = tid; i < NS; i += T) gix[i] = gidx[(size_t)g * NS + i];
    __syncthreads();

    // ---- gather full input as bf16 (rel-xyz in fp32, then RNE; pad = 0) ----
    for (int idx = tid; idx < NS * KP; idx += T) {
        const int p = idx / KP, k = idx - p * KP;
        float v = 0.f;
        if (k < CIN) {
            const int gi = gix[p];
            if (k < 3) {
                const float c = (k == 0) ? ctr0 : ((k == 1) ? ctr1 : ctr2);
                v = sxyz[((size_t)b * NSRC + gi) * 3 + k] - c;
            } else {
                v = sfeat[((size_t)b * NSRC + gi) * CF + (k - 3)];
            }
        }
        xb[(size_t)p * LDXB + k] = f2bf_rne(v);
    }
    __syncthreads();

    // ---- Phase A: h1 = relu(x @ W1 + b1) via MFMA ----
    {
        bf16x8 af[NMT][KBA];
#pragma unroll
        for (int mt = 0; mt < NMT; ++mt)
#pragma unroll
            for (int kb = 0; kb < KBA; ++kb)
                af[mt][kb] = *(const bf16x8*)&xb[(size_t)(mt * 16 + lr) * LDXB + kb * 32 + lg * 8];

#pragma unroll
        for (int q = 0; q < NTA; ++q) {
            const int nt = w * NTA + q;
            const int c  = nt * 16 + lr;
            bf16x8 bfr[KBA];
#pragma unroll
            for (int kb = 0; kb < KBA; ++kb) {
#pragma unroll
                for (int j = 0; j < 8; ++j) {
                    const int kk = kb * 32 + lg * 8 + j;
                    const float wv = (kk < CIN) ? W1[(size_t)kk * C1 + c] : 0.f;
                    bfr[kb][j] = (short)f2bf_rne(wv);
                }
            }
            const float bb = B1v[c];
#pragma unroll
            for (int mt = 0; mt < NMT; ++mt) {
                f32x4 ac = {bb, bb, bb, bb};
#pragma unroll
                for (int kb = 0; kb < KBA; ++kb)
                    ac = __builtin_amdgcn_mfma_f32_16x16x32_bf16(af[mt][kb], bfr[kb], ac, 0, 0, 0);
#pragma unroll
                for (int i = 0; i < 4; ++i) {
                    const int row = mt * 16 + lg * 4 + i;
                    h1b[(size_t)row * LDHB + c] = f2bf_rne(fmaxf(ac[i], 0.f));
                }
            }
        }
    }
    __syncthreads();

    // ---- Phase B: out = maxpool_p relu-free (bias included) via MFMA ----
    {
        bf16x8 af[NMT][KBB];
#pragma unroll
        for (int mt = 0; mt < NMT; ++mt)
#pragma unroll
            for (int kb = 0; kb < KBB; ++kb)
                af[mt][kb] = *(const bf16x8*)&h1b[(size_t)(mt * 16 + lr) * LDHB + kb * 32 + lg * 8];

#pragma unroll
        for (int q = 0; q < NTB; ++q) {
            const int nt = w * NTB + q;
            const int c  = nt * 16 + lr;
            bf16x8 bfr[KBB];
#pragma unroll
            for (int kb = 0; kb < KBB; ++kb) {
#pragma unroll
                for (int j = 0; j < 8; ++j) {
                    const float wv = W2[(size_t)(kb * 32 + lg * 8 + j) * C2 + c];
                    bfr[kb][j] = (short)f2bf_rne(wv);
                }
            }
            const float bb = B2v[c];
            float colmax = 0.f;   // relu >= 0
#pragma unroll
            for (int mt = 0; mt < NMT; ++mt) {
                f32x4 ac = {bb, bb, bb, bb};
#pragma unroll
                for (int kb = 0; kb < KBB; ++kb)
                    ac = __builtin_amdgcn_mfma_f32_16x16x32_bf16(af[mt][kb], bfr[kb], ac, 0, 0, 0);
                float pm = fmaxf(fmaxf(ac[0], ac[1]), fmaxf(ac[2], ac[3]));
                pm = fmaxf(pm, __shfl_xor(pm, 16));
                pm = fmaxf(pm, __shfl_xor(pm, 32));
                colmax = fmaxf(colmax, pm);
            }
            if (lg == 0) outf[(size_t)g * C2 + c] = colmax;
        }
    }
}

// ---------------- Head part 1: 4 points per block, 515->512->1024 MLP ----
__global__ __launch_bounds__(256)
void head1_kernel(const float* __restrict__ nxyz3, const float* __restrict__ feats3,
                  const float* __restrict__ w4a, const float* __restrict__ b4a,
                  const float* __restrict__ w4b, const float* __restrict__ b4b,
                  float* __restrict__ h4)
{
    const int g0  = blockIdx.x * 4;   // 4 consecutive (b,point) groups
    const int tid = threadIdx.x;
    __shared__ float xrow[4][516];
    __shared__ float h1s[4][512];
    for (int i = tid; i < 4 * 515; i += 256) {
        const int p = i / 515, k = i - p * 515;
        xrow[p][k] = (k < 3) ? nxyz3[(size_t)(g0 + p) * 3 + k]
                             : feats3[(size_t)(g0 + p) * 512 + (k - 3)];
    }
    __syncthreads();
#pragma unroll
    for (int cc = 0; cc < 2; ++cc) {
        const int c = tid + cc * 256;
        const float bb = b4a[c];
        float a0 = bb, a1 = bb, a2 = bb, a3 = bb;
#pragma unroll 4
        for (int k = 0; k < 515; ++k) {
            const float w = w4a[(size_t)k * 512 + c];
            a0 = fmaf(xrow[0][k], w, a0);
            a1 = fmaf(xrow[1][k], w, a1);
            a2 = fmaf(xrow[2][k], w, a2);
            a3 = fmaf(xrow[3][k], w, a3);
        }
        h1s[0][c] = fmaxf(a0, 0.f); h1s[1][c] = fmaxf(a1, 0.f);
        h1s[2][c] = fmaxf(a2, 0.f); h1s[3][c] = fmaxf(a3, 0.f);
    }
    __syncthreads();
    {
        const int c0 = tid * 4;
        const float4 bb = *(const float4*)&b4b[c0];
        float4 a0 = bb, a1 = bb, a2 = bb, a3 = bb;
#pragma unroll 4
        for (int k = 0; k < 512; ++k) {
            const float4 w = *(const float4*)&w4b[(size_t)k * 1024 + c0];
            fma4(a0, h1s[0][k], w);
            fma4(a1, h1s[1][k], w);
            fma4(a2, h1s[2][k], w);
            fma4(a3, h1s[3][k], w);
        }
        float4 r;
        r.x = fmaxf(a0.x, 0.f); r.y = fmaxf(a0.y, 0.f); r.z = fmaxf(a0.z, 0.f); r.w = fmaxf(a0.w, 0.f);
        *(float4*)&h4[(size_t)(g0 + 0) * 1024 + c0] = r;
        r.x = fmaxf(a1.x, 0.f); r.y = fmaxf(a1.y, 0.f); r.z = fmaxf(a1.z, 0.f); r.w = fmaxf(a1.w, 0.f);
        *(float4*)&h4[(size_t)(g0 + 1) * 1024 + c0] = r;
        r.x = fmaxf(a2.x, 0.f); r.y = fmaxf(a2.y, 0.f); r.z = fmaxf(a2.z, 0.f); r.w = fmaxf(a2.w, 0.f);
        *(float4*)&h4[(size_t)(g0 + 2) * 1024 + c0] = r;
        r.x = fmaxf(a3.x, 0.f); r.y = fmaxf(a3.y, 0.f); r.z = fmaxf(a3.z, 0.f); r.w = fmaxf(a3.w, 0.f);
        *(float4*)&h4[(size_t)(g0 + 3) * 1024 + c0] = r;
    }
}

// ---------------- Head part 2: maxpool(16) -> fc1(relu) -> fc2 -> bn-ish ----
__global__ __launch_bounds__(256)
void head2_kernel(const float* __restrict__ h4,
                  const float* __restrict__ fc1w, const float* __restrict__ fc1b,
                  const float* __restrict__ fc2w, const float* __restrict__ fc2b,
                  const float* __restrict__ gamma, const float* __restrict__ beta,
                  float* __restrict__ out)
{
    const int b   = blockIdx.x;
    const int tid = threadIdx.x;
    __shared__ float gm[1024], g1[1024];
    {
        const int c0 = tid * 4;
        float4 m = *(const float4*)&h4[((size_t)b * 16 + 0) * 1024 + c0];
#pragma unroll
        for (int p = 1; p < 16; ++p) {
            const float4 v = *(const float4*)&h4[((size_t)b * 16 + p) * 1024 + c0];
            m.x = fmaxf(m.x, v.x); m.y = fmaxf(m.y, v.y);
            m.z = fmaxf(m.z, v.z); m.w = fmaxf(m.w, v.w);
        }
        *(float4*)&gm[c0] = m;
    }
    __syncthreads();
    {
        const int c0 = tid * 4;
        float4 a = *(const float4*)&fc1b[c0];
#pragma unroll 4
        for (int k = 0; k < 1024; ++k) {
            const float4 w = *(const float4*)&fc1w[(size_t)k * 1024 + c0];
            fma4(a, gm[k], w);
        }
        g1[c0 + 0] = fmaxf(a.x, 0.f); g1[c0 + 1] = fmaxf(a.y, 0.f);
        g1[c0 + 2] = fmaxf(a.z, 0.f); g1[c0 + 3] = fmaxf(a.w, 0.f);
    }
    __syncthreads();
    if (tid < 128) {
        const float s = sqrtf(1.00001f);
        const int c = tid;
        float a = fc2b[c];
#pragma unroll 4
        for (int k = 0; k < 1024; ++k) a = fmaf(g1[k], fc2w[(size_t)k * 128 + c], a);
        out[(size_t)b * 128 + c] = (a / s) * gamma[c] + beta[c];
    }
}

// ---------------------------------------------------------------------------
extern "C" void kernel_launch(void* const* d_in, const int* in_sizes, int n_in,
                              void* d_out, int out_size, void* d_ws, size_t ws_size,
                              hipStream_t stream)
{
    const float* pc   = (const float*)d_in[0];
    const float* w1a  = (const float*)d_in[1];  const float* b1a = (const float*)d_in[2];
    const float* w1b  = (const float*)d_in[3];  const float* b1b = (const float*)d_in[4];
    const float* w2a  = (const float*)d_in[5];  const float* b2a = (const float*)d_in[6];
    const float* w2b  = (const float*)d_in[7];  const float* b2b = (const float*)d_in[8];
    const float* w3a  = (const float*)d_in[9];  const float* b3a = (const float*)d_in[10];
    const float* w3b  = (const float*)d_in[11]; const float* b3b = (const float*)d_in[12];
    const float* w4a  = (const float*)d_in[13]; const float* b4a = (const float*)d_in[14];
    const float* w4b  = (const float*)d_in[15]; const float* b4b = (const float*)d_in[16];
    const float* fc1w = (const float*)d_in[17]; const float* fc1b = (const float*)d_in[18];
    const float* fc2w = (const float*)d_in[19]; const float* fc2b = (const float*)d_in[20];
    const float* gam  = (const float*)d_in[21]; const float* bet  = (const float*)d_in[22];
    float* out = (float*)d_out;

    char* ws = (char*)d_ws;
    size_t off = 0;
    auto alloc = [&](size_t bytes) -> void* {
        void* p = ws + off;
        off = (off + bytes + 255) & ~(size_t)255;
        return p;
    };
    float* nxyz1  = (float*)alloc((size_t)32 * 256 * 3 * 4);
    int*   gidx1  = (int*)  alloc((size_t)32 * 256 * 64 * 4);
    float* feats1 = (float*)alloc((size_t)32 * 256 * 128 * 4);
    float* nxyz2  = (float*)alloc((size_t)32 * 64 * 3 * 4);
    int*   gidx2  = (int*)  alloc((size_t)32 * 64 * 64 * 4);
    float* feats2 = (float*)alloc((size_t)32 * 64 * 256 * 4);
    float* nxyz3  = (float*)alloc((size_t)32 * 16 * 3 * 4);
    int*   gidx3  = (int*)  alloc((size_t)32 * 16 * 32 * 4);
    float* feats3 = (float*)alloc((size_t)32 * 16 * 512 * 4);
    float* h4     = (float*)alloc((size_t)32 * 16 * 1024 * 4);

    const float r2a = (float)(0.1 * 0.1);
    const float r2b = (float)(0.2 * 0.2);
    const float r2c = (float)(0.4 * 0.4);

    // ---- All three FPS stages fused (one block per batch, 4-wave config) ----
    fps_fused_kernel<<<32, 256, 0, stream>>>(pc, nxyz1, nxyz2, nxyz3);

    // ---- Ball queries ----
    bq_kernel<4096, 64, 6><<<(32 * 256 + 3) / 4, 256, 0, stream>>>(pc, nxyz1, gidx1, r2a, 256, 32 * 256);
    bq_kernel<256, 64, 3><<<(32 * 64 + 3) / 4, 256, 0, stream>>>(nxyz1, nxyz2, gidx2, r2b, 64, 32 * 64);
    bq_kernel<64, 32, 3><<<(32 * 16 + 3) / 4, 256, 0, stream>>>(nxyz2, nxyz3, gidx3, r2c, 16, 32 * 16);

    // ---- SA MLPs: stage1 hybrid (fp32 A / MFMA B); stages 2,3 full MFMA ----
    sa_mlp2_kernel<64, 9, 64, 128, 4096, 0, true><<<32 * 256, 256, 0, stream>>>(
        pc, pc, nxyz1, gidx1, w1a, b1a, w1b, b1b, feats1, 256);
    sa_mlp_mfma_kernel<64, 131, 128, 256, 256><<<32 * 64, 256, 0, stream>>>(
        nxyz1, feats1, nxyz2, gidx2, w2a, b2a, w2b, b2b, feats2, 64);
    sa_mlp_mfma_kernel<32, 259, 256, 512, 64><<<32 * 16, 256, 0, stream>>>(
        nxyz2, feats2, nxyz3, gidx3, w3a, b3a, w3b, b3b, feats3, 16);

    // ---- Head: 4 points per block (128 blocks), then maxpool+fc in head2
    head1_kernel<<<32 * 16 / 4, 256, 0, stream>>>(nxyz3, feats3, w4a, b4a, w4b, b4b, h4);
    head2_kernel<<<32, 256, 0, stream>>>(h4, fc1w, fc1b, fc2w, fc2b, gam, bet, out);
}

// Round 20
// 740.200 us; speedup vs baseline: 1.6571x; 1.1182x over previous
//
#include <hip/hip_runtime.h>

#define DEV static __device__ __forceinline__

using bf16x8 = __attribute__((ext_vector_type(8))) short;   // 8 bf16 (4 VGPRs)
using f32x4  = __attribute__((ext_vector_type(4))) float;

DEV float sqdist(float dx, float dy, float dz) {
    // ((dx*dx + dy*dy) + dz*dz) with no FMA contraction — must match numpy f32
    return __fadd_rn(__fadd_rn(__fmul_rn(dx, dx), __fmul_rn(dy, dy)), __fmul_rn(dz, dz));
}

DEV void fma4(float4& acc, float h, const float4& w) {
    acc.x = fmaf(h, w.x, acc.x); acc.y = fmaf(h, w.y, acc.y);
    acc.z = fmaf(h, w.z, acc.z); acc.w = fmaf(h, w.w, acc.w);
}

DEV unsigned short f2bf_rne(float f) {   // fp32 -> bf16, round-nearest-even
    unsigned u = __builtin_bit_cast(unsigned, f);
    return (unsigned short)((u + 0x7FFFu + ((u >> 16) & 1u)) >> 16);
}

// ---- weight pre-swizzle: fp32 W[K][C] -> bf16 fragment layout ----
// out[((nt*KB+kb)*64+lane)*8 + j] = bf16(W[kb*32+(lane>>4)*8+j][nt*16+(lane&15)])
// (zero-padded for k >= KSRC). Same f2bf_rne as before => bit-identical math.
template<int KSRC, int KB, int C>
__global__ __launch_bounds__(256)
void wswz_kernel(const float* __restrict__ W, unsigned short* __restrict__ out)
{
    constexpr int NT = C / 16;
    constexpr int TOTAL = NT * KB * 64 * 8;
    for (int idx = blockIdx.x * 256 + threadIdx.x; idx < TOTAL; idx += gridDim.x * 256) {
        const int j    = idx & 7;
        const int lane = (idx >> 3) & 63;
        const int fb   = idx >> 9;          // nt*KB + kb
        const int kb   = fb % KB, nt = fb / KB;
        const int k    = kb * 32 + (lane >> 4) * 8 + j;
        const int c    = nt * 16 + (lane & 15);
        const float v  = (k < KSRC) ? W[(size_t)k * C + c] : 0.f;
        out[idx] = f2bf_rne(v);
    }
}

// ---- argmax combine steps (value desc, index asc on ties) ----
template<int CTRL>
DEV int dpp_mov(int v) {
    return __builtin_amdgcn_update_dpp(v, v, CTRL, 0xF, 0xF, false);
}
template<int CTRL>
DEV void red_step_dpp(float& bv, int& bi) {
    float ov = __builtin_bit_cast(float, dpp_mov<CTRL>(__builtin_bit_cast(int, bv)));
    int   oi = dpp_mov<CTRL>(bi);
    if (ov > bv || (ov == bv && oi < bi)) { bv = ov; bi = oi; }
}
// full 64-lane argmax; result valid in lane 63
DEV void wave_argmax(float& bv, int& bi) {
    red_step_dpp<0xB1>(bv, bi);    // quad_perm xor 1
    red_step_dpp<0x4E>(bv, bi);    // quad_perm xor 2
    red_step_dpp<0x141>(bv, bi);   // row_half_mirror (xor 4)
    red_step_dpp<0x140>(bv, bi);   // row_mirror (xor 8)
    red_step_dpp<0x142>(bv, bi);   // row_bcast15
    red_step_dpp<0x143>(bv, bi);   // row_bcast31 -> lane 63 has full result
}

// ---- single-wave FPS over LDS points (no barriers) ----
template<int N, int NPOINT>
DEV void fps_wave64(const float4* pts, float* sout, int lane) {
    constexpr int K = (N + 63) / 64;
    float rx[K], ry[K], rz[K], d[K];
#pragma unroll
    for (int k = 0; k < K; ++k) {
        const float4 c = pts[lane + k * 64];
        rx[k] = c.x; ry[k] = c.y; rz[k] = c.z; d[k] = 1e10f;
    }
    const float4 c0 = pts[0];
    float cx = c0.x, cy = c0.y, cz = c0.z;
    for (int s = 0; s < NPOINT; ++s) {
        if (lane == 0) { sout[s * 3 + 0] = cx; sout[s * 3 + 1] = cy; sout[s * 3 + 2] = cz; }
        float bestv = -1.0f; int besti = 0x7fffffff;
#pragma unroll
        for (int k = 0; k < K; ++k) {
            float d2 = sqdist(rx[k] - cx, ry[k] - cy, rz[k] - cz);
            d[k] = fminf(d[k], d2);
            if (d[k] > bestv) { bestv = d[k]; besti = lane + k * 64; }
        }
        wave_argmax(bestv, besti);
        const int far = __builtin_amdgcn_readlane(besti, 63);
        const float4 c = pts[far];
        cx = c.x; cy = c.y; cz = c.z;
    }
}

// ---------------- Fused FPS (all 3 stages) — measured-floor config ----
__global__ __launch_bounds__(256)
void fps_fused_kernel(const float* __restrict__ pc,
                      float* __restrict__ nxyz1, float* __restrict__ nxyz2,
                      float* __restrict__ nxyz3)
{
    constexpr int N1 = 4096, NP1 = 256, NP2 = 64, NP3 = 16, T = 256, NW = T / 64;
    constexpr int K = N1 / T;
    __shared__ float4 pxyz[N1];
    __shared__ float  sout1[NP1 * 3];
    __shared__ float  sout2[NP2 * 3];
    __shared__ float  sout3[NP3 * 3];
    __shared__ float  rv[2][NW];
    __shared__ int    ri[2][NW];

    const int b = blockIdx.x, tid = threadIdx.x;
    const int w = tid >> 6, lane = tid & 63;
    const float* base = pc + (size_t)b * N1 * 6;

    float rx[K], ry[K], rz[K], d[K];
#pragma unroll
    for (int k = 0; k < K; ++k) {
        const int p = tid + k * T;
        const float x = base[p * 6 + 0];
        const float y = base[p * 6 + 1];
        const float z = base[p * 6 + 2];
        pxyz[p] = make_float4(x, y, z, 0.f);
        rx[k] = x; ry[k] = y; rz[k] = z;
        d[k] = 1e10f;
    }
    __syncthreads();

    // ---- stage 1 ----
    {
        const float4 c0 = pxyz[0];
        float cx = c0.x, cy = c0.y, cz = c0.z;
        for (int s = 0; s < NP1; ++s) {
            if (tid == 0) { sout1[s * 3 + 0] = cx; sout1[s * 3 + 1] = cy; sout1[s * 3 + 2] = cz; }
            float bestv = -1.0f; int besti = 0x7fffffff;
#pragma unroll
            for (int k = 0; k < K; ++k) {
                float d2 = sqdist(rx[k] - cx, ry[k] - cy, rz[k] - cz);
                d[k] = fminf(d[k], d2);
                if (d[k] > bestv) { bestv = d[k]; besti = tid + k * T; }  // k asc => lowest p
            }
            wave_argmax(bestv, besti);

            const int par = s & 1;
            if (lane == 63) { rv[par][w] = bestv; ri[par][w] = besti; }
            __syncthreads();
            float bvv = rv[par][0]; int bii = ri[par][0];
#pragma unroll
            for (int q = 1; q < NW; ++q) {
                const float qv = rv[par][q]; const int qi = ri[par][q];
                if (qv > bvv || (qv == bvv && qi < bii)) { bvv = qv; bii = qi; }
            }
            const float4 c = pxyz[bii];
            cx = c.x; cy = c.y; cz = c.z;
        }
    }

    // ---- stages 2 + 3 on wave 0 ----
    if (w == 0) {
        for (int i = lane; i < NP1; i += 64)
            pxyz[i] = make_float4(sout1[i * 3 + 0], sout1[i * 3 + 1], sout1[i * 3 + 2], 0.f);
        fps_wave64<NP1, NP2>(pxyz, sout2, lane);
        for (int i = lane; i < NP2; i += 64)
            pxyz[i] = make_float4(sout2[i * 3 + 0], sout2[i * 3 + 1], sout2[i * 3 + 2], 0.f);
        fps_wave64<NP2, NP3>(pxyz, sout3, lane);
    }
    __syncthreads();

    float* o1 = nxyz1 + (size_t)b * NP1 * 3;
    for (int i = tid; i < NP1 * 3; i += T) o1[i] = sout1[i];
    float* o2 = nxyz2 + (size_t)b * NP2 * 3;
    if (tid < NP2 * 3) o2[tid] = sout2[tid];
    float* o3 = nxyz3 + (size_t)b * NP3 * 3;
    if (tid < NP3 * 3) o3[tid] = sout3[tid];
}

// ---------------- Ball query -----------------
template<int N, int NSAMP, int STRIDE>
__global__ __launch_bounds__(256)
void bq_kernel(const float* __restrict__ xyz, const float* __restrict__ newxyz,
               int* __restrict__ gidx, float r2, int S, int total)
{
    const int wid = blockIdx.x * 4 + (threadIdx.x >> 6);
    if (wid >= total) return;
    const int lane = threadIdx.x & 63;
    const int b = wid / S;
    const float cx = newxyz[(size_t)wid * 3 + 0];
    const float cy = newxyz[(size_t)wid * 3 + 1];
    const float cz = newxyz[(size_t)wid * 3 + 2];
    const float* base = xyz + (size_t)b * N * STRIDE;
    int* out = gidx + (size_t)wid * NSAMP;

    int count = 0, first = N - 1;
    constexpr int NCH = (N + 63) / 64;
    for (int ch = 0; ch < NCH; ++ch) {
        int p = ch * 64 + lane;
        bool pred = false;
        if (N % 64 == 0 || p < N) {
            float dx = base[p * STRIDE + 0] - cx;
            float dy = base[p * STRIDE + 1] - cy;
            float dz = base[p * STRIDE + 2] - cz;
            pred = sqdist(dx, dy, dz) < r2;
        }
        unsigned long long m = __ballot(pred);
        if (m) {
            if (count == 0) first = ch * 64 + __builtin_ctzll(m);
            int pos = count + __popcll(m & ((1ull << lane) - 1ull));
            if (pred && pos < NSAMP) out[pos] = p;
            count += __popcll(m);
            if (count >= NSAMP) break;
        }
    }
    if (count > NSAMP) count = NSAMP;
    for (int pos = count + lane; pos < NSAMP; pos += 64) out[pos] = first;
}

// ---------------- Grouped 2-layer MLP + maxpool (hybrid: fp32 A / MFMA B) ----
// Used for stage 1 (CIN=9). MODE 0: xyz stride 6, feats = pc permuted.
// W2s = pre-swizzled bf16 W2 fragments.
template<int NS, int CIN, int C1, int C2, int NSRC, int MODE>
__global__ __launch_bounds__(256)
void sa_mlp2_kernel(const float* __restrict__ sxyz, const float* __restrict__ sfeat,
                    const float* __restrict__ newxyz, const int* __restrict__ gidx,
                    const float* __restrict__ W1, const float* __restrict__ B1v,
                    const unsigned short* __restrict__ W2s, const float* __restrict__ B2v,
                    float* __restrict__ outf, int S)
{
    constexpr int T    = 256;
    constexpr int KCC  = (CIN < 32) ? CIN : 32;            // k-chunk length
    constexpr int KCP0 = ((KCC + 3) / 4) * 4 + 4;
    constexpr int KCP  = ((KCP0 / 4) % 2 == 0) ? KCP0 + 4 : KCP0;  // odd quad stride
    constexpr int NPT  = NS / 4;
    constexpr int NCT1 = C1 / 4;
    constexpr int TPT  = (NPT * NCT1) / T;                 // phase-A tiles per thread
    constexpr int LDHB = C1 + 8;                           // bf16 h1 row stride (16B mult)
    constexpr int XS   = (MODE == 0) ? 6 : 3;
    constexpr int CF   = CIN - 3;
    static_assert(NS % 16 == 0 && C1 % 32 == 0 && C2 % 64 == 0, "");
    static_assert((NPT * NCT1) % T == 0 && TPT >= 1, "");

    __shared__ float xgc[NS][KCP];
    __shared__ __align__(16) unsigned short h1b[NS * LDHB];
    __shared__ int   gix[NS];

    const int g   = blockIdx.x;
    const int b   = g / S;
    const int tid = threadIdx.x;

    const float ctr0 = newxyz[(size_t)g * 3 + 0];
    const float ctr1 = newxyz[(size_t)g * 3 + 1];
    const float ctr2 = newxyz[(size_t)g * 3 + 2];
    for (int i = tid; i < NS; i += T) gix[i] = gidx[(size_t)g * NS + i];
    __syncthreads();

    // ---- Phase A: layer 1, K-chunked, accumulators in registers (fp32) ----
    float4 acc[TPT][4];
#pragma unroll
    for (int j = 0; j < TPT; ++j) {
        const int tl = tid + j * T;
        const int ct = tl % NCT1;
        const float4 bb = *(const float4*)&B1v[ct * 4];
#pragma unroll
        for (int i = 0; i < 4; ++i) acc[j][i] = bb;
    }

    const int nchunk = (CIN + KCC - 1) / KCC;
    for (int cch = 0; cch < nchunk; ++cch) {
        const int k0 = cch * KCC;
        const int kcLen = (CIN - k0 < KCC) ? (CIN - k0) : KCC;
        if (cch > 0) __syncthreads();
        // gather chunk
        for (int idx = tid; idx < NS * kcLen; idx += T) {
            const int p = idx / kcLen, kk = idx - p * kcLen, k = k0 + kk;
            float v;
            const int gi = gix[p];
            if (k < 3) {
                const float c = (k == 0) ? ctr0 : ((k == 1) ? ctr1 : ctr2);
                v = sxyz[((size_t)b * NSRC + gi) * XS + k] - c;
            } else if constexpr (MODE == 0) {
                const int j2 = k - 3;
                v = sfeat[((size_t)b * NSRC + gi) * 6 + (j2 < 3 ? 3 + j2 : j2 - 3)];
            } else {
                v = sfeat[((size_t)b * NSRC + gi) * CF + (k - 3)];
            }
            xgc[p][kk] = v;
        }
        __syncthreads();
        // compute chunk
#pragma unroll
        for (int j = 0; j < TPT; ++j) {
            const int tl = tid + j * T;
            const int pt = tl / NCT1, ct = tl % NCT1;
            const int p0 = pt * 4, c0 = ct * 4;
            int kk = 0;
            for (; kk + 4 <= kcLen; kk += 4) {
                const float4 xa = *(const float4*)&xgc[p0 + 0][kk];
                const float4 xb = *(const float4*)&xgc[p0 + 1][kk];
                const float4 xc = *(const float4*)&xgc[p0 + 2][kk];
                const float4 xd = *(const float4*)&xgc[p0 + 3][kk];
                const float4 w0 = *(const float4*)&W1[(size_t)(k0 + kk + 0) * C1 + c0];
                const float4 w1 = *(const float4*)&W1[(size_t)(k0 + kk + 1) * C1 + c0];
                const float4 w2 = *(const float4*)&W1[(size_t)(k0 + kk + 2) * C1 + c0];
                const float4 w3 = *(const float4*)&W1[(size_t)(k0 + kk + 3) * C1 + c0];
                fma4(acc[j][0], xa.x, w0); fma4(acc[j][0], xa.y, w1); fma4(acc[j][0], xa.z, w2); fma4(acc[j][0], xa.w, w3);
                fma4(acc[j][1], xb.x, w0); fma4(acc[j][1], xb.y, w1); fma4(acc[j][1], xb.z, w2); fma4(acc[j][1], xb.w, w3);
                fma4(acc[j][2], xc.x, w0); fma4(acc[j][2], xc.y, w1); fma4(acc[j][2], xc.z, w2); fma4(acc[j][2], xc.w, w3);
                fma4(acc[j][3], xd.x, w0); fma4(acc[j][3], xd.y, w1); fma4(acc[j][3], xd.z, w2); fma4(acc[j][3], xd.w, w3);
            }
            for (; kk < kcLen; ++kk) {
                const float4 w = *(const float4*)&W1[(size_t)(k0 + kk) * C1 + c0];
                fma4(acc[j][0], xgc[p0 + 0][kk], w);
                fma4(acc[j][1], xgc[p0 + 1][kk], w);
                fma4(acc[j][2], xgc[p0 + 2][kk], w);
                fma4(acc[j][3], xgc[p0 + 3][kk], w);
            }
        }
    }
    // write h1 (relu) as bf16
    __syncthreads();
#pragma unroll
    for (int j = 0; j < TPT; ++j) {
        const int tl = tid + j * T;
        const int pt = tl / NCT1, ct = tl % NCT1;
        const int p0 = pt * 4, c0 = ct * 4;
#pragma unroll
        for (int i = 0; i < 4; ++i) {
            unsigned short* row = &h1b[(size_t)(p0 + i) * LDHB + c0];
            row[0] = f2bf_rne(fmaxf(acc[j][i].x, 0.f));
            row[1] = f2bf_rne(fmaxf(acc[j][i].y, 0.f));
            row[2] = f2bf_rne(fmaxf(acc[j][i].z, 0.f));
            row[3] = f2bf_rne(fmaxf(acc[j][i].w, 0.f));
        }
    }
    __syncthreads();

    // ---- Phase B: MFMA (pre-swizzled W2 fragments) ----
    {
        constexpr int NMT = NS / 16;       // M-tiles (points)
        constexpr int NKB = C1 / 32;       // K-blocks
        constexpr int NNT = C2 / 16;       // N-tiles total
        constexpr int NTW = NNT / 4;       // N-tiles per wave (4 waves)
        const int w    = tid >> 6;
        const int lane = tid & 63;
        const int lr   = lane & 15;
        const int lg   = lane >> 4;

        bf16x8 af[NMT][NKB];
#pragma unroll
        for (int mt = 0; mt < NMT; ++mt)
#pragma unroll
            for (int kb = 0; kb < NKB; ++kb)
                af[mt][kb] = *(const bf16x8*)&h1b[(size_t)(mt * 16 + lr) * LDHB + kb * 32 + lg * 8];

#pragma unroll
        for (int q = 0; q < NTW; ++q) {
            const int nt = w * NTW + q;
            const int c  = nt * 16 + lr;
            bf16x8 bfr[NKB];
#pragma unroll
            for (int kb = 0; kb < NKB; ++kb)
                bfr[kb] = *(const bf16x8*)&W2s[(size_t)((nt * NKB + kb) * 64 + lane) * 8];
            const float bb = B2v[c];
            float colmax = 0.f;   // relu >= 0
#pragma unroll
            for (int mt = 0; mt < NMT; ++mt) {
                f32x4 ac = {bb, bb, bb, bb};
#pragma unroll
                for (int kb = 0; kb < NKB; ++kb)
                    ac = __builtin_amdgcn_mfma_f32_16x16x32_bf16(af[mt][kb], bfr[kb], ac, 0, 0, 0);
                float pm = fmaxf(fmaxf(ac[0], ac[1]), fmaxf(ac[2], ac[3]));
                pm = fmaxf(pm, __shfl_xor(pm, 16));
                pm = fmaxf(pm, __shfl_xor(pm, 32));
                colmax = fmaxf(colmax, pm);
            }
            if (lg == 0) outf[(size_t)g * C2 + c] = colmax;
        }
    }
}

// ---------------- Grouped 2-layer MLP + maxpool, FULL MFMA (stages 2/3) ----
// Both layers on mfma_f32_16x16x32_bf16; W1s/W2s pre-swizzled bf16 fragments.
template<int NS, int CIN, int C1, int C2, int NSRC>
__global__ __launch_bounds__(256)
void sa_mlp_mfma_kernel(const float* __restrict__ sxyz, const float* __restrict__ sfeat,
                        const float* __restrict__ newxyz, const int* __restrict__ gidx,
                        const unsigned short* __restrict__ W1s, const float* __restrict__ B1v,
                        const unsigned short* __restrict__ W2s, const float* __restrict__ B2v,
                        float* __restrict__ outf, int S)
{
    constexpr int T    = 256;
    constexpr int KP   = ((CIN + 31) / 32) * 32;   // K padded
    constexpr int LDXB = KP + 8;                   // bf16 x row stride (16B mult)
    constexpr int KBA  = KP / 32;                  // phase-A K-blocks
    constexpr int NMT  = NS / 16;                  // M-tiles
    constexpr int NTA  = C1 / 16 / 4;              // phase-A N-tiles per wave
    constexpr int LDHB = C1 + 8;                   // bf16 h1 row stride
    constexpr int KBB  = C1 / 32;                  // phase-B K-blocks
    constexpr int NTB  = C2 / 16 / 4;              // phase-B N-tiles per wave
    constexpr int CF   = CIN - 3;
    static_assert(NS % 16 == 0 && C1 % 64 == 0 && C2 % 64 == 0, "");

    __shared__ __align__(16) unsigned short xb[NS * LDXB];
    __shared__ __align__(16) unsigned short h1b[NS * LDHB];
    __shared__ int gix[NS];

    const int g   = blockIdx.x;
    const int b   = g / S;
    const int tid = threadIdx.x;
    const int w    = tid >> 6;
    const int lane = tid & 63;
    const int lr   = lane & 15;
    const int lg   = lane >> 4;

    const float ctr0 = newxyz[(size_t)g * 3 + 0];
    const float ctr1 = newxyz[(size_t)g * 3 + 1];
    const float ctr2 = newxyz[(size_t)g * 3 + 2];
    for (int i = tid; i < NS; i += T) gix[i] = gidx[(size_t)g * NS + i];
    __syncthreads();

    // ---- gather full input as bf16 (rel-xyz in fp32, then RNE; pad = 0) ----
    for (int idx = tid; idx < NS * KP; idx += T) {
        const int p = idx / KP, k = idx - p * KP;
        float v = 0.f;
        if (k < CIN) {
            const int gi = gix[p];
            if (k < 3) {
                const float c = (k == 0) ? ctr0 : ((k == 1) ? ctr1 : ctr2);
                v = sxyz[((size_t)b * NSRC + gi) * 3 + k] - c;
            } else {
                v = sfeat[((size_t)b * NSRC + gi) * CF + (k - 3)];
            }
        }
        xb[(size_t)p * LDXB + k] = f2bf_rne(v);
    }
    __syncthreads();

    // ---- Phase A: h1 = relu(x @ W1 + b1) via MFMA ----
    {
        bf16x8 af[NMT][KBA];
#pragma unroll
        for (int mt = 0; mt < NMT; ++mt)
#pragma unroll
            for (int kb = 0; kb < KBA; ++kb)
                af[mt][kb] = *(const bf16x8*)&xb[(size_t)(mt * 16 + lr) * LDXB + kb * 32 + lg * 8];

#pragma unroll
        for (int q = 0; q < NTA; ++q) {
            const int nt = w * NTA + q;
            const int c  = nt * 16 + lr;
            bf16x8 bfr[KBA];
#pragma unroll
            for (int kb = 0; kb < KBA; ++kb)
                bfr[kb] = *(const bf16x8*)&W1s[(size_t)((nt * KBA + kb) * 64 + lane) * 8];
            const float bb = B1v[c];
#pragma unroll
            for (int mt = 0; mt < NMT; ++mt) {
                f32x4 ac = {bb, bb, bb, bb};
#pragma unroll
                for (int kb = 0; kb < KBA; ++kb)
                    ac = __builtin_amdgcn_mfma_f32_16x16x32_bf16(af[mt][kb], bfr[kb], ac, 0, 0, 0);
#pragma unroll
                for (int i = 0; i < 4; ++i) {
                    const int row = mt * 16 + lg * 4 + i;
                    h1b[(size_t)row * LDHB + c] = f2bf_rne(fmaxf(ac[i], 0.f));
                }
            }
        }
    }
    __syncthreads();

    // ---- Phase B: out = maxpool_p (h1 @ W2 + b2) via MFMA ----
    {
        bf16x8 af[NMT][KBB];
#pragma unroll
        for (int mt = 0; mt < NMT; ++mt)
#pragma unroll
            for (int kb = 0; kb < KBB; ++kb)
                af[mt][kb] = *(const bf16x8*)&h1b[(size_t)(mt * 16 + lr) * LDHB + kb * 32 + lg * 8];

#pragma unroll
        for (int q = 0; q < NTB; ++q) {
            const int nt = w * NTB + q;
            const int c  = nt * 16 + lr;
            bf16x8 bfr[KBB];
#pragma unroll
            for (int kb = 0; kb < KBB; ++kb)
                bfr[kb] = *(const bf16x8*)&W2s[(size_t)((nt * KBB + kb) * 64 + lane) * 8];
            const float bb = B2v[c];
            float colmax = 0.f;   // relu >= 0
#pragma unroll
            for (int mt = 0; mt < NMT; ++mt) {
                f32x4 ac = {bb, bb, bb, bb};
#pragma unroll
                for (int kb = 0; kb < KBB; ++kb)
                    ac = __builtin_amdgcn_mfma_f32_16x16x32_bf16(af[mt][kb], bfr[kb], ac, 0, 0, 0);
                float pm = fmaxf(fmaxf(ac[0], ac[1]), fmaxf(ac[2], ac[3]));
                pm = fmaxf(pm, __shfl_xor(pm, 16));
                pm = fmaxf(pm, __shfl_xor(pm, 32));
                colmax = fmaxf(colmax, pm);
            }
            if (lg == 0) outf[(size_t)g * C2 + c] = colmax;
        }
    }
}

// ---------------- Head part 1: 4 points per block, 515->512->1024 MLP ----
__global__ __launch_bounds__(256)
void head1_kernel(const float* __restrict__ nxyz3, const float* __restrict__ feats3,
                  const float* __restrict__ w4a, const float* __restrict__ b4a,
                  const float* __restrict__ w4b, const float* __restrict__ b4b,
                  float* __restrict__ h4)
{
    const int g0  = blockIdx.x * 4;   // 4 consecutive (b,point) groups
    const int tid = threadIdx.x;
    __shared__ float xrow[4][516];
    __shared__ float h1s[4][512];
    for (int i = tid; i < 4 * 515; i += 256) {
        const int p = i / 515, k = i - p * 515;
        xrow[p][k] = (k < 3) ? nxyz3[(size_t)(g0 + p) * 3 + k]
                             : feats3[(size_t)(g0 + p) * 512 + (k - 3)];
    }
    __syncthreads();
#pragma unroll
    for (int cc = 0; cc < 2; ++cc) {
        const int c = tid + cc * 256;
        const float bb = b4a[c];
        float a0 = bb, a1 = bb, a2 = bb, a3 = bb;
#pragma unroll 4
        for (int k = 0; k < 515; ++k) {
            const float w = w4a[(size_t)k * 512 + c];
            a0 = fmaf(xrow[0][k], w, a0);
            a1 = fmaf(xrow[1][k], w, a1);
            a2 = fmaf(xrow[2][k], w, a2);
            a3 = fmaf(xrow[3][k], w, a3);
        }
        h1s[0][c] = fmaxf(a0, 0.f); h1s[1][c] = fmaxf(a1, 0.f);
        h1s[2][c] = fmaxf(a2, 0.f); h1s[3][c] = fmaxf(a3, 0.f);
    }
    __syncthreads();
    {
        const int c0 = tid * 4;
        const float4 bb = *(const float4*)&b4b[c0];
        float4 a0 = bb, a1 = bb, a2 = bb, a3 = bb;
#pragma unroll 4
        for (int k = 0; k < 512; ++k) {
            const float4 w = *(const float4*)&w4b[(size_t)k * 1024 + c0];
            fma4(a0, h1s[0][k], w);
            fma4(a1, h1s[1][k], w);
            fma4(a2, h1s[2][k], w);
            fma4(a3, h1s[3][k], w);
        }
        float4 r;
        r.x = fmaxf(a0.x, 0.f); r.y = fmaxf(a0.y, 0.f); r.z = fmaxf(a0.z, 0.f); r.w = fmaxf(a0.w, 0.f);
        *(float4*)&h4[(size_t)(g0 + 0) * 1024 + c0] = r;
        r.x = fmaxf(a1.x, 0.f); r.y = fmaxf(a1.y, 0.f); r.z = fmaxf(a1.z, 0.f); r.w = fmaxf(a1.w, 0.f);
        *(float4*)&h4[(size_t)(g0 + 1) * 1024 + c0] = r;
        r.x = fmaxf(a2.x, 0.f); r.y = fmaxf(a2.y, 0.f); r.z = fmaxf(a2.z, 0.f); r.w = fmaxf(a2.w, 0.f);
        *(float4*)&h4[(size_t)(g0 + 2) * 1024 + c0] = r;
        r.x = fmaxf(a3.x, 0.f); r.y = fmaxf(a3.y, 0.f); r.z = fmaxf(a3.z, 0.f); r.w = fmaxf(a3.w, 0.f);
        *(float4*)&h4[(size_t)(g0 + 3) * 1024 + c0] = r;
    }
}

// ---------------- Head part 2: maxpool(16) -> fc1(relu) -> fc2 -> bn-ish ----
__global__ __launch_bounds__(256)
void head2_kernel(const float* __restrict__ h4,
                  const float* __restrict__ fc1w, const float* __restrict__ fc1b,
                  const float* __restrict__ fc2w, const float* __restrict__ fc2b,
                  const float* __restrict__ gamma, const float* __restrict__ beta,
                  float* __restrict__ out)
{
    const int b   = blockIdx.x;
    const int tid = threadIdx.x;
    __shared__ float gm[1024], g1[1024];
    {
        const int c0 = tid * 4;
        float4 m = *(const float4*)&h4[((size_t)b * 16 + 0) * 1024 + c0];
#pragma unroll
        for (int p = 1; p < 16; ++p) {
            const float4 v = *(const float4*)&h4[((size_t)b * 16 + p) * 1024 + c0];
            m.x = fmaxf(m.x, v.x); m.y = fmaxf(m.y, v.y);
            m.z = fmaxf(m.z, v.z); m.w = fmaxf(m.w, v.w);
        }
        *(float4*)&gm[c0] = m;
    }
    __syncthreads();
    {
        const int c0 = tid * 4;
        float4 a = *(const float4*)&fc1b[c0];
#pragma unroll 4
        for (int k = 0; k < 1024; ++k) {
            const float4 w = *(const float4*)&fc1w[(size_t)k * 1024 + c0];
            fma4(a, gm[k], w);
        }
        g1[c0 + 0] = fmaxf(a.x, 0.f); g1[c0 + 1] = fmaxf(a.y, 0.f);
        g1[c0 + 2] = fmaxf(a.z, 0.f); g1[c0 + 3] = fmaxf(a.w, 0.f);
    }
    __syncthreads();
    if (tid < 128) {
        const float s = sqrtf(1.00001f);
        const int c = tid;
        float a = fc2b[c];
#pragma unroll 4
        for (int k = 0; k < 1024; ++k) a = fmaf(g1[k], fc2w[(size_t)k * 128 + c], a);
        out[(size_t)b * 128 + c] = (a / s) * gamma[c] + beta[c];
    }
}

// ---------------------------------------------------------------------------
extern "C" void kernel_launch(void* const* d_in, const int* in_sizes, int n_in,
                              void* d_out, int out_size, void* d_ws, size_t ws_size,
                              hipStream_t stream)
{
    const float* pc   = (const float*)d_in[0];
    const float* w1a  = (const float*)d_in[1];  const float* b1a = (const float*)d_in[2];
    const float* w1b  = (const float*)d_in[3];  const float* b1b = (const float*)d_in[4];
    const float* w2a  = (const float*)d_in[5];  const float* b2a = (const float*)d_in[6];
    const float* w2b  = (const float*)d_in[7];  const float* b2b = (const float*)d_in[8];
    const float* w3a  = (const float*)d_in[9];  const float* b3a = (const float*)d_in[10];
    const float* w3b  = (const float*)d_in[11]; const float* b3b = (const float*)d_in[12];
    const float* w4a  = (const float*)d_in[13]; const float* b4a = (const float*)d_in[14];
    const float* w4b  = (const float*)d_in[15]; const float* b4b = (const float*)d_in[16];
    const float* fc1w = (const float*)d_in[17]; const float* fc1b = (const float*)d_in[18];
    const float* fc2w = (const float*)d_in[19]; const float* fc2b = (const float*)d_in[20];
    const float* gam  = (const float*)d_in[21]; const float* bet  = (const float*)d_in[22];
    float* out = (float*)d_out;

    char* ws = (char*)d_ws;
    size_t off = 0;
    auto alloc = [&](size_t bytes) -> void* {
        void* p = ws + off;
        off = (off + bytes + 255) & ~(size_t)255;
        return p;
    };
    float* nxyz1  = (float*)alloc((size_t)32 * 256 * 3 * 4);
    int*   gidx1  = (int*)  alloc((size_t)32 * 256 * 64 * 4);
    float* feats1 = (float*)alloc((size_t)32 * 256 * 128 * 4);
    float* nxyz2  = (float*)alloc((size_t)32 * 64 * 3 * 4);
    int*   gidx2  = (int*)  alloc((size_t)32 * 64 * 64 * 4);
    float* feats2 = (float*)alloc((size_t)32 * 64 * 256 * 4);
    float* nxyz3  = (float*)alloc((size_t)32 * 16 * 3 * 4);
    int*   gidx3  = (int*)  alloc((size_t)32 * 16 * 32 * 4);
    float* feats3 = (float*)alloc((size_t)32 * 16 * 512 * 4);
    float* h4     = (float*)alloc((size_t)32 * 16 * 1024 * 4);
    // pre-swizzled bf16 weight fragments
    unsigned short* w1bs = (unsigned short*)alloc((size_t)8  * 2 * 64 * 8 * 2);   // stage1 W2 (64x128)
    unsigned short* w2as = (unsigned short*)alloc((size_t)8  * 5 * 64 * 8 * 2);   // stage2 W1 (131->160 x128)
    unsigned short* w2bs = (unsigned short*)alloc((size_t)16 * 4 * 64 * 8 * 2);   // stage2 W2 (128x256)
    unsigned short* w3as = (unsigned short*)alloc((size_t)16 * 9 * 64 * 8 * 2);   // stage3 W1 (259->288 x256)
    unsigned short* w3bs = (unsigned short*)alloc((size_t)32 * 8 * 64 * 8 * 2);   // stage3 W2 (256x512)

    const float r2a = (float)(0.1 * 0.1);
    const float r2b = (float)(0.2 * 0.2);
    const float r2c = (float)(0.4 * 0.4);

    // ---- Weight pre-swizzle (bit-identical RNE conversion, done once) ----
    wswz_kernel<64,  2, 128><<<16,  256, 0, stream>>>(w1b, w1bs);
    wswz_kernel<131, 5, 128><<<40,  256, 0, stream>>>(w2a, w2as);
    wswz_kernel<128, 4, 256><<<64,  256, 0, stream>>>(w2b, w2bs);
    wswz_kernel<259, 9, 256><<<144, 256, 0, stream>>>(w3a, w3as);
    wswz_kernel<256, 8, 512><<<256, 256, 0, stream>>>(w3b, w3bs);

    // ---- All three FPS stages fused (one block per batch, 4-wave config) ----
    fps_fused_kernel<<<32, 256, 0, stream>>>(pc, nxyz1, nxyz2, nxyz3);

    // ---- Ball queries ----
    bq_kernel<4096, 64, 6><<<(32 * 256 + 3) / 4, 256, 0, stream>>>(pc, nxyz1, gidx1, r2a, 256, 32 * 256);
    bq_kernel<256, 64, 3><<<(32 * 64 + 3) / 4, 256, 0, stream>>>(nxyz1, nxyz2, gidx2, r2b, 64, 32 * 64);
    bq_kernel<64, 32, 3><<<(32 * 16 + 3) / 4, 256, 0, stream>>>(nxyz2, nxyz3, gidx3, r2c, 16, 32 * 16);

    // ---- SA MLPs: stage1 hybrid (fp32 A / MFMA B); stages 2,3 full MFMA ----
    sa_mlp2_kernel<64, 9, 64, 128, 4096, 0><<<32 * 256, 256, 0, stream>>>(
        pc, pc, nxyz1, gidx1, w1a, b1a, w1bs, b1b, feats1, 256);
    sa_mlp_mfma_kernel<64, 131, 128, 256, 256><<<32 * 64, 256, 0, stream>>>(
        nxyz1, feats1, nxyz2, gidx2, w2as, b2a, w2bs, b2b, feats2, 64);
    sa_mlp_mfma_kernel<32, 259, 256, 512, 64><<<32 * 16, 256, 0, stream>>>(
        nxyz2, feats2, nxyz3, gidx3, w3as, b3a, w3bs, b3b, feats3, 16);

    // ---- Head: 4 points per block (128 blocks), then maxpool+fc in head2
    head1_kernel<<<32 * 16 / 4, 256, 0, stream>>>(nxyz3, feats3, w4a, b4a, w4b, b4b, h4);
    head2_kernel<<<32, 256, 0, stream>>>(h4, fc1w, fc1b, fc2w, fc2b, gam, bet, out);
}

// Round 21
// 617.686 us; speedup vs baseline: 1.9858x; 1.1983x over previous
//
#include <hip/hip_runtime.h>

#define DEV static __device__ __forceinline__

using bf16x8 = __attribute__((ext_vector_type(8))) short;   // 8 bf16 (4 VGPRs)
using f32x4  = __attribute__((ext_vector_type(4))) float;

DEV float sqdist(float dx, float dy, float dz) {
    // ((dx*dx + dy*dy) + dz*dz) with no FMA contraction — must match numpy f32
    return __fadd_rn(__fadd_rn(__fmul_rn(dx, dx), __fmul_rn(dy, dy)), __fmul_rn(dz, dz));
}

DEV void fma4(float4& acc, float h, const float4& w) {
    acc.x = fmaf(h, w.x, acc.x); acc.y = fmaf(h, w.y, acc.y);
    acc.z = fmaf(h, w.z, acc.z); acc.w = fmaf(h, w.w, acc.w);
}

DEV unsigned short f2bf_rne(float f) {   // fp32 -> bf16, round-nearest-even
    unsigned u = __builtin_bit_cast(unsigned, f);
    return (unsigned short)((u + 0x7FFFu + ((u >> 16) & 1u)) >> 16);
}

// ---- weight pre-swizzle: fp32 W[K][C] -> bf16 fragment layout ----
// out[((nt*KB+kb)*64+lane)*8 + j] = bf16(W[kb*32+(lane>>4)*8+j][nt*16+(lane&15)])
template<int KSRC, int KB, int C>
__global__ __launch_bounds__(256)
void wswz_kernel(const float* __restrict__ W, unsigned short* __restrict__ out)
{
    constexpr int NT = C / 16;
    constexpr int TOTAL = NT * KB * 64 * 8;
    for (int idx = blockIdx.x * 256 + threadIdx.x; idx < TOTAL; idx += gridDim.x * 256) {
        const int j    = idx & 7;
        const int lane = (idx >> 3) & 63;
        const int fb   = idx >> 9;          // nt*KB + kb
        const int kb   = fb % KB, nt = fb / KB;
        const int k    = kb * 32 + (lane >> 4) * 8 + j;
        const int c    = nt * 16 + (lane & 15);
        const float v  = (k < KSRC) ? W[(size_t)k * C + c] : 0.f;
        out[idx] = f2bf_rne(v);
    }
}

// ---- argmax combine steps (value desc, index asc on ties) ----
template<int CTRL>
DEV int dpp_mov(int v) {
    return __builtin_amdgcn_update_dpp(v, v, CTRL, 0xF, 0xF, false);
}
template<int CTRL>
DEV void red_step_dpp(float& bv, int& bi) {
    float ov = __builtin_bit_cast(float, dpp_mov<CTRL>(__builtin_bit_cast(int, bv)));
    int   oi = dpp_mov<CTRL>(bi);
    if (ov > bv || (ov == bv && oi < bi)) { bv = ov; bi = oi; }
}
// full 64-lane argmax; result valid in lane 63
DEV void wave_argmax(float& bv, int& bi) {
    red_step_dpp<0xB1>(bv, bi);    // quad_perm xor 1
    red_step_dpp<0x4E>(bv, bi);    // quad_perm xor 2
    red_step_dpp<0x141>(bv, bi);   // row_half_mirror (xor 4)
    red_step_dpp<0x140>(bv, bi);   // row_mirror (xor 8)
    red_step_dpp<0x142>(bv, bi);   // row_bcast15
    red_step_dpp<0x143>(bv, bi);   // row_bcast31 -> lane 63 has full result
}

// ---- single-wave FPS over LDS points (no barriers) ----
template<int N, int NPOINT>
DEV void fps_wave64(const float4* pts, float* sout, int lane) {
    constexpr int K = (N + 63) / 64;
    float rx[K], ry[K], rz[K], d[K];
#pragma unroll
    for (int k = 0; k < K; ++k) {
        const float4 c = pts[lane + k * 64];
        rx[k] = c.x; ry[k] = c.y; rz[k] = c.z; d[k] = 1e10f;
    }
    const float4 c0 = pts[0];
    float cx = c0.x, cy = c0.y, cz = c0.z;
    for (int s = 0; s < NPOINT; ++s) {
        if (lane == 0) { sout[s * 3 + 0] = cx; sout[s * 3 + 1] = cy; sout[s * 3 + 2] = cz; }
        float bestv = -1.0f; int besti = 0x7fffffff;
#pragma unroll
        for (int k = 0; k < K; ++k) {
            float d2 = sqdist(rx[k] - cx, ry[k] - cy, rz[k] - cz);
            d[k] = fminf(d[k], d2);
            if (d[k] > bestv) { bestv = d[k]; besti = lane + k * 64; }
        }
        wave_argmax(bestv, besti);
        const int far = __builtin_amdgcn_readlane(besti, 63);
        const float4 c = pts[far];
        cx = c.x; cy = c.y; cz = c.z;
    }
}

// ---------------- Fused FPS (all 3 stages) — measured-floor config ----
__global__ __launch_bounds__(256)
void fps_fused_kernel(const float* __restrict__ pc,
                      float* __restrict__ nxyz1, float* __restrict__ nxyz2,
                      float* __restrict__ nxyz3)
{
    constexpr int N1 = 4096, NP1 = 256, NP2 = 64, NP3 = 16, T = 256, NW = T / 64;
    constexpr int K = N1 / T;
    __shared__ float4 pxyz[N1];
    __shared__ float  sout1[NP1 * 3];
    __shared__ float  sout2[NP2 * 3];
    __shared__ float  sout3[NP3 * 3];
    __shared__ float  rv[2][NW];
    __shared__ int    ri[2][NW];

    const int b = blockIdx.x, tid = threadIdx.x;
    const int w = tid >> 6, lane = tid & 63;
    const float* base = pc + (size_t)b * N1 * 6;

    float rx[K], ry[K], rz[K], d[K];
#pragma unroll
    for (int k = 0; k < K; ++k) {
        const int p = tid + k * T;
        const float x = base[p * 6 + 0];
        const float y = base[p * 6 + 1];
        const float z = base[p * 6 + 2];
        pxyz[p] = make_float4(x, y, z, 0.f);
        rx[k] = x; ry[k] = y; rz[k] = z;
        d[k] = 1e10f;
    }
    __syncthreads();

    // ---- stage 1 ----
    {
        const float4 c0 = pxyz[0];
        float cx = c0.x, cy = c0.y, cz = c0.z;
        for (int s = 0; s < NP1; ++s) {
            if (tid == 0) { sout1[s * 3 + 0] = cx; sout1[s * 3 + 1] = cy; sout1[s * 3 + 2] = cz; }
            float bestv = -1.0f; int besti = 0x7fffffff;
#pragma unroll
            for (int k = 0; k < K; ++k) {
                float d2 = sqdist(rx[k] - cx, ry[k] - cy, rz[k] - cz);
                d[k] = fminf(d[k], d2);
                if (d[k] > bestv) { bestv = d[k]; besti = tid + k * T; }  // k asc => lowest p
            }
            wave_argmax(bestv, besti);

            const int par = s & 1;
            if (lane == 63) { rv[par][w] = bestv; ri[par][w] = besti; }
            __syncthreads();
            float bvv = rv[par][0]; int bii = ri[par][0];
#pragma unroll
            for (int q = 1; q < NW; ++q) {
                const float qv = rv[par][q]; const int qi = ri[par][q];
                if (qv > bvv || (qv == bvv && qi < bii)) { bvv = qv; bii = qi; }
            }
            const float4 c = pxyz[bii];
            cx = c.x; cy = c.y; cz = c.z;
        }
    }

    // ---- stages 2 + 3 on wave 0 ----
    if (w == 0) {
        for (int i = lane; i < NP1; i += 64)
            pxyz[i] = make_float4(sout1[i * 3 + 0], sout1[i * 3 + 1], sout1[i * 3 + 2], 0.f);
        fps_wave64<NP1, NP2>(pxyz, sout2, lane);
        for (int i = lane; i < NP2; i += 64)
            pxyz[i] = make_float4(sout2[i * 3 + 0], sout2[i * 3 + 1], sout2[i * 3 + 2], 0.f);
        fps_wave64<NP2, NP3>(pxyz, sout3, lane);
    }
    __syncthreads();

    float* o1 = nxyz1 + (size_t)b * NP1 * 3;
    for (int i = tid; i < NP1 * 3; i += T) o1[i] = sout1[i];
    float* o2 = nxyz2 + (size_t)b * NP2 * 3;
    if (tid < NP2 * 3) o2[tid] = sout2[tid];
    float* o3 = nxyz3 + (size_t)b * NP3 * 3;
    if (tid < NP3 * 3) o3[tid] = sout3[tid];
}

// ---------------- Ball query -----------------
template<int N, int NSAMP, int STRIDE>
__global__ __launch_bounds__(256)
void bq_kernel(const float* __restrict__ xyz, const float* __restrict__ newxyz,
               int* __restrict__ gidx, float r2, int S, int total)
{
    const int wid = blockIdx.x * 4 + (threadIdx.x >> 6);
    if (wid >= total) return;
    const int lane = threadIdx.x & 63;
    const int b = wid / S;
    const float cx = newxyz[(size_t)wid * 3 + 0];
    const float cy = newxyz[(size_t)wid * 3 + 1];
    const float cz = newxyz[(size_t)wid * 3 + 2];
    const float* base = xyz + (size_t)b * N * STRIDE;
    int* out = gidx + (size_t)wid * NSAMP;

    int count = 0, first = N - 1;
    constexpr int NCH = (N + 63) / 64;
    for (int ch = 0; ch < NCH; ++ch) {
        int p = ch * 64 + lane;
        bool pred = false;
        if (N % 64 == 0 || p < N) {
            float dx = base[p * STRIDE + 0] - cx;
            float dy = base[p * STRIDE + 1] - cy;
            float dz = base[p * STRIDE + 2] - cz;
            pred = sqdist(dx, dy, dz) < r2;
        }
        unsigned long long m = __ballot(pred);
        if (m) {
            if (count == 0) first = ch * 64 + __builtin_ctzll(m);
            int pos = count + __popcll(m & ((1ull << lane) - 1ull));
            if (pred && pos < NSAMP) out[pos] = p;
            count += __popcll(m);
            if (count >= NSAMP) break;
        }
    }
    if (count > NSAMP) count = NSAMP;
    for (int pos = count + lane; pos < NSAMP; pos += 64) out[pos] = first;
}

// ---------------- Grouped 2-layer MLP + maxpool (hybrid: fp32 A / MFMA B) ----
// Used for stage 1 (CIN=9). MODE 0: xyz stride 6, feats = pc permuted.
template<int NS, int CIN, int C1, int C2, int NSRC, int MODE>
__global__ __launch_bounds__(256)
void sa_mlp2_kernel(const float* __restrict__ sxyz, const float* __restrict__ sfeat,
                    const float* __restrict__ newxyz, const int* __restrict__ gidx,
                    const float* __restrict__ W1, const float* __restrict__ B1v,
                    const unsigned short* __restrict__ W2s, const float* __restrict__ B2v,
                    float* __restrict__ outf, int S)
{
    constexpr int T    = 256;
    constexpr int KCC  = (CIN < 32) ? CIN : 32;            // k-chunk length
    constexpr int KCP0 = ((KCC + 3) / 4) * 4 + 4;
    constexpr int KCP  = ((KCP0 / 4) % 2 == 0) ? KCP0 + 4 : KCP0;  // odd quad stride
    constexpr int NPT  = NS / 4;
    constexpr int NCT1 = C1 / 4;
    constexpr int TPT  = (NPT * NCT1) / T;                 // phase-A tiles per thread
    constexpr int LDHB = C1 + 8;                           // bf16 h1 row stride (16B mult)
    constexpr int XS   = (MODE == 0) ? 6 : 3;
    constexpr int CF   = CIN - 3;
    static_assert(NS % 16 == 0 && C1 % 32 == 0 && C2 % 64 == 0, "");
    static_assert((NPT * NCT1) % T == 0 && TPT >= 1, "");

    __shared__ float xgc[NS][KCP];
    __shared__ __align__(16) unsigned short h1b[NS * LDHB];
    __shared__ int   gix[NS];

    const int g   = blockIdx.x;
    const int b   = g / S;
    const int tid = threadIdx.x;

    const float ctr0 = newxyz[(size_t)g * 3 + 0];
    const float ctr1 = newxyz[(size_t)g * 3 + 1];
    const float ctr2 = newxyz[(size_t)g * 3 + 2];
    for (int i = tid; i < NS; i += T) gix[i] = gidx[(size_t)g * NS + i];
    __syncthreads();

    // ---- Phase A: layer 1, K-chunked, accumulators in registers (fp32) ----
    float4 acc[TPT][4];
#pragma unroll
    for (int j = 0; j < TPT; ++j) {
        const int tl = tid + j * T;
        const int ct = tl % NCT1;
        const float4 bb = *(const float4*)&B1v[ct * 4];
#pragma unroll
        for (int i = 0; i < 4; ++i) acc[j][i] = bb;
    }

    const int nchunk = (CIN + KCC - 1) / KCC;
    for (int cch = 0; cch < nchunk; ++cch) {
        const int k0 = cch * KCC;
        const int kcLen = (CIN - k0 < KCC) ? (CIN - k0) : KCC;
        if (cch > 0) __syncthreads();
        // gather chunk
        for (int idx = tid; idx < NS * kcLen; idx += T) {
            const int p = idx / kcLen, kk = idx - p * kcLen, k = k0 + kk;
            float v;
            const int gi = gix[p];
            if (k < 3) {
                const float c = (k == 0) ? ctr0 : ((k == 1) ? ctr1 : ctr2);
                v = sxyz[((size_t)b * NSRC + gi) * XS + k] - c;
            } else if constexpr (MODE == 0) {
                const int j2 = k - 3;
                v = sfeat[((size_t)b * NSRC + gi) * 6 + (j2 < 3 ? 3 + j2 : j2 - 3)];
            } else {
                v = sfeat[((size_t)b * NSRC + gi) * CF + (k - 3)];
            }
            xgc[p][kk] = v;
        }
        __syncthreads();
        // compute chunk
#pragma unroll
        for (int j = 0; j < TPT; ++j) {
            const int tl = tid + j * T;
            const int pt = tl / NCT1, ct = tl % NCT1;
            const int p0 = pt * 4, c0 = ct * 4;
            int kk = 0;
            for (; kk + 4 <= kcLen; kk += 4) {
                const float4 xa = *(const float4*)&xgc[p0 + 0][kk];
                const float4 xb = *(const float4*)&xgc[p0 + 1][kk];
                const float4 xc = *(const float4*)&xgc[p0 + 2][kk];
                const float4 xd = *(const float4*)&xgc[p0 + 3][kk];
                const float4 w0 = *(const float4*)&W1[(size_t)(k0 + kk + 0) * C1 + c0];
                const float4 w1 = *(const float4*)&W1[(size_t)(k0 + kk + 1) * C1 + c0];
                const float4 w2 = *(const float4*)&W1[(size_t)(k0 + kk + 2) * C1 + c0];
                const float4 w3 = *(const float4*)&W1[(size_t)(k0 + kk + 3) * C1 + c0];
                fma4(acc[j][0], xa.x, w0); fma4(acc[j][0], xa.y, w1); fma4(acc[j][0], xa.z, w2); fma4(acc[j][0], xa.w, w3);
                fma4(acc[j][1], xb.x, w0); fma4(acc[j][1], xb.y, w1); fma4(acc[j][1], xb.z, w2); fma4(acc[j][1], xb.w, w3);
                fma4(acc[j][2], xc.x, w0); fma4(acc[j][2], xc.y, w1); fma4(acc[j][2], xc.z, w2); fma4(acc[j][2], xc.w, w3);
                fma4(acc[j][3], xd.x, w0); fma4(acc[j][3], xd.y, w1); fma4(acc[j][3], xd.z, w2); fma4(acc[j][3], xd.w, w3);
            }
            for (; kk < kcLen; ++kk) {
                const float4 w = *(const float4*)&W1[(size_t)(k0 + kk) * C1 + c0];
                fma4(acc[j][0], xgc[p0 + 0][kk], w);
                fma4(acc[j][1], xgc[p0 + 1][kk], w);
                fma4(acc[j][2], xgc[p0 + 2][kk], w);
                fma4(acc[j][3], xgc[p0 + 3][kk], w);
            }
        }
    }
    // write h1 (relu) as bf16
    __syncthreads();
#pragma unroll
    for (int j = 0; j < TPT; ++j) {
        const int tl = tid + j * T;
        const int pt = tl / NCT1, ct = tl % NCT1;
        const int p0 = pt * 4, c0 = ct * 4;
#pragma unroll
        for (int i = 0; i < 4; ++i) {
            unsigned short* row = &h1b[(size_t)(p0 + i) * LDHB + c0];
            row[0] = f2bf_rne(fmaxf(acc[j][i].x, 0.f));
            row[1] = f2bf_rne(fmaxf(acc[j][i].y, 0.f));
            row[2] = f2bf_rne(fmaxf(acc[j][i].z, 0.f));
            row[3] = f2bf_rne(fmaxf(acc[j][i].w, 0.f));
        }
    }
    __syncthreads();

    // ---- Phase B: MFMA (pre-swizzled W2 fragments) ----
    {
        constexpr int NMT = NS / 16;       // M-tiles (points)
        constexpr int NKB = C1 / 32;       // K-blocks
        constexpr int NNT = C2 / 16;       // N-tiles total
        constexpr int NTW = NNT / 4;       // N-tiles per wave (4 waves)
        const int w    = tid >> 6;
        const int lane = tid & 63;
        const int lr   = lane & 15;
        const int lg   = lane >> 4;

        bf16x8 af[NMT][NKB];
#pragma unroll
        for (int mt = 0; mt < NMT; ++mt)
#pragma unroll
            for (int kb = 0; kb < NKB; ++kb)
                af[mt][kb] = *(const bf16x8*)&h1b[(size_t)(mt * 16 + lr) * LDHB + kb * 32 + lg * 8];

#pragma unroll
        for (int q = 0; q < NTW; ++q) {
            const int nt = w * NTW + q;
            const int c  = nt * 16 + lr;
            bf16x8 bfr[NKB];
#pragma unroll
            for (int kb = 0; kb < NKB; ++kb)
                bfr[kb] = *(const bf16x8*)&W2s[(size_t)((nt * NKB + kb) * 64 + lane) * 8];
            const float bb = B2v[c];
            float colmax = 0.f;   // relu >= 0
#pragma unroll
            for (int mt = 0; mt < NMT; ++mt) {
                f32x4 ac = {bb, bb, bb, bb};
#pragma unroll
                for (int kb = 0; kb < NKB; ++kb)
                    ac = __builtin_amdgcn_mfma_f32_16x16x32_bf16(af[mt][kb], bfr[kb], ac, 0, 0, 0);
                float pm = fmaxf(fmaxf(ac[0], ac[1]), fmaxf(ac[2], ac[3]));
                pm = fmaxf(pm, __shfl_xor(pm, 16));
                pm = fmaxf(pm, __shfl_xor(pm, 32));
                colmax = fmaxf(colmax, pm);
            }
            if (lg == 0) outf[(size_t)g * C2 + c] = colmax;
        }
    }
}

// ---------------- Grouped 2-layer MLP + maxpool, FULL MFMA ----
// Both layers on mfma_f32_16x16x32_bf16; W1s/W2s pre-swizzled bf16 fragments.
// HEAD=false: MODE-1 gather via gidx (stages 2/3).
// HEAD=true : per-batch direct gather of [nxyz3, feats3] rows (no gidx);
//             output = g4[b][C2] with maxpool over the 16 points fused.
template<int NS, int CIN, int C1, int C2, int NSRC, bool HEAD = false>
__global__ __launch_bounds__(256)
void sa_mlp_mfma_kernel(const float* __restrict__ sxyz, const float* __restrict__ sfeat,
                        const float* __restrict__ newxyz, const int* __restrict__ gidx,
                        const unsigned short* __restrict__ W1s, const float* __restrict__ B1v,
                        const unsigned short* __restrict__ W2s, const float* __restrict__ B2v,
                        float* __restrict__ outf, int S)
{
    constexpr int T    = 256;
    constexpr int KP   = ((CIN + 31) / 32) * 32;   // K padded
    constexpr int LDXB = KP + 8;                   // bf16 x row stride (16B mult)
    constexpr int KBA  = KP / 32;                  // phase-A K-blocks
    constexpr int NMT  = NS / 16;                  // M-tiles
    constexpr int NTA  = C1 / 16 / 4;              // phase-A N-tiles per wave
    constexpr int LDHB = C1 + 8;                   // bf16 h1 row stride
    constexpr int KBB  = C1 / 32;                  // phase-B K-blocks
    constexpr int NTB  = C2 / 16 / 4;              // phase-B N-tiles per wave
    constexpr int CF   = CIN - 3;
    static_assert(NS % 16 == 0 && C1 % 64 == 0 && C2 % 64 == 0, "");

    __shared__ __align__(16) unsigned short xb[NS * LDXB];
    __shared__ __align__(16) unsigned short h1b[NS * LDHB];
    __shared__ int gix[NS];

    const int g   = blockIdx.x;
    const int b   = g / S;
    const int tid = threadIdx.x;
    const int w    = tid >> 6;
    const int lane = tid & 63;
    const int lr   = lane & 15;
    const int lg   = lane >> 4;

    float ctr0 = 0.f, ctr1 = 0.f, ctr2 = 0.f;
    if constexpr (!HEAD) {
        ctr0 = newxyz[(size_t)g * 3 + 0];
        ctr1 = newxyz[(size_t)g * 3 + 1];
        ctr2 = newxyz[(size_t)g * 3 + 2];
        for (int i = tid; i < NS; i += T) gix[i] = gidx[(size_t)g * NS + i];
        __syncthreads();
    }

    // ---- gather full input as bf16 (pad = 0) ----
    for (int idx = tid; idx < NS * KP; idx += T) {
        const int p = idx / KP, k = idx - p * KP;
        float v = 0.f;
        if (k < CIN) {
            if constexpr (HEAD) {
                v = (k < 3) ? sxyz[((size_t)g * NS + p) * 3 + k]
                            : sfeat[((size_t)g * NS + p) * CF + (k - 3)];
            } else {
                const int gi = gix[p];
                if (k < 3) {
                    const float c = (k == 0) ? ctr0 : ((k == 1) ? ctr1 : ctr2);
                    v = sxyz[((size_t)b * NSRC + gi) * 3 + k] - c;
                } else {
                    v = sfeat[((size_t)b * NSRC + gi) * CF + (k - 3)];
                }
            }
        }
        xb[(size_t)p * LDXB + k] = f2bf_rne(v);
    }
    __syncthreads();

    // ---- Phase A: h1 = relu(x @ W1 + b1) via MFMA ----
    {
        bf16x8 af[NMT][KBA];
#pragma unroll
        for (int mt = 0; mt < NMT; ++mt)
#pragma unroll
            for (int kb = 0; kb < KBA; ++kb)
                af[mt][kb] = *(const bf16x8*)&xb[(size_t)(mt * 16 + lr) * LDXB + kb * 32 + lg * 8];

#pragma unroll
        for (int q = 0; q < NTA; ++q) {
            const int nt = w * NTA + q;
            const int c  = nt * 16 + lr;
            bf16x8 bfr[KBA];
#pragma unroll
            for (int kb = 0; kb < KBA; ++kb)
                bfr[kb] = *(const bf16x8*)&W1s[(size_t)((nt * KBA + kb) * 64 + lane) * 8];
            const float bb = B1v[c];
#pragma unroll
            for (int mt = 0; mt < NMT; ++mt) {
                f32x4 ac = {bb, bb, bb, bb};
#pragma unroll
                for (int kb = 0; kb < KBA; ++kb)
                    ac = __builtin_amdgcn_mfma_f32_16x16x32_bf16(af[mt][kb], bfr[kb], ac, 0, 0, 0);
#pragma unroll
                for (int i = 0; i < 4; ++i) {
                    const int row = mt * 16 + lg * 4 + i;
                    h1b[(size_t)row * LDHB + c] = f2bf_rne(fmaxf(ac[i], 0.f));
                }
            }
        }
    }
    __syncthreads();

    // ---- Phase B: out = maxpool_p (h1 @ W2 + b2) via MFMA ----
    {
        bf16x8 af[NMT][KBB];
#pragma unroll
        for (int mt = 0; mt < NMT; ++mt)
#pragma unroll
            for (int kb = 0; kb < KBB; ++kb)
                af[mt][kb] = *(const bf16x8*)&h1b[(size_t)(mt * 16 + lr) * LDHB + kb * 32 + lg * 8];

#pragma unroll
        for (int q = 0; q < NTB; ++q) {
            const int nt = w * NTB + q;
            const int c  = nt * 16 + lr;
            bf16x8 bfr[KBB];
#pragma unroll
            for (int kb = 0; kb < KBB; ++kb)
                bfr[kb] = *(const bf16x8*)&W2s[(size_t)((nt * KBB + kb) * 64 + lane) * 8];
            const float bb = B2v[c];
            float colmax = 0.f;   // relu >= 0
#pragma unroll
            for (int mt = 0; mt < NMT; ++mt) {
                f32x4 ac = {bb, bb, bb, bb};
#pragma unroll
                for (int kb = 0; kb < KBB; ++kb)
                    ac = __builtin_amdgcn_mfma_f32_16x16x32_bf16(af[mt][kb], bfr[kb], ac, 0, 0, 0);
                float pm = fmaxf(fmaxf(ac[0], ac[1]), fmaxf(ac[2], ac[3]));
                pm = fmaxf(pm, __shfl_xor(pm, 16));
                pm = fmaxf(pm, __shfl_xor(pm, 32));
                colmax = fmaxf(colmax, pm);
            }
            if (lg == 0) outf[(size_t)g * C2 + c] = colmax;
        }
    }
}

// ---------------- Head part 2: fc1(relu) -> fc2 -> bn-ish ----
// g4 already maxpooled by the HEAD mfma kernel.
__global__ __launch_bounds__(256)
void head2_kernel(const float* __restrict__ g4,
                  const float* __restrict__ fc1w, const float* __restrict__ fc1b,
                  const float* __restrict__ fc2w, const float* __restrict__ fc2b,
                  const float* __restrict__ gamma, const float* __restrict__ beta,
                  float* __restrict__ out)
{
    const int b   = blockIdx.x;
    const int tid = threadIdx.x;
    __shared__ float gm[1024], g1[1024];
    for (int c = tid; c < 1024; c += 256) gm[c] = g4[(size_t)b * 1024 + c];
    __syncthreads();
    {
        const int c0 = tid * 4;
        float4 a = *(const float4*)&fc1b[c0];
#pragma unroll 4
        for (int k = 0; k < 1024; ++k) {
            const float4 w = *(const float4*)&fc1w[(size_t)k * 1024 + c0];
            fma4(a, gm[k], w);
        }
        g1[c0 + 0] = fmaxf(a.x, 0.f); g1[c0 + 1] = fmaxf(a.y, 0.f);
        g1[c0 + 2] = fmaxf(a.z, 0.f); g1[c0 + 3] = fmaxf(a.w, 0.f);
    }
    __syncthreads();
    if (tid < 128) {
        const float s = sqrtf(1.00001f);
        const int c = tid;
        float a = fc2b[c];
#pragma unroll 4
        for (int k = 0; k < 1024; ++k) a = fmaf(g1[k], fc2w[(size_t)k * 128 + c], a);
        out[(size_t)b * 128 + c] = (a / s) * gamma[c] + beta[c];
    }
}

// ---------------------------------------------------------------------------
extern "C" void kernel_launch(void* const* d_in, const int* in_sizes, int n_in,
                              void* d_out, int out_size, void* d_ws, size_t ws_size,
                              hipStream_t stream)
{
    const float* pc   = (const float*)d_in[0];
    const float* w1a  = (const float*)d_in[1];  const float* b1a = (const float*)d_in[2];
    const float* w1b  = (const float*)d_in[3];  const float* b1b = (const float*)d_in[4];
    const float* w2a  = (const float*)d_in[5];  const float* b2a = (const float*)d_in[6];
    const float* w2b  = (const float*)d_in[7];  const float* b2b = (const float*)d_in[8];
    const float* w3a  = (const float*)d_in[9];  const float* b3a = (const float*)d_in[10];
    const float* w3b  = (const float*)d_in[11]; const float* b3b = (const float*)d_in[12];
    const float* w4a  = (const float*)d_in[13]; const float* b4a = (const float*)d_in[14];
    const float* w4b  = (const float*)d_in[15]; const float* b4b = (const float*)d_in[16];
    const float* fc1w = (const float*)d_in[17]; const float* fc1b = (const float*)d_in[18];
    const float* fc2w = (const float*)d_in[19]; const float* fc2b = (const float*)d_in[20];
    const float* gam  = (const float*)d_in[21]; const float* bet  = (const float*)d_in[22];
    float* out = (float*)d_out;

    char* ws = (char*)d_ws;
    size_t off = 0;
    auto alloc = [&](size_t bytes) -> void* {
        void* p = ws + off;
        off = (off + bytes + 255) & ~(size_t)255;
        return p;
    };
    float* nxyz1  = (float*)alloc((size_t)32 * 256 * 3 * 4);
    int*   gidx1  = (int*)  alloc((size_t)32 * 256 * 64 * 4);
    float* feats1 = (float*)alloc((size_t)32 * 256 * 128 * 4);
    float* nxyz2  = (float*)alloc((size_t)32 * 64 * 3 * 4);
    int*   gidx2  = (int*)  alloc((size_t)32 * 64 * 64 * 4);
    float* feats2 = (float*)alloc((size_t)32 * 64 * 256 * 4);
    float* nxyz3  = (float*)alloc((size_t)32 * 16 * 3 * 4);
    int*   gidx3  = (int*)  alloc((size_t)32 * 16 * 32 * 4);
    float* feats3 = (float*)alloc((size_t)32 * 16 * 512 * 4);
    float* g4     = (float*)alloc((size_t)32 * 1024 * 4);
    // pre-swizzled bf16 weight fragments
    unsigned short* w1bs = (unsigned short*)alloc((size_t)8  * 2  * 64 * 8 * 2);  // stage1 W2 (64x128)
    unsigned short* w2as = (unsigned short*)alloc((size_t)8  * 5  * 64 * 8 * 2);  // stage2 W1 (131->160 x128)
    unsigned short* w2bs = (unsigned short*)alloc((size_t)16 * 4  * 64 * 8 * 2);  // stage2 W2 (128x256)
    unsigned short* w3as = (unsigned short*)alloc((size_t)16 * 9  * 64 * 8 * 2);  // stage3 W1 (259->288 x256)
    unsigned short* w3bs = (unsigned short*)alloc((size_t)32 * 8  * 64 * 8 * 2);  // stage3 W2 (256x512)
    unsigned short* w4as = (unsigned short*)alloc((size_t)32 * 17 * 64 * 8 * 2);  // head W1 (515->544 x512)
    unsigned short* w4bs = (unsigned short*)alloc((size_t)64 * 16 * 64 * 8 * 2);  // head W2 (512x1024)

    const float r2a = (float)(0.1 * 0.1);
    const float r2b = (float)(0.2 * 0.2);
    const float r2c = (float)(0.4 * 0.4);

    // ---- Weight pre-swizzle (bit-identical RNE conversion, done once) ----
    wswz_kernel<64,  2,  128><<<16,  256, 0, stream>>>(w1b, w1bs);
    wswz_kernel<131, 5,  128><<<40,  256, 0, stream>>>(w2a, w2as);
    wswz_kernel<128, 4,  256><<<64,  256, 0, stream>>>(w2b, w2bs);
    wswz_kernel<259, 9,  256><<<144, 256, 0, stream>>>(w3a, w3as);
    wswz_kernel<256, 8,  512><<<256, 256, 0, stream>>>(w3b, w3bs);
    wswz_kernel<515, 17, 512><<<256, 256, 0, stream>>>(w4a, w4as);
    wswz_kernel<512, 16, 1024><<<256, 256, 0, stream>>>(w4b, w4bs);

    // ---- All three FPS stages fused (one block per batch, 4-wave config) ----
    fps_fused_kernel<<<32, 256, 0, stream>>>(pc, nxyz1, nxyz2, nxyz3);

    // ---- Ball queries ----
    bq_kernel<4096, 64, 6><<<(32 * 256 + 3) / 4, 256, 0, stream>>>(pc, nxyz1, gidx1, r2a, 256, 32 * 256);
    bq_kernel<256, 64, 3><<<(32 * 64 + 3) / 4, 256, 0, stream>>>(nxyz1, nxyz2, gidx2, r2b, 64, 32 * 64);
    bq_kernel<64, 32, 3><<<(32 * 16 + 3) / 4, 256, 0, stream>>>(nxyz2, nxyz3, gidx3, r2c, 16, 32 * 16);

    // ---- SA MLPs: stage1 hybrid (fp32 A / MFMA B); stages 2,3 full MFMA ----
    sa_mlp2_kernel<64, 9, 64, 128, 4096, 0><<<32 * 256, 256, 0, stream>>>(
        pc, pc, nxyz1, gidx1, w1a, b1a, w1bs, b1b, feats1, 256);
    sa_mlp_mfma_kernel<64, 131, 128, 256, 256><<<32 * 64, 256, 0, stream>>>(
        nxyz1, feats1, nxyz2, gidx2, w2as, b2a, w2bs, b2b, feats2, 64);
    sa_mlp_mfma_kernel<32, 259, 256, 512, 64><<<32 * 16, 256, 0, stream>>>(
        nxyz2, feats2, nxyz3, gidx3, w3as, b3a, w3bs, b3b, feats3, 16);

    // ---- Head: per-batch full-MFMA MLP with fused maxpool(16), then fc ----
    sa_mlp_mfma_kernel<16, 515, 512, 1024, 16, true><<<32, 256, 0, stream>>>(
        nxyz3, feats3, nullptr, nullptr, w4as, b4a, w4bs, b4b, g4, 1);
    head2_kernel<<<32, 256, 0, stream>>>(g4, fc1w, fc1b, fc2w, fc2b, gam, bet, out);
}

// Round 22
// 590.184 us; speedup vs baseline: 2.0783x; 1.0466x over previous
//
#include <hip/hip_runtime.h>

#define DEV static __device__ __forceinline__

using bf16x8 = __attribute__((ext_vector_type(8))) short;   // 8 bf16 (4 VGPRs)
using f32x4  = __attribute__((ext_vector_type(4))) float;

DEV float sqdist(float dx, float dy, float dz) {
    // ((dx*dx + dy*dy) + dz*dz) with no FMA contraction — must match numpy f32
    return __fadd_rn(__fadd_rn(__fmul_rn(dx, dx), __fmul_rn(dy, dy)), __fmul_rn(dz, dz));
}

DEV void fma4(float4& acc, float h, const float4& w) {
    acc.x = fmaf(h, w.x, acc.x); acc.y = fmaf(h, w.y, acc.y);
    acc.z = fmaf(h, w.z, acc.z); acc.w = fmaf(h, w.w, acc.w);
}

DEV unsigned short f2bf_rne(float f) {   // fp32 -> bf16, round-nearest-even
    unsigned u = __builtin_bit_cast(unsigned, f);
    return (unsigned short)((u + 0x7FFFu + ((u >> 16) & 1u)) >> 16);
}

// ---- weight pre-swizzle section: fp32 W[K][C] -> bf16 fragment layout ----
// out[((nt*KB+kb)*64+lane)*8 + j] = bf16(W[kb*32+(lane>>4)*8+j][nt*16+(lane&15)])
template<int KSRC, int KB, int C>
DEV void wswz_sec(const float* __restrict__ W, unsigned short* __restrict__ out,
                  int idx0, int stride)
{
    constexpr int NT = C / 16;
    constexpr int TOTAL = NT * KB * 64 * 8;
    for (int idx = idx0; idx < TOTAL; idx += stride) {
        const int j    = idx & 7;
        const int lane = (idx >> 3) & 63;
        const int fb   = idx >> 9;          // nt*KB + kb
        const int kb   = fb % KB, nt = fb / KB;
        const int k    = kb * 32 + (lane >> 4) * 8 + j;
        const int c    = nt * 16 + (lane & 15);
        const float v  = (k < KSRC) ? W[(size_t)k * C + c] : 0.f;
        out[idx] = f2bf_rne(v);
    }
}

// one launch converts all 8 weight matrices
__global__ __launch_bounds__(256)
void wswz_all_kernel(const float* w1a, unsigned short* o1a,
                     const float* w1b, unsigned short* o1b,
                     const float* w2a, unsigned short* o2a,
                     const float* w2b, unsigned short* o2b,
                     const float* w3a, unsigned short* o3a,
                     const float* w3b, unsigned short* o3b,
                     const float* w4a, unsigned short* o4a,
                     const float* w4b, unsigned short* o4b)
{
    const int idx0   = blockIdx.x * 256 + threadIdx.x;
    const int stride = gridDim.x * 256;
    wswz_sec<9,   1,  64 >(w1a, o1a, idx0, stride);
    wswz_sec<64,  2,  128>(w1b, o1b, idx0, stride);
    wswz_sec<131, 5,  128>(w2a, o2a, idx0, stride);
    wswz_sec<128, 4,  256>(w2b, o2b, idx0, stride);
    wswz_sec<259, 9,  256>(w3a, o3a, idx0, stride);
    wswz_sec<256, 8,  512>(w3b, o3b, idx0, stride);
    wswz_sec<515, 17, 512>(w4a, o4a, idx0, stride);
    wswz_sec<512, 16, 1024>(w4b, o4b, idx0, stride);
}

// ---- argmax combine steps (value desc, index asc on ties) ----
template<int CTRL>
DEV int dpp_mov(int v) {
    return __builtin_amdgcn_update_dpp(v, v, CTRL, 0xF, 0xF, false);
}
template<int CTRL>
DEV void red_step_dpp(float& bv, int& bi) {
    float ov = __builtin_bit_cast(float, dpp_mov<CTRL>(__builtin_bit_cast(int, bv)));
    int   oi = dpp_mov<CTRL>(bi);
    if (ov > bv || (ov == bv && oi < bi)) { bv = ov; bi = oi; }
}
// full 64-lane argmax; result valid in lane 63
DEV void wave_argmax(float& bv, int& bi) {
    red_step_dpp<0xB1>(bv, bi);    // quad_perm xor 1
    red_step_dpp<0x4E>(bv, bi);    // quad_perm xor 2
    red_step_dpp<0x141>(bv, bi);   // row_half_mirror (xor 4)
    red_step_dpp<0x140>(bv, bi);   // row_mirror (xor 8)
    red_step_dpp<0x142>(bv, bi);   // row_bcast15
    red_step_dpp<0x143>(bv, bi);   // row_bcast31 -> lane 63 has full result
}

// ---- single-wave FPS over LDS points (no barriers) ----
template<int N, int NPOINT>
DEV void fps_wave64(const float4* pts, float* sout, int lane) {
    constexpr int K = (N + 63) / 64;
    float rx[K], ry[K], rz[K], d[K];
#pragma unroll
    for (int k = 0; k < K; ++k) {
        const float4 c = pts[lane + k * 64];
        rx[k] = c.x; ry[k] = c.y; rz[k] = c.z; d[k] = 1e10f;
    }
    const float4 c0 = pts[0];
    float cx = c0.x, cy = c0.y, cz = c0.z;
    for (int s = 0; s < NPOINT; ++s) {
        if (lane == 0) { sout[s * 3 + 0] = cx; sout[s * 3 + 1] = cy; sout[s * 3 + 2] = cz; }
        float bestv = -1.0f; int besti = 0x7fffffff;
#pragma unroll
        for (int k = 0; k < K; ++k) {
            float d2 = sqdist(rx[k] - cx, ry[k] - cy, rz[k] - cz);
            d[k] = fminf(d[k], d2);
            if (d[k] > bestv) { bestv = d[k]; besti = lane + k * 64; }
        }
        wave_argmax(bestv, besti);
        const int far = __builtin_amdgcn_readlane(besti, 63);
        const float4 c = pts[far];
        cx = c.x; cy = c.y; cz = c.z;
    }
}

// ---------------- Fused FPS (all 3 stages) — measured-floor config ----
__global__ __launch_bounds__(256)
void fps_fused_kernel(const float* __restrict__ pc,
                      float* __restrict__ nxyz1, float* __restrict__ nxyz2,
                      float* __restrict__ nxyz3)
{
    constexpr int N1 = 4096, NP1 = 256, NP2 = 64, NP3 = 16, T = 256, NW = T / 64;
    constexpr int K = N1 / T;
    __shared__ float4 pxyz[N1];
    __shared__ float  sout1[NP1 * 3];
    __shared__ float  sout2[NP2 * 3];
    __shared__ float  sout3[NP3 * 3];
    __shared__ float  rv[2][NW];
    __shared__ int    ri[2][NW];

    const int b = blockIdx.x, tid = threadIdx.x;
    const int w = tid >> 6, lane = tid & 63;
    const float* base = pc + (size_t)b * N1 * 6;

    float rx[K], ry[K], rz[K], d[K];
#pragma unroll
    for (int k = 0; k < K; ++k) {
        const int p = tid + k * T;
        const float x = base[p * 6 + 0];
        const float y = base[p * 6 + 1];
        const float z = base[p * 6 + 2];
        pxyz[p] = make_float4(x, y, z, 0.f);
        rx[k] = x; ry[k] = y; rz[k] = z;
        d[k] = 1e10f;
    }
    __syncthreads();

    // ---- stage 1 ----
    {
        const float4 c0 = pxyz[0];
        float cx = c0.x, cy = c0.y, cz = c0.z;
        for (int s = 0; s < NP1; ++s) {
            if (tid == 0) { sout1[s * 3 + 0] = cx; sout1[s * 3 + 1] = cy; sout1[s * 3 + 2] = cz; }
            float bestv = -1.0f; int besti = 0x7fffffff;
#pragma unroll
            for (int k = 0; k < K; ++k) {
                float d2 = sqdist(rx[k] - cx, ry[k] - cy, rz[k] - cz);
                d[k] = fminf(d[k], d2);
                if (d[k] > bestv) { bestv = d[k]; besti = tid + k * T; }  // k asc => lowest p
            }
            wave_argmax(bestv, besti);

            const int par = s & 1;
            if (lane == 63) { rv[par][w] = bestv; ri[par][w] = besti; }
            __syncthreads();
            float bvv = rv[par][0]; int bii = ri[par][0];
#pragma unroll
            for (int q = 1; q < NW; ++q) {
                const float qv = rv[par][q]; const int qi = ri[par][q];
                if (qv > bvv || (qv == bvv && qi < bii)) { bvv = qv; bii = qi; }
            }
            const float4 c = pxyz[bii];
            cx = c.x; cy = c.y; cz = c.z;
        }
    }

    // ---- stages 2 + 3 on wave 0 ----
    if (w == 0) {
        for (int i = lane; i < NP1; i += 64)
            pxyz[i] = make_float4(sout1[i * 3 + 0], sout1[i * 3 + 1], sout1[i * 3 + 2], 0.f);
        fps_wave64<NP1, NP2>(pxyz, sout2, lane);
        for (int i = lane; i < NP2; i += 64)
            pxyz[i] = make_float4(sout2[i * 3 + 0], sout2[i * 3 + 1], sout2[i * 3 + 2], 0.f);
        fps_wave64<NP2, NP3>(pxyz, sout3, lane);
    }
    __syncthreads();

    float* o1 = nxyz1 + (size_t)b * NP1 * 3;
    for (int i = tid; i < NP1 * 3; i += T) o1[i] = sout1[i];
    float* o2 = nxyz2 + (size_t)b * NP2 * 3;
    if (tid < NP2 * 3) o2[tid] = sout2[tid];
    float* o3 = nxyz3 + (size_t)b * NP3 * 3;
    if (tid < NP3 * 3) o3[tid] = sout3[tid];
}

// ---------------- Ball query (device body) -----------------
template<int N, int NSAMP, int STRIDE>
DEV void bq_dev(const float* __restrict__ xyz, const float* __restrict__ newxyz,
                int* __restrict__ gidx, float r2, int S, int total, int wid, int lane)
{
    if (wid >= total) return;
    const int b = wid / S;
    const float cx = newxyz[(size_t)wid * 3 + 0];
    const float cy = newxyz[(size_t)wid * 3 + 1];
    const float cz = newxyz[(size_t)wid * 3 + 2];
    const float* base = xyz + (size_t)b * N * STRIDE;
    int* out = gidx + (size_t)wid * NSAMP;

    int count = 0, first = N - 1;
    constexpr int NCH = (N + 63) / 64;
    for (int ch = 0; ch < NCH; ++ch) {
        int p = ch * 64 + lane;
        bool pred = false;
        if (N % 64 == 0 || p < N) {
            float dx = base[p * STRIDE + 0] - cx;
            float dy = base[p * STRIDE + 1] - cy;
            float dz = base[p * STRIDE + 2] - cz;
            pred = sqdist(dx, dy, dz) < r2;
        }
        unsigned long long m = __ballot(pred);
        if (m) {
            if (count == 0) first = ch * 64 + __builtin_ctzll(m);
            int pos = count + __popcll(m & ((1ull << lane) - 1ull));
            if (pred && pos < NSAMP) out[pos] = p;
            count += __popcll(m);
            if (count >= NSAMP) break;
        }
    }
    if (count > NSAMP) count = NSAMP;
    for (int pos = count + lane; pos < NSAMP; pos += 64) out[pos] = first;
}

// All three ball queries in one launch (block-range dispatch).
// blocks [0,2048): bq1, [2048,2560): bq2, [2560,2688): bq3.
__global__ __launch_bounds__(256)
void bq_all_kernel(const float* __restrict__ pc,
                   const float* __restrict__ nxyz1, int* __restrict__ gidx1, float r2a,
                   const float* __restrict__ nxyz2, int* __restrict__ gidx2, float r2b,
                   const float* __restrict__ nxyz3, int* __restrict__ gidx3, float r2c)
{
    const int blk  = blockIdx.x;
    const int w    = threadIdx.x >> 6;
    const int lane = threadIdx.x & 63;
    if (blk < 2048) {
        bq_dev<4096, 64, 6>(pc, nxyz1, gidx1, r2a, 256, 32 * 256, blk * 4 + w, lane);
    } else if (blk < 2560) {
        bq_dev<256, 64, 3>(nxyz1, nxyz2, gidx2, r2b, 64, 32 * 64, (blk - 2048) * 4 + w, lane);
    } else {
        bq_dev<64, 32, 3>(nxyz2, nxyz3, gidx3, r2c, 16, 32 * 16, (blk - 2560) * 4 + w, lane);
    }
}

// ---------------- Grouped 2-layer MLP + maxpool, FULL MFMA ----
// Both layers on mfma_f32_16x16x32_bf16; W1s/W2s pre-swizzled bf16 fragments.
// MODE 0: stage1 gather (xyz stride 6, feats = pc permuted [3:6]++[0:3]).
// MODE 1: mid stages (xyz stride 3, feats array) via gidx.
// MODE 2: head (direct rows of [nxyz3, feats3], no gidx, no centroid).
template<int NS, int CIN, int C1, int C2, int NSRC, int MODE>
__global__ __launch_bounds__(256)
void sa_mlp_mfma_kernel(const float* __restrict__ sxyz, const float* __restrict__ sfeat,
                        const float* __restrict__ newxyz, const int* __restrict__ gidx,
                        const unsigned short* __restrict__ W1s, const float* __restrict__ B1v,
                        const unsigned short* __restrict__ W2s, const float* __restrict__ B2v,
                        float* __restrict__ outf, int S)
{
    constexpr int T    = 256;
    constexpr int KP   = ((CIN + 31) / 32) * 32;   // K padded
    constexpr int LDXB = KP + 8;                   // bf16 x row stride (16B mult)
    constexpr int KBA  = KP / 32;                  // phase-A K-blocks
    constexpr int NMT  = NS / 16;                  // M-tiles
    constexpr int NTA  = C1 / 16 / 4;              // phase-A N-tiles per wave
    constexpr int LDHB = C1 + 8;                   // bf16 h1 row stride
    constexpr int KBB  = C1 / 32;                  // phase-B K-blocks
    constexpr int NTB  = C2 / 16 / 4;              // phase-B N-tiles per wave
    constexpr int CF   = CIN - 3;
    constexpr int XS   = (MODE == 0) ? 6 : 3;
    static_assert(NS % 16 == 0 && C1 % 64 == 0 && C2 % 64 == 0, "");

    __shared__ __align__(16) unsigned short xb[NS * LDXB];
    __shared__ __align__(16) unsigned short h1b[NS * LDHB];
    __shared__ int gix[NS];

    const int g   = blockIdx.x;
    const int b   = g / S;
    const int tid = threadIdx.x;
    const int w    = tid >> 6;
    const int lane = tid & 63;
    const int lr   = lane & 15;
    const int lg   = lane >> 4;

    float ctr0 = 0.f, ctr1 = 0.f, ctr2 = 0.f;
    if constexpr (MODE != 2) {
        ctr0 = newxyz[(size_t)g * 3 + 0];
        ctr1 = newxyz[(size_t)g * 3 + 1];
        ctr2 = newxyz[(size_t)g * 3 + 2];
        for (int i = tid; i < NS; i += T) gix[i] = gidx[(size_t)g * NS + i];
        __syncthreads();
    }

    // ---- gather full input as bf16 (rel-xyz in fp32, then RNE; pad = 0) ----
    for (int idx = tid; idx < NS * KP; idx += T) {
        const int p = idx / KP, k = idx - p * KP;
        float v = 0.f;
        if (k < CIN) {
            if constexpr (MODE == 2) {
                v = (k < 3) ? sxyz[((size_t)g * NS + p) * 3 + k]
                            : sfeat[((size_t)g * NS + p) * CF + (k - 3)];
            } else if constexpr (MODE == 0) {
                const int gi = gix[p];
                if (k < 3) {
                    const float c = (k == 0) ? ctr0 : ((k == 1) ? ctr1 : ctr2);
                    v = sxyz[((size_t)b * NSRC + gi) * 6 + k] - c;
                } else {
                    const int j2 = k - 3;   // feats = [pc[:,3:6], pc[:,0:3]]
                    v = sfeat[((size_t)b * NSRC + gi) * 6 + (j2 < 3 ? 3 + j2 : j2 - 3)];
                }
            } else {
                const int gi = gix[p];
                if (k < 3) {
                    const float c = (k == 0) ? ctr0 : ((k == 1) ? ctr1 : ctr2);
                    v = sxyz[((size_t)b * NSRC + gi) * 3 + k] - c;
                } else {
                    v = sfeat[((size_t)b * NSRC + gi) * CF + (k - 3)];
                }
            }
        }
        xb[(size_t)p * LDXB + k] = f2bf_rne(v);
    }
    __syncthreads();

    // ---- Phase A: h1 = relu(x @ W1 + b1) via MFMA ----
    {
        bf16x8 af[NMT][KBA];
#pragma unroll
        for (int mt = 0; mt < NMT; ++mt)
#pragma unroll
            for (int kb = 0; kb < KBA; ++kb)
                af[mt][kb] = *(const bf16x8*)&xb[(size_t)(mt * 16 + lr) * LDXB + kb * 32 + lg * 8];

#pragma unroll
        for (int q = 0; q < NTA; ++q) {
            const int nt = w * NTA + q;
            const int c  = nt * 16 + lr;
            bf16x8 bfr[KBA];
#pragma unroll
            for (int kb = 0; kb < KBA; ++kb)
                bfr[kb] = *(const bf16x8*)&W1s[(size_t)((nt * KBA + kb) * 64 + lane) * 8];
            const float bb = B1v[c];
#pragma unroll
            for (int mt = 0; mt < NMT; ++mt) {
                f32x4 ac = {bb, bb, bb, bb};
#pragma unroll
                for (int kb = 0; kb < KBA; ++kb)
                    ac = __builtin_amdgcn_mfma_f32_16x16x32_bf16(af[mt][kb], bfr[kb], ac, 0, 0, 0);
#pragma unroll
                for (int i = 0; i < 4; ++i) {
                    const int row = mt * 16 + lg * 4 + i;
                    h1b[(size_t)row * LDHB + c] = f2bf_rne(fmaxf(ac[i], 0.f));
                }
            }
        }
    }
    __syncthreads();

    // ---- Phase B: out = maxpool_p (h1 @ W2 + b2) via MFMA ----
    {
        bf16x8 af[NMT][KBB];
#pragma unroll
        for (int mt = 0; mt < NMT; ++mt)
#pragma unroll
            for (int kb = 0; kb < KBB; ++kb)
                af[mt][kb] = *(const bf16x8*)&h1b[(size_t)(mt * 16 + lr) * LDHB + kb * 32 + lg * 8];

#pragma unroll
        for (int q = 0; q < NTB; ++q) {
            const int nt = w * NTB + q;
            const int c  = nt * 16 + lr;
            bf16x8 bfr[KBB];
#pragma unroll
            for (int kb = 0; kb < KBB; ++kb)
                bfr[kb] = *(const bf16x8*)&W2s[(size_t)((nt * KBB + kb) * 64 + lane) * 8];
            const float bb = B2v[c];
            float colmax = 0.f;   // relu >= 0
#pragma unroll
            for (int mt = 0; mt < NMT; ++mt) {
                f32x4 ac = {bb, bb, bb, bb};
#pragma unroll
                for (int kb = 0; kb < KBB; ++kb)
                    ac = __builtin_amdgcn_mfma_f32_16x16x32_bf16(af[mt][kb], bfr[kb], ac, 0, 0, 0);
                float pm = fmaxf(fmaxf(ac[0], ac[1]), fmaxf(ac[2], ac[3]));
                pm = fmaxf(pm, __shfl_xor(pm, 16));
                pm = fmaxf(pm, __shfl_xor(pm, 32));
                colmax = fmaxf(colmax, pm);
            }
            if (lg == 0) outf[(size_t)g * C2 + c] = colmax;
        }
    }
}

// ---------------- Head part 2: fc1(relu) -> fc2 -> bn-ish ----
__global__ __launch_bounds__(256)
void head2_kernel(const float* __restrict__ g4,
                  const float* __restrict__ fc1w, const float* __restrict__ fc1b,
                  const float* __restrict__ fc2w, const float* __restrict__ fc2b,
                  const float* __restrict__ gamma, const float* __restrict__ beta,
                  float* __restrict__ out)
{
    const int b   = blockIdx.x;
    const int tid = threadIdx.x;
    __shared__ float gm[1024], g1[1024];
    for (int c = tid; c < 1024; c += 256) gm[c] = g4[(size_t)b * 1024 + c];
    __syncthreads();
    {
        const int c0 = tid * 4;
        float4 a = *(const float4*)&fc1b[c0];
#pragma unroll 4
        for (int k = 0; k < 1024; ++k) {
            const float4 w = *(const float4*)&fc1w[(size_t)k * 1024 + c0];
            fma4(a, gm[k], w);
        }
        g1[c0 + 0] = fmaxf(a.x, 0.f); g1[c0 + 1] = fmaxf(a.y, 0.f);
        g1[c0 + 2] = fmaxf(a.z, 0.f); g1[c0 + 3] = fmaxf(a.w, 0.f);
    }
    __syncthreads();
    if (tid < 128) {
        const float s = sqrtf(1.00001f);
        const int c = tid;
        float a = fc2b[c];
#pragma unroll 4
        for (int k = 0; k < 1024; ++k) a = fmaf(g1[k], fc2w[(size_t)k * 128 + c], a);
        out[(size_t)b * 128 + c] = (a / s) * gamma[c] + beta[c];
    }
}

// ---------------------------------------------------------------------------
extern "C" void kernel_launch(void* const* d_in, const int* in_sizes, int n_in,
                              void* d_out, int out_size, void* d_ws, size_t ws_size,
                              hipStream_t stream)
{
    const float* pc   = (const float*)d_in[0];
    const float* w1a  = (const float*)d_in[1];  const float* b1a = (const float*)d_in[2];
    const float* w1b  = (const float*)d_in[3];  const float* b1b = (const float*)d_in[4];
    const float* w2a  = (const float*)d_in[5];  const float* b2a = (const float*)d_in[6];
    const float* w2b  = (const float*)d_in[7];  const float* b2b = (const float*)d_in[8];
    const float* w3a  = (const float*)d_in[9];  const float* b3a = (const float*)d_in[10];
    const float* w3b  = (const float*)d_in[11]; const float* b3b = (const float*)d_in[12];
    const float* w4a  = (const float*)d_in[13]; const float* b4a = (const float*)d_in[14];
    const float* w4b  = (const float*)d_in[15]; const float* b4b = (const float*)d_in[16];
    const float* fc1w = (const float*)d_in[17]; const float* fc1b = (const float*)d_in[18];
    const float* fc2w = (const float*)d_in[19]; const float* fc2b = (const float*)d_in[20];
    const float* gam  = (const float*)d_in[21]; const float* bet  = (const float*)d_in[22];
    float* out = (float*)d_out;

    char* ws = (char*)d_ws;
    size_t off = 0;
    auto alloc = [&](size_t bytes) -> void* {
        void* p = ws + off;
        off = (off + bytes + 255) & ~(size_t)255;
        return p;
    };
    float* nxyz1  = (float*)alloc((size_t)32 * 256 * 3 * 4);
    int*   gidx1  = (int*)  alloc((size_t)32 * 256 * 64 * 4);
    float* feats1 = (float*)alloc((size_t)32 * 256 * 128 * 4);
    float* nxyz2  = (float*)alloc((size_t)32 * 64 * 3 * 4);
    int*   gidx2  = (int*)  alloc((size_t)32 * 64 * 64 * 4);
    float* feats2 = (float*)alloc((size_t)32 * 64 * 256 * 4);
    float* nxyz3  = (float*)alloc((size_t)32 * 16 * 3 * 4);
    int*   gidx3  = (int*)  alloc((size_t)32 * 16 * 32 * 4);
    float* feats3 = (float*)alloc((size_t)32 * 16 * 512 * 4);
    float* g4     = (float*)alloc((size_t)32 * 1024 * 4);
    // pre-swizzled bf16 weight fragments
    unsigned short* w1as = (unsigned short*)alloc((size_t)4  * 1  * 64 * 8 * 2);  // stage1 W1 (9->32 x64)
    unsigned short* w1bs = (unsigned short*)alloc((size_t)8  * 2  * 64 * 8 * 2);  // stage1 W2 (64x128)
    unsigned short* w2as = (unsigned short*)alloc((size_t)8  * 5  * 64 * 8 * 2);  // stage2 W1 (131->160 x128)
    unsigned short* w2bs = (unsigned short*)alloc((size_t)16 * 4  * 64 * 8 * 2);  // stage2 W2 (128x256)
    unsigned short* w3as = (unsigned short*)alloc((size_t)16 * 9  * 64 * 8 * 2);  // stage3 W1 (259->288 x256)
    unsigned short* w3bs = (unsigned short*)alloc((size_t)32 * 8  * 64 * 8 * 2);  // stage3 W2 (256x512)
    unsigned short* w4as = (unsigned short*)alloc((size_t)32 * 17 * 64 * 8 * 2);  // head W1 (515->544 x512)
    unsigned short* w4bs = (unsigned short*)alloc((size_t)64 * 16 * 64 * 8 * 2);  // head W2 (512x1024)

    const float r2a = (float)(0.1 * 0.1);
    const float r2b = (float)(0.2 * 0.2);
    const float r2c = (float)(0.4 * 0.4);

    // ---- Weight pre-swizzle: ONE launch for all 8 matrices ----
    wswz_all_kernel<<<1024, 256, 0, stream>>>(w1a, w1as, w1b, w1bs, w2a, w2as, w2b, w2bs,
                                              w3a, w3as, w3b, w3bs, w4a, w4as, w4b, w4bs);

    // ---- All three FPS stages fused (one block per batch, 4-wave config) ----
    fps_fused_kernel<<<32, 256, 0, stream>>>(pc, nxyz1, nxyz2, nxyz3);

    // ---- All three ball queries: ONE launch (block-range dispatch) ----
    bq_all_kernel<<<2688, 256, 0, stream>>>(pc, nxyz1, gidx1, r2a,
                                            nxyz2, gidx2, r2b,
                                            nxyz3, gidx3, r2c);

    // ---- SA MLPs: all full MFMA ----
    sa_mlp_mfma_kernel<64, 9, 64, 128, 4096, 0><<<32 * 256, 256, 0, stream>>>(
        pc, pc, nxyz1, gidx1, w1as, b1a, w1bs, b1b, feats1, 256);
    sa_mlp_mfma_kernel<64, 131, 128, 256, 256, 1><<<32 * 64, 256, 0, stream>>>(
        nxyz1, feats1, nxyz2, gidx2, w2as, b2a, w2bs, b2b, feats2, 64);
    sa_mlp_mfma_kernel<32, 259, 256, 512, 64, 1><<<32 * 16, 256, 0, stream>>>(
        nxyz2, feats2, nxyz3, gidx3, w3as, b3a, w3bs, b3b, feats3, 16);

    // ---- Head: per-batch full-MFMA MLP with fused maxpool(16), then fc ----
    sa_mlp_mfma_kernel<16, 515, 512, 1024, 16, 2><<<32, 256, 0, stream>>>(
        nxyz3, feats3, nullptr, nullptr, w4as, b4a, w4bs, b4b, g4, 1);
    head2_kernel<<<32, 256, 0, stream>>>(g4, fc1w, fc1b, fc2w, fc2b, gam, bet, out);
}

// Round 23
// 584.606 us; speedup vs baseline: 2.0982x; 1.0095x over previous
//
#include <hip/hip_runtime.h>

#define DEV static __device__ __forceinline__

using bf16x8 = __attribute__((ext_vector_type(8))) short;   // 8 bf16 (4 VGPRs)
using f32x4  = __attribute__((ext_vector_type(4))) float;

DEV float sqdist(float dx, float dy, float dz) {
    // ((dx*dx + dy*dy) + dz*dz) with no FMA contraction — must match numpy f32
    return __fadd_rn(__fadd_rn(__fmul_rn(dx, dx), __fmul_rn(dy, dy)), __fmul_rn(dz, dz));
}

DEV void fma4(float4& acc, float h, const float4& w) {
    acc.x = fmaf(h, w.x, acc.x); acc.y = fmaf(h, w.y, acc.y);
    acc.z = fmaf(h, w.z, acc.z); acc.w = fmaf(h, w.w, acc.w);
}

DEV unsigned short f2bf_rne(float f) {   // fp32 -> bf16, round-nearest-even
    unsigned u = __builtin_bit_cast(unsigned, f);
    return (unsigned short)((u + 0x7FFFu + ((u >> 16) & 1u)) >> 16);
}

// ---- weight pre-swizzle section: fp32 W[K][C] -> bf16 fragment layout ----
// out[((nt*KB+kb)*64+lane)*8 + j] = bf16(W[kb*32+(lane>>4)*8+j][nt*16+(lane&15)])
template<int KSRC, int KB, int C>
DEV void wswz_sec(const float* __restrict__ W, unsigned short* __restrict__ out,
                  int idx0, int stride)
{
    constexpr int NT = C / 16;
    constexpr int TOTAL = NT * KB * 64 * 8;
    for (int idx = idx0; idx < TOTAL; idx += stride) {
        const int j    = idx & 7;
        const int lane = (idx >> 3) & 63;
        const int fb   = idx >> 9;          // nt*KB + kb
        const int kb   = fb % KB, nt = fb / KB;
        const int k    = kb * 32 + (lane >> 4) * 8 + j;
        const int c    = nt * 16 + (lane & 15);
        const float v  = (k < KSRC) ? W[(size_t)k * C + c] : 0.f;
        out[idx] = f2bf_rne(v);
    }
}

// ---- argmax combine steps (value desc, index asc on ties) ----
template<int CTRL>
DEV int dpp_mov(int v) {
    return __builtin_amdgcn_update_dpp(v, v, CTRL, 0xF, 0xF, false);
}
template<int CTRL>
DEV void red_step_dpp(float& bv, int& bi) {
    float ov = __builtin_bit_cast(float, dpp_mov<CTRL>(__builtin_bit_cast(int, bv)));
    int   oi = dpp_mov<CTRL>(bi);
    if (ov > bv || (ov == bv && oi < bi)) { bv = ov; bi = oi; }
}
// full 64-lane argmax; result valid in lane 63
DEV void wave_argmax(float& bv, int& bi) {
    red_step_dpp<0xB1>(bv, bi);    // quad_perm xor 1
    red_step_dpp<0x4E>(bv, bi);    // quad_perm xor 2
    red_step_dpp<0x141>(bv, bi);   // row_half_mirror (xor 4)
    red_step_dpp<0x140>(bv, bi);   // row_mirror (xor 8)
    red_step_dpp<0x142>(bv, bi);   // row_bcast15
    red_step_dpp<0x143>(bv, bi);   // row_bcast31 -> lane 63 has full result
}

// ---- single-wave FPS over LDS points (no barriers) ----
template<int N, int NPOINT>
DEV void fps_wave64(const float4* pts, float* sout, int lane) {
    constexpr int K = (N + 63) / 64;
    float rx[K], ry[K], rz[K], d[K];
#pragma unroll
    for (int k = 0; k < K; ++k) {
        const float4 c = pts[lane + k * 64];
        rx[k] = c.x; ry[k] = c.y; rz[k] = c.z; d[k] = 1e10f;
    }
    const float4 c0 = pts[0];
    float cx = c0.x, cy = c0.y, cz = c0.z;
    for (int s = 0; s < NPOINT; ++s) {
        if (lane == 0) { sout[s * 3 + 0] = cx; sout[s * 3 + 1] = cy; sout[s * 3 + 2] = cz; }
        float bestv = -1.0f; int besti = 0x7fffffff;
#pragma unroll
        for (int k = 0; k < K; ++k) {
            float d2 = sqdist(rx[k] - cx, ry[k] - cy, rz[k] - cz);
            d[k] = fminf(d[k], d2);
            if (d[k] > bestv) { bestv = d[k]; besti = lane + k * 64; }
        }
        wave_argmax(bestv, besti);
        const int far = __builtin_amdgcn_readlane(besti, 63);
        const float4 c = pts[far];
        cx = c.x; cy = c.y; cz = c.z;
    }
}

// ---- FPS device body (all 3 stages, 4-wave measured-floor config) ----
DEV void fps_body(const float* __restrict__ pc, int b, int tid,
                  float* __restrict__ nxyz1, float* __restrict__ nxyz2,
                  float* __restrict__ nxyz3)
{
    constexpr int N1 = 4096, NP1 = 256, NP2 = 64, NP3 = 16, T = 256, NW = T / 64;
    constexpr int K = N1 / T;
    __shared__ float4 pxyz[N1];
    __shared__ float  sout1[NP1 * 3];
    __shared__ float  sout2[NP2 * 3];
    __shared__ float  sout3[NP3 * 3];
    __shared__ float  rv[2][NW];
    __shared__ int    ri[2][NW];

    const int w = tid >> 6, lane = tid & 63;
    const float* base = pc + (size_t)b * N1 * 6;

    float rx[K], ry[K], rz[K], d[K];
#pragma unroll
    for (int k = 0; k < K; ++k) {
        const int p = tid + k * T;
        const float x = base[p * 6 + 0];
        const float y = base[p * 6 + 1];
        const float z = base[p * 6 + 2];
        pxyz[p] = make_float4(x, y, z, 0.f);
        rx[k] = x; ry[k] = y; rz[k] = z;
        d[k] = 1e10f;
    }
    __syncthreads();

    // ---- stage 1 ----
    {
        const float4 c0 = pxyz[0];
        float cx = c0.x, cy = c0.y, cz = c0.z;
        for (int s = 0; s < NP1; ++s) {
            if (tid == 0) { sout1[s * 3 + 0] = cx; sout1[s * 3 + 1] = cy; sout1[s * 3 + 2] = cz; }
            float bestv = -1.0f; int besti = 0x7fffffff;
#pragma unroll
            for (int k = 0; k < K; ++k) {
                float d2 = sqdist(rx[k] - cx, ry[k] - cy, rz[k] - cz);
                d[k] = fminf(d[k], d2);
                if (d[k] > bestv) { bestv = d[k]; besti = tid + k * T; }  // k asc => lowest p
            }
            wave_argmax(bestv, besti);

            const int par = s & 1;
            if (lane == 63) { rv[par][w] = bestv; ri[par][w] = besti; }
            __syncthreads();
            float bvv = rv[par][0]; int bii = ri[par][0];
#pragma unroll
            for (int q = 1; q < NW; ++q) {
                const float qv = rv[par][q]; const int qi = ri[par][q];
                if (qv > bvv || (qv == bvv && qi < bii)) { bvv = qv; bii = qi; }
            }
            const float4 c = pxyz[bii];
            cx = c.x; cy = c.y; cz = c.z;
        }
    }

    // ---- stages 2 + 3 on wave 0 ----
    if (w == 0) {
        for (int i = lane; i < NP1; i += 64)
            pxyz[i] = make_float4(sout1[i * 3 + 0], sout1[i * 3 + 1], sout1[i * 3 + 2], 0.f);
        fps_wave64<NP1, NP2>(pxyz, sout2, lane);
        for (int i = lane; i < NP2; i += 64)
            pxyz[i] = make_float4(sout2[i * 3 + 0], sout2[i * 3 + 1], sout2[i * 3 + 2], 0.f);
        fps_wave64<NP2, NP3>(pxyz, sout3, lane);
    }
    __syncthreads();

    float* o1 = nxyz1 + (size_t)b * NP1 * 3;
    for (int i = tid; i < NP1 * 3; i += T) o1[i] = sout1[i];
    float* o2 = nxyz2 + (size_t)b * NP2 * 3;
    if (tid < NP2 * 3) o2[tid] = sout2[tid];
    float* o3 = nxyz3 + (size_t)b * NP3 * 3;
    if (tid < NP3 * 3) o3[tid] = sout3[tid];
}

// ---- merged launch: blocks 0-31 run FPS; blocks 32-159 run weight swizzle ----
__global__ __launch_bounds__(256)
void fps_wswz_kernel(const float* __restrict__ pc,
                     float* __restrict__ nxyz1, float* __restrict__ nxyz2,
                     float* __restrict__ nxyz3,
                     const float* w1a, unsigned short* o1a,
                     const float* w1b, unsigned short* o1b,
                     const float* w2a, unsigned short* o2a,
                     const float* w2b, unsigned short* o2b,
                     const float* w3a, unsigned short* o3a,
                     const float* w3b, unsigned short* o3b,
                     const float* w4a, unsigned short* o4a,
                     const float* w4b, unsigned short* o4b)
{
    if (blockIdx.x < 32) {
        fps_body(pc, blockIdx.x, threadIdx.x, nxyz1, nxyz2, nxyz3);
    } else {
        const int idx0   = (blockIdx.x - 32) * 256 + threadIdx.x;
        const int stride = 128 * 256;
        wswz_sec<9,   1,  64 >(w1a, o1a, idx0, stride);
        wswz_sec<64,  2,  128>(w1b, o1b, idx0, stride);
        wswz_sec<131, 5,  128>(w2a, o2a, idx0, stride);
        wswz_sec<128, 4,  256>(w2b, o2b, idx0, stride);
        wswz_sec<259, 9,  256>(w3a, o3a, idx0, stride);
        wswz_sec<256, 8,  512>(w3b, o3b, idx0, stride);
        wswz_sec<515, 17, 512>(w4a, o4a, idx0, stride);
        wswz_sec<512, 16, 1024>(w4b, o4b, idx0, stride);
    }
}

// ---------------- Ball query (device body) -----------------
template<int N, int NSAMP, int STRIDE>
DEV void bq_dev(const float* __restrict__ xyz, const float* __restrict__ newxyz,
                int* __restrict__ gidx, float r2, int S, int total, int wid, int lane)
{
    if (wid >= total) return;
    const int b = wid / S;
    const float cx = newxyz[(size_t)wid * 3 + 0];
    const float cy = newxyz[(size_t)wid * 3 + 1];
    const float cz = newxyz[(size_t)wid * 3 + 2];
    const float* base = xyz + (size_t)b * N * STRIDE;
    int* out = gidx + (size_t)wid * NSAMP;

    int count = 0, first = N - 1;
    constexpr int NCH = (N + 63) / 64;
    for (int ch = 0; ch < NCH; ++ch) {
        int p = ch * 64 + lane;
        bool pred = false;
        if (N % 64 == 0 || p < N) {
            float dx = base[p * STRIDE + 0] - cx;
            float dy = base[p * STRIDE + 1] - cy;
            float dz = base[p * STRIDE + 2] - cz;
            pred = sqdist(dx, dy, dz) < r2;
        }
        unsigned long long m = __ballot(pred);
        if (m) {
            if (count == 0) first = ch * 64 + __builtin_ctzll(m);
            int pos = count + __popcll(m & ((1ull << lane) - 1ull));
            if (pred && pos < NSAMP) out[pos] = p;
            count += __popcll(m);
            if (count >= NSAMP) break;
        }
    }
    if (count > NSAMP) count = NSAMP;
    for (int pos = count + lane; pos < NSAMP; pos += 64) out[pos] = first;
}

// All three ball queries in one launch (block-range dispatch).
__global__ __launch_bounds__(256)
void bq_all_kernel(const float* __restrict__ pc,
                   const float* __restrict__ nxyz1, int* __restrict__ gidx1, float r2a,
                   const float* __restrict__ nxyz2, int* __restrict__ gidx2, float r2b,
                   const float* __restrict__ nxyz3, int* __restrict__ gidx3, float r2c)
{
    const int blk  = blockIdx.x;
    const int w    = threadIdx.x >> 6;
    const int lane = threadIdx.x & 63;
    if (blk < 2048) {
        bq_dev<4096, 64, 6>(pc, nxyz1, gidx1, r2a, 256, 32 * 256, blk * 4 + w, lane);
    } else if (blk < 2560) {
        bq_dev<256, 64, 3>(nxyz1, nxyz2, gidx2, r2b, 64, 32 * 64, (blk - 2048) * 4 + w, lane);
    } else {
        bq_dev<64, 32, 3>(nxyz2, nxyz3, gidx3, r2c, 16, 32 * 16, (blk - 2560) * 4 + w, lane);
    }
}

// ---------------- Grouped 2-layer MLP + maxpool, FULL MFMA ----
// Both layers on mfma_f32_16x16x32_bf16; W1s/W2s pre-swizzled bf16 fragments.
// MODE 0: stage1 gather (xyz stride 6, feats = pc permuted [3:6]++[0:3]).
// MODE 1: mid stages (xyz stride 3, feats array) via gidx.
// MODE 2: head — direct rows, fused maxpool, then fc1/fc2/bn in-block.
template<int NS, int CIN, int C1, int C2, int NSRC, int MODE>
__global__ __launch_bounds__(256)
void sa_mlp_mfma_kernel(const float* __restrict__ sxyz, const float* __restrict__ sfeat,
                        const float* __restrict__ newxyz, const int* __restrict__ gidx,
                        const unsigned short* __restrict__ W1s, const float* __restrict__ B1v,
                        const unsigned short* __restrict__ W2s, const float* __restrict__ B2v,
                        float* __restrict__ outf, int S,
                        const float* __restrict__ fc1w = nullptr, const float* __restrict__ fc1b = nullptr,
                        const float* __restrict__ fc2w = nullptr, const float* __restrict__ fc2b = nullptr,
                        const float* __restrict__ gamma = nullptr, const float* __restrict__ beta = nullptr)
{
    constexpr int T    = 256;
    constexpr int KP   = ((CIN + 31) / 32) * 32;   // K padded
    constexpr int LDXB = KP + 8;                   // bf16 x row stride (16B mult)
    constexpr int KBA  = KP / 32;                  // phase-A K-blocks
    constexpr int NMT  = NS / 16;                  // M-tiles
    constexpr int NTA  = C1 / 16 / 4;              // phase-A N-tiles per wave
    constexpr int LDHB = C1 + 8;                   // bf16 h1 row stride
    constexpr int KBB  = C1 / 32;                  // phase-B K-blocks
    constexpr int NTB  = C2 / 16 / 4;              // phase-B N-tiles per wave
    constexpr int CF   = CIN - 3;
    static_assert(NS % 16 == 0 && C1 % 64 == 0 && C2 % 64 == 0, "");

    __shared__ __align__(16) unsigned short xb[NS * LDXB];
    __shared__ __align__(16) unsigned short h1b[NS * LDHB];
    __shared__ int gix[NS];
    __shared__ float gmS[(MODE == 2) ? C2 : 4];    // fused-head: pooled features
    __shared__ float g1S[(MODE == 2) ? 1024 : 4];  // fused-head: fc1 output

    const int g   = blockIdx.x;
    const int b   = g / S;
    const int tid = threadIdx.x;
    const int w    = tid >> 6;
    const int lane = tid & 63;
    const int lr   = lane & 15;
    const int lg   = lane >> 4;

    float ctr0 = 0.f, ctr1 = 0.f, ctr2 = 0.f;
    if constexpr (MODE != 2) {
        ctr0 = newxyz[(size_t)g * 3 + 0];
        ctr1 = newxyz[(size_t)g * 3 + 1];
        ctr2 = newxyz[(size_t)g * 3 + 2];
        for (int i = tid; i < NS; i += T) gix[i] = gidx[(size_t)g * NS + i];
        __syncthreads();
    }

    // ---- gather full input as bf16 (rel-xyz in fp32, then RNE; pad = 0) ----
    for (int idx = tid; idx < NS * KP; idx += T) {
        const int p = idx / KP, k = idx - p * KP;
        float v = 0.f;
        if (k < CIN) {
            if constexpr (MODE == 2) {
                v = (k < 3) ? sxyz[((size_t)g * NS + p) * 3 + k]
                            : sfeat[((size_t)g * NS + p) * CF + (k - 3)];
            } else if constexpr (MODE == 0) {
                const int gi = gix[p];
                if (k < 3) {
                    const float c = (k == 0) ? ctr0 : ((k == 1) ? ctr1 : ctr2);
                    v = sxyz[((size_t)b * NSRC + gi) * 6 + k] - c;
                } else {
                    const int j2 = k - 3;   // feats = [pc[:,3:6], pc[:,0:3]]
                    v = sfeat[((size_t)b * NSRC + gi) * 6 + (j2 < 3 ? 3 + j2 : j2 - 3)];
                }
            } else {
                const int gi = gix[p];
                if (k < 3) {
                    const float c = (k == 0) ? ctr0 : ((k == 1) ? ctr1 : ctr2);
                    v = sxyz[((size_t)b * NSRC + gi) * 3 + k] - c;
                } else {
                    v = sfeat[((size_t)b * NSRC + gi) * CF + (k - 3)];
                }
            }
        }
        xb[(size_t)p * LDXB + k] = f2bf_rne(v);
    }
    __syncthreads();

    // ---- Phase A: h1 = relu(x @ W1 + b1) via MFMA ----
    {
        bf16x8 af[NMT][KBA];
#pragma unroll
        for (int mt = 0; mt < NMT; ++mt)
#pragma unroll
            for (int kb = 0; kb < KBA; ++kb)
                af[mt][kb] = *(const bf16x8*)&xb[(size_t)(mt * 16 + lr) * LDXB + kb * 32 + lg * 8];

#pragma unroll
        for (int q = 0; q < NTA; ++q) {
            const int nt = w * NTA + q;
            const int c  = nt * 16 + lr;
            bf16x8 bfr[KBA];
#pragma unroll
            for (int kb = 0; kb < KBA; ++kb)
                bfr[kb] = *(const bf16x8*)&W1s[(size_t)((nt * KBA + kb) * 64 + lane) * 8];
            const float bb = B1v[c];
#pragma unroll
            for (int mt = 0; mt < NMT; ++mt) {
                f32x4 ac = {bb, bb, bb, bb};
#pragma unroll
                for (int kb = 0; kb < KBA; ++kb)
                    ac = __builtin_amdgcn_mfma_f32_16x16x32_bf16(af[mt][kb], bfr[kb], ac, 0, 0, 0);
#pragma unroll
                for (int i = 0; i < 4; ++i) {
                    const int row = mt * 16 + lg * 4 + i;
                    h1b[(size_t)row * LDHB + c] = f2bf_rne(fmaxf(ac[i], 0.f));
                }
            }
        }
    }
    __syncthreads();

    // ---- Phase B: out = maxpool_p (h1 @ W2 + b2) via MFMA ----
    {
        bf16x8 af[NMT][KBB];
#pragma unroll
        for (int mt = 0; mt < NMT; ++mt)
#pragma unroll
            for (int kb = 0; kb < KBB; ++kb)
                af[mt][kb] = *(const bf16x8*)&h1b[(size_t)(mt * 16 + lr) * LDHB + kb * 32 + lg * 8];

#pragma unroll
        for (int q = 0; q < NTB; ++q) {
            const int nt = w * NTB + q;
            const int c  = nt * 16 + lr;
            bf16x8 bfr[KBB];
#pragma unroll
            for (int kb = 0; kb < KBB; ++kb)
                bfr[kb] = *(const bf16x8*)&W2s[(size_t)((nt * KBB + kb) * 64 + lane) * 8];
            const float bb = B2v[c];
            float colmax = 0.f;   // relu >= 0
#pragma unroll
            for (int mt = 0; mt < NMT; ++mt) {
                f32x4 ac = {bb, bb, bb, bb};
#pragma unroll
                for (int kb = 0; kb < KBB; ++kb)
                    ac = __builtin_amdgcn_mfma_f32_16x16x32_bf16(af[mt][kb], bfr[kb], ac, 0, 0, 0);
                float pm = fmaxf(fmaxf(ac[0], ac[1]), fmaxf(ac[2], ac[3]));
                pm = fmaxf(pm, __shfl_xor(pm, 16));
                pm = fmaxf(pm, __shfl_xor(pm, 32));
                colmax = fmaxf(colmax, pm);
            }
            if constexpr (MODE == 2) {
                if (lg == 0) gmS[c] = colmax;
            } else {
                if (lg == 0) outf[(size_t)g * C2 + c] = colmax;
            }
        }
    }

    // ---- fused head tail: fc1(relu) -> fc2 -> bn-ish (MODE 2 only) ----
    if constexpr (MODE == 2) {
        __syncthreads();
        {
            const int c0 = tid * 4;
            float4 a = *(const float4*)&fc1b[c0];
#pragma unroll 4
            for (int k = 0; k < 1024; ++k) {
                const float4 ww = *(const float4*)&fc1w[(size_t)k * 1024 + c0];
                fma4(a, gmS[k], ww);
            }
            g1S[c0 + 0] = fmaxf(a.x, 0.f); g1S[c0 + 1] = fmaxf(a.y, 0.f);
            g1S[c0 + 2] = fmaxf(a.z, 0.f); g1S[c0 + 3] = fmaxf(a.w, 0.f);
        }
        __syncthreads();
        if (tid < 128) {
            const float s = sqrtf(1.00001f);
            const int c = tid;
            float a = fc2b[c];
#pragma unroll 4
            for (int k = 0; k < 1024; ++k) a = fmaf(g1S[k], fc2w[(size_t)k * 128 + c], a);
            outf[(size_t)g * 128 + c] = (a / s) * gamma[c] + beta[c];
        }
    }
}

// ---------------------------------------------------------------------------
extern "C" void kernel_launch(void* const* d_in, const int* in_sizes, int n_in,
                              void* d_out, int out_size, void* d_ws, size_t ws_size,
                              hipStream_t stream)
{
    const float* pc   = (const float*)d_in[0];
    const float* w1a  = (const float*)d_in[1];  const float* b1a = (const float*)d_in[2];
    const float* w1b  = (const float*)d_in[3];  const float* b1b = (const float*)d_in[4];
    const float* w2a  = (const float*)d_in[5];  const float* b2a = (const float*)d_in[6];
    const float* w2b  = (const float*)d_in[7];  const float* b2b = (const float*)d_in[8];
    const float* w3a  = (const float*)d_in[9];  const float* b3a = (const float*)d_in[10];
    const float* w3b  = (const float*)d_in[11]; const float* b3b = (const float*)d_in[12];
    const float* w4a  = (const float*)d_in[13]; const float* b4a = (const float*)d_in[14];
    const float* w4b  = (const float*)d_in[15]; const float* b4b = (const float*)d_in[16];
    const float* fc1w = (const float*)d_in[17]; const float* fc1b = (const float*)d_in[18];
    const float* fc2w = (const float*)d_in[19]; const float* fc2b = (const float*)d_in[20];
    const float* gam  = (const float*)d_in[21]; const float* bet  = (const float*)d_in[22];
    float* out = (float*)d_out;

    char* ws = (char*)d_ws;
    size_t off = 0;
    auto alloc = [&](size_t bytes) -> void* {
        void* p = ws + off;
        off = (off + bytes + 255) & ~(size_t)255;
        return p;
    };
    float* nxyz1  = (float*)alloc((size_t)32 * 256 * 3 * 4);
    int*   gidx1  = (int*)  alloc((size_t)32 * 256 * 64 * 4);
    float* feats1 = (float*)alloc((size_t)32 * 256 * 128 * 4);
    float* nxyz2  = (float*)alloc((size_t)32 * 64 * 3 * 4);
    int*   gidx2  = (int*)  alloc((size_t)32 * 64 * 64 * 4);
    float* feats2 = (float*)alloc((size_t)32 * 64 * 256 * 4);
    float* nxyz3  = (float*)alloc((size_t)32 * 16 * 3 * 4);
    int*   gidx3  = (int*)  alloc((size_t)32 * 16 * 32 * 4);
    float* feats3 = (float*)alloc((size_t)32 * 16 * 512 * 4);
    // pre-swizzled bf16 weight fragments
    unsigned short* w1as = (unsigned short*)alloc((size_t)4  * 1  * 64 * 8 * 2);  // stage1 W1 (9->32 x64)
    unsigned short* w1bs = (unsigned short*)alloc((size_t)8  * 2  * 64 * 8 * 2);  // stage1 W2 (64x128)
    unsigned short* w2as = (unsigned short*)alloc((size_t)8  * 5  * 64 * 8 * 2);  // stage2 W1 (131->160 x128)
    unsigned short* w2bs = (unsigned short*)alloc((size_t)16 * 4  * 64 * 8 * 2);  // stage2 W2 (128x256)
    unsigned short* w3as = (unsigned short*)alloc((size_t)16 * 9  * 64 * 8 * 2);  // stage3 W1 (259->288 x256)
    unsigned short* w3bs = (unsigned short*)alloc((size_t)32 * 8  * 64 * 8 * 2);  // stage3 W2 (256x512)
    unsigned short* w4as = (unsigned short*)alloc((size_t)32 * 17 * 64 * 8 * 2);  // head W1 (515->544 x512)
    unsigned short* w4bs = (unsigned short*)alloc((size_t)64 * 16 * 64 * 8 * 2);  // head W2 (512x1024)

    const float r2a = (float)(0.1 * 0.1);
    const float r2b = (float)(0.2 * 0.2);
    const float r2c = (float)(0.4 * 0.4);

    // ---- FPS (blocks 0-31) + weight pre-swizzle (blocks 32-159), one launch ----
    fps_wswz_kernel<<<160, 256, 0, stream>>>(pc, nxyz1, nxyz2, nxyz3,
                                             w1a, w1as, w1b, w1bs, w2a, w2as, w2b, w2bs,
                                             w3a, w3as, w3b, w3bs, w4a, w4as, w4b, w4bs);

    // ---- All three ball queries: ONE launch (block-range dispatch) ----
    bq_all_kernel<<<2688, 256, 0, stream>>>(pc, nxyz1, gidx1, r2a,
                                            nxyz2, gidx2, r2b,
                                            nxyz3, gidx3, r2c);

    // ---- SA MLPs: all full MFMA ----
    sa_mlp_mfma_kernel<64, 9, 64, 128, 4096, 0><<<32 * 256, 256, 0, stream>>>(
        pc, pc, nxyz1, gidx1, w1as, b1a, w1bs, b1b, feats1, 256);
    sa_mlp_mfma_kernel<64, 131, 128, 256, 256, 1><<<32 * 64, 256, 0, stream>>>(
        nxyz1, feats1, nxyz2, gidx2, w2as, b2a, w2bs, b2b, feats2, 64);
    sa_mlp_mfma_kernel<32, 259, 256, 512, 64, 1><<<32 * 16, 256, 0, stream>>>(
        nxyz2, feats2, nxyz3, gidx3, w3as, b3a, w3bs, b3b, feats3, 16);

    // ---- Head: full-MFMA MLP + fused maxpool(16) + fc1/fc2/bn, one launch ----
    sa_mlp_mfma_kernel<16, 515, 512, 1024, 16, 2><<<32, 256, 0, stream>>>(
        nxyz3, feats3, nullptr, nullptr, w4as, b4a, w4bs, b4b, out, 1,
        fc1w, fc1b, fc2w, fc2b, gam, bet);
}